// Round 4
// baseline (7557.084 us; speedup 1.0000x reference)
//
#include <hip/hip_runtime.h>
#include <hip/hip_bf16.h>
#include <stdint.h>

#define NF 256
#define EPSV 1e-5f

typedef unsigned short u16;

// param block offsets (floats)
#define P_BGCN 0
#define P_G1 256
#define P_BE1 512
#define P_BAGG 768
#define P_AGG1 1024
#define P_AGBE1 1280
#define P_ASRC 1536
#define P_ADST 1792
#define P_BGAT 2048
#define P_ASRC2 2304
#define P_ADST2 2560
#define P_BGAT2 2816
#define P_G2 3072
#define P_BE2 3584
#define P_WFC 4096
#define P_AGG2 4608
#define P_AGBE2 5120
#define P_WAGFC 5632
#define P_BFC 6144
#define P_BAGFC 6145

__device__ __forceinline__ float bf2f(u16 u) {
    union { unsigned int i; float f; } v; v.i = ((unsigned int)u) << 16; return v.f;
}
__device__ __forceinline__ float sane(float f) {
    return (f == f && fabsf(f) < 1e30f) ? f : 0.f;
}
__device__ __forceinline__ float lrelu(float x) { return x > 0.f ? x : 0.2f * x; }

__device__ __forceinline__ void atomicMaxF(float* addr, float v) {
    if (v >= 0.f) atomicMax((int*)addr, __float_as_int(v));
    else          atomicMin((unsigned int*)addr, __float_as_uint(v));
}

// ---------------- dtype detect: flag=1 -> float inputs are bf16, 0 -> fp32 ----------------
__global__ void detect_k(const u16* __restrict__ x, int* __restrict__ flag) {
    __shared__ int cnt;
    if (threadIdx.x == 0) cnt = 0;
    __syncthreads();
    int c = 0;
#pragma unroll
    for (int k = 0; k < 4; ++k) {
        unsigned int u = x[2 * (threadIdx.x + 256 * k)];
        int e = (int)((u >> 7) & 0xFFu);
        if (u == 0u || (e >= 100 && e <= 140)) c++;
    }
    atomicAdd(&cnt, c);
    __syncthreads();
    if (threadIdx.x == 0) flag[0] = (cnt >= 512) ? 1 : 0;
}

// convert one param tensor into fp32 prm block
__global__ void cvt_k(const void* __restrict__ src, float* __restrict__ dst, int n,
                      const int* __restrict__ flagp) {
    int i = blockIdx.x * 256 + threadIdx.x;
    if (i >= n) return;
    float v = flagp[0] ? bf2f(((const u16*)src)[i]) : ((const float*)src)[i];
    dst[i] = sane(v);
}

// ---------------- utility ----------------
__global__ void fill_k(float* __restrict__ p, float v, int n) {
    int i = blockIdx.x * 256 + threadIdx.x;
    if (i < n) p[i] = v;
}
__global__ void relu_k(float* __restrict__ p, int n) {
    int i = blockIdx.x * 256 + threadIdx.x;
    if (i < n) p[i] = fmaxf(p[i], 0.f);
}

// ---------------- simple correct GEMM: C(Mx256) = A(Mx256) @ W(256x256) ----------------
// amode: 2 = raw network input (dtype per flag), 0 = fp32 ws buffer. W always raw (per flag).
// 8 rows per block; A rows staged in LDS (broadcast reads); W read coalesced, native layout.
__global__ __launch_bounds__(256) void gemm8_k(const void* __restrict__ Aptr, int amode,
                                               const void* __restrict__ Wptr,
                                               const int* __restrict__ flagp,
                                               float* __restrict__ C, int M) {
    __shared__ float As[8][256];
    int f = flagp[0];
    int abf = (amode == 2) ? f : 0;
    int r0 = blockIdx.x * 8;
    int j = threadIdx.x;
#pragma unroll
    for (int rr = 0; rr < 8; ++rr) {
        int r = r0 + rr;
        float v = 0.f;
        if (r < M) {
            v = abf ? bf2f(((const u16*)Aptr)[(size_t)r * NF + j])
                    : ((const float*)Aptr)[(size_t)r * NF + j];
        }
        As[rr][j] = sane(v);
    }
    __syncthreads();
    float a0 = 0.f, a1 = 0.f, a2 = 0.f, a3 = 0.f;
    float a4 = 0.f, a5 = 0.f, a6 = 0.f, a7 = 0.f;
    for (int k = 0; k < 256; ++k) {
        float w = f ? bf2f(((const u16*)Wptr)[k * NF + j]) : ((const float*)Wptr)[k * NF + j];
        w = sane(w);
        a0 += As[0][k] * w;
        a1 += As[1][k] * w;
        a2 += As[2][k] * w;
        a3 += As[3][k] * w;
        a4 += As[4][k] * w;
        a5 += As[5][k] * w;
        a6 += As[6][k] * w;
        a7 += As[7][k] * w;
    }
    float acc[8] = {a0, a1, a2, a3, a4, a5, a6, a7};
#pragma unroll
    for (int rr = 0; rr < 8; ++rr) {
        if (r0 + rr < M) C[(size_t)(r0 + rr) * NF + j] = acc[rr];
    }
}

// ---------------- GCN ----------------
__global__ void deg_k(const int* __restrict__ dst, int E, float* __restrict__ deg) {
    int i = blockIdx.x * 256 + threadIdx.x;
    if (i < E) atomicAdd(&deg[dst[i]], 1.0f);
}
__global__ void rsqrt_k(float* __restrict__ p, int n) {
    int i = blockIdx.x * 256 + threadIdx.x;
    if (i < n) p[i] = rsqrtf(fmaxf(p[i], 1.0f));
}
__global__ void gcn_init_k(const float* __restrict__ h, const float* __restrict__ dinv,
                           const float* __restrict__ b, float* __restrict__ out, int n) {
    int t = blockIdx.x * 256 + threadIdx.x;
    if (t >= n * 64) return;
    int i = t >> 6, c = (t & 63) * 4;
    float di = dinv[i]; float w = di * di;
    float4 hv = *(const float4*)(h + (size_t)i * NF + c);
    float4 o;
    o.x = hv.x * w + b[c + 0];
    o.y = hv.y * w + b[c + 1];
    o.z = hv.z * w + b[c + 2];
    o.w = hv.w * w + b[c + 3];
    *(float4*)(out + (size_t)i * NF + c) = o;
}
__global__ void gcn_edge_k(const float* __restrict__ h, const float* __restrict__ dinv,
                           const int* __restrict__ ei, int E, float* __restrict__ out) {
    int t = blockIdx.x * 256 + threadIdx.x;
    if (t >= E * 64) return;
    int e = t >> 6, c = (t & 63) * 4;
    int s = ei[e], d = ei[E + e];
    float nrm = dinv[s] * dinv[d];
    float4 hv = *(const float4*)(h + (size_t)s * NF + c);
    float* o = out + (size_t)d * NF + c;
    atomicAdd(o + 0, hv.x * nrm);
    atomicAdd(o + 1, hv.y * nrm);
    atomicAdd(o + 2, hv.z * nrm);
    atomicAdd(o + 3, hv.w * nrm);
}

// ---------------- BN ----------------
__global__ void bn_stats_k(const float* __restrict__ x, int n,
                           float* __restrict__ sum, float* __restrict__ sumsq) {
    int c = threadIdx.x;
    int r0 = blockIdx.x * 128;
    int rend = min(r0 + 128, n);
    float s = 0.f, qq = 0.f;
    for (int r = r0; r < rend; ++r) {
        float v = x[(size_t)r * NF + c];
        s += v; qq += v * v;
    }
    atomicAdd(&sum[c], s);
    atomicAdd(&sumsq[c], qq);
}
__global__ void bn_stats_cat_k(const float* __restrict__ xa, const float* __restrict__ xb,
                               int n, float* __restrict__ sum, float* __restrict__ sumsq) {
    int c = threadIdx.x;  // 512
    int r0 = blockIdx.x * 128;
    int rend = min(r0 + 128, n);
    const float* src = (c < 256) ? xa : xb;
    int cc = c & 255;
    float s = 0.f, qq = 0.f;
    for (int r = r0; r < rend; ++r) {
        float v = src[(size_t)r * NF + cc];
        s += v; qq += v * v;
    }
    atomicAdd(&sum[c], s);
    atomicAdd(&sumsq[c], qq);
}
__global__ void bn_fin_k(float* __restrict__ st, int n, int C) {
    int c = blockIdx.x * 256 + threadIdx.x;
    if (c >= C) return;
    float inv_n = 1.0f / (float)n;
    float mean = st[c] * inv_n;
    float var = fmaxf(st[C + c] * inv_n - mean * mean, 0.f);
    st[c] = mean;
    st[C + c] = rsqrtf(var + EPSV);
}
__global__ void bn_apply_k(const float* __restrict__ x, const float* __restrict__ st,
                           const float* __restrict__ g, const float* __restrict__ be,
                           float* __restrict__ out, int n) {
    int t = blockIdx.x * 256 + threadIdx.x;
    if (t >= n * NF) return;
    int c = t & 255;
    float v = (x[t] - st[c]) * st[256 + c] * g[c] + be[c];
    out[t] = fmaxf(v, 0.f);
}

// ---------------- GAT ----------------
__global__ void gat_scores_k(const float* __restrict__ h, const float* __restrict__ as_,
                             const float* __restrict__ ad_, float* __restrict__ es,
                             float* __restrict__ ed, int n) {
    int wave = threadIdx.x >> 6, lane = threadIdx.x & 63;
    int i = blockIdx.x * 4 + wave;
    if (i >= n) return;
    int c = lane * 4;
    float4 hv = *(const float4*)(h + (size_t)i * NF + c);
    float s1 = hv.x * as_[c] + hv.y * as_[c + 1] + hv.z * as_[c + 2] + hv.w * as_[c + 3];
    float s2 = hv.x * ad_[c] + hv.y * ad_[c + 1] + hv.z * ad_[c + 2] + hv.w * ad_[c + 3];
#pragma unroll
    for (int off = 32; off > 0; off >>= 1) {
        s1 += __shfl_down(s1, off, 64);
        s2 += __shfl_down(s2, off, 64);
    }
    if (lane == 0) { es[i] = s1; ed[i] = s2; }
}
__global__ void gat_minit_k(const float* __restrict__ es, const float* __restrict__ ed,
                            float* __restrict__ mb, int n) {
    int i = blockIdx.x * 256 + threadIdx.x;
    if (i < n) mb[i] = lrelu(es[i] + ed[i]);
}
__global__ void gat_emax_k(const int* __restrict__ ei, int E, const float* __restrict__ es,
                           const float* __restrict__ ed, float* __restrict__ mb) {
    int e = blockIdx.x * 256 + threadIdx.x;
    if (e >= E) return;
    int s = ei[e], d = ei[E + e];
    atomicMaxF(&mb[d], lrelu(es[s] + ed[d]));
}
__global__ void gat_sinit_k(const float* __restrict__ es, const float* __restrict__ ed,
                            const float* __restrict__ mb, float* __restrict__ sb, int n) {
    int i = blockIdx.x * 256 + threadIdx.x;
    if (i < n) sb[i] = expf(lrelu(es[i] + ed[i]) - mb[i]);
}
__global__ void gat_esum_k(const int* __restrict__ ei, int E, const float* __restrict__ es,
                           const float* __restrict__ ed, const float* __restrict__ mb,
                           float* __restrict__ sb) {
    int e = blockIdx.x * 256 + threadIdx.x;
    if (e >= E) return;
    int s = ei[e], d = ei[E + e];
    atomicAdd(&sb[d], expf(lrelu(es[s] + ed[d]) - mb[d]));
}
__global__ void gat_agginit_k(const float* __restrict__ h, const float* __restrict__ es,
                              const float* __restrict__ ed, const float* __restrict__ mb,
                              const float* __restrict__ sb, const float* __restrict__ b,
                              float* __restrict__ out, int n) {
    int t = blockIdx.x * 256 + threadIdx.x;
    if (t >= n * 64) return;
    int i = t >> 6, c = (t & 63) * 4;
    float al = expf(lrelu(es[i] + ed[i]) - mb[i]) / sb[i];
    float4 hv = *(const float4*)(h + (size_t)i * NF + c);
    float4 o;
    o.x = b[c + 0] + al * hv.x;
    o.y = b[c + 1] + al * hv.y;
    o.z = b[c + 2] + al * hv.z;
    o.w = b[c + 3] + al * hv.w;
    *(float4*)(out + (size_t)i * NF + c) = o;
}
__global__ void gat_aggedge_k(const float* __restrict__ h, const int* __restrict__ ei, int E,
                              const float* __restrict__ es, const float* __restrict__ ed,
                              const float* __restrict__ mb, const float* __restrict__ sb,
                              float* __restrict__ out) {
    int t = blockIdx.x * 256 + threadIdx.x;
    if (t >= E * 64) return;
    int e = t >> 6, c = (t & 63) * 4;
    int s = ei[e], d = ei[E + e];
    float al = expf(lrelu(es[s] + ed[d]) - mb[d]) / sb[d];
    float4 hv = *(const float4*)(h + (size_t)s * NF + c);
    float* o = out + (size_t)d * NF + c;
    atomicAdd(o + 0, hv.x * al);
    atomicAdd(o + 1, hv.y * al);
    atomicAdd(o + 2, hv.z * al);
    atomicAdd(o + 3, hv.w * al);
}

// ---------------- final: relu(bn(cat(x,h))) @ w + bias -> fp32 ----------------
__global__ void final_k(const float* __restrict__ xp, const float* __restrict__ hp,
                        const float* __restrict__ st, const float* __restrict__ g,
                        const float* __restrict__ be, const float* __restrict__ w,
                        const float* __restrict__ bias, float* __restrict__ out, int n) {
    int wave = threadIdx.x >> 6, lane = threadIdx.x & 63;
    int i = blockIdx.x * 4 + wave;
    if (i >= n) return;
    const float* src = (lane < 32) ? (xp + (size_t)i * NF + lane * 8)
                                   : (hp + (size_t)i * NF + (lane - 32) * 8);
    int c0 = lane * 8;
    float acc = 0.f;
#pragma unroll
    for (int j = 0; j < 8; ++j) {
        int c = c0 + j;
        float v = (src[j] - st[c]) * st[512 + c] * g[c] + be[c];
        v = fmaxf(v, 0.f);
        acc += v * w[c];
    }
#pragma unroll
    for (int off = 32; off > 0; off >>= 1) acc += __shfl_down(acc, off, 64);
    if (lane == 0) out[i] = acc + bias[0];   // fp32 output — reference returns float32
}

// ---------------- host ----------------
extern "C" void kernel_launch(void* const* d_in, const int* in_sizes, int n_in,
                              void* d_out, int out_size, void* d_ws, size_t ws_size,
                              hipStream_t stream) {
    const void* x_ab = d_in[0];
    const void* x_ag = d_in[1];
    const void* W_gcn = d_in[2];
    const void* b_gcn = d_in[3];
    const void* g1 = d_in[4];
    const void* be1 = d_in[5];
    const void* W_aggcn = d_in[6];
    const void* b_aggcn = d_in[7];
    const void* ag_g1 = d_in[8];
    const void* ag_be1 = d_in[9];
    const void* W_gat = d_in[10];
    const void* a_src = d_in[11];
    const void* a_dst = d_in[12];
    const void* b_gat = d_in[13];
    const void* W_gat2 = d_in[14];
    const void* a_src2 = d_in[15];
    const void* a_dst2 = d_in[16];
    const void* b_gat2 = d_in[17];
    const void* ag_g2 = d_in[18];
    const void* ag_be2 = d_in[19];
    const void* W_agfc = d_in[20];
    const void* b_agfc = d_in[21];
    const void* g2 = d_in[22];
    const void* be2 = d_in[23];
    const void* W_fc = d_in[24];
    const void* b_fc = d_in[25];
    const int* e_ab = (const int*)d_in[26];
    const int* e_ag = (const int*)d_in[27];
    const int* e_d = (const int*)d_in[28];

    const int NAB = 20000, NAG = 20000, NT = 40000;
    const int EAB = 320000, EAG = 320000, ED = 640000;

    float* hcat = (float*)d_ws;                 // NT*NF
    float* bufA = hcat + (size_t)NT * NF;
    float* bufB = bufA + (size_t)NT * NF;
    float* dinv = bufB + (size_t)NT * NF;       // NT
    float* es = dinv + NT;
    float* edv = es + NT;
    float* mb = edv + NT;
    float* sb = mb + NT;
    float* st = sb + NT;                        // 2048
    float* prm = st + 2048;                     // 8192
    int* flag = (int*)(prm + 8192);             // 16

    dim3 t256(256), t512(512);

    // dtype detect + param conversion
    detect_k<<<dim3(1), t256, 0, stream>>>((const u16*)x_ab, flag);
    auto cvt = [&](const void* s, int off, int n) {
        cvt_k<<<dim3((n + 255) / 256), t256, 0, stream>>>(s, prm + off, n, flag);
    };
    cvt(b_gcn, P_BGCN, 256);  cvt(g1, P_G1, 256);        cvt(be1, P_BE1, 256);
    cvt(b_aggcn, P_BAGG, 256); cvt(ag_g1, P_AGG1, 256);  cvt(ag_be1, P_AGBE1, 256);
    cvt(a_src, P_ASRC, 256);  cvt(a_dst, P_ADST, 256);   cvt(b_gat, P_BGAT, 256);
    cvt(a_src2, P_ASRC2, 256); cvt(a_dst2, P_ADST2, 256); cvt(b_gat2, P_BGAT2, 256);
    cvt(g2, P_G2, 512);       cvt(be2, P_BE2, 512);      cvt(W_fc, P_WFC, 512);
    cvt(ag_g2, P_AGG2, 512);  cvt(ag_be2, P_AGBE2, 512); cvt(W_agfc, P_WAGFC, 512);
    cvt(b_fc, P_BFC, 1);      cvt(b_agfc, P_BAGFC, 1);

    auto gcn = [&](const void* x, const void* W, int pb, int pg, int pbe,
                   const int* ei, int E, int n, float* hout) {
        gemm8_k<<<dim3((n + 7) / 8), t256, 0, stream>>>(x, 2, W, flag, bufA, n);
        fill_k<<<dim3((n + 255) / 256), t256, 0, stream>>>(dinv, 1.0f, n);
        deg_k<<<dim3((E + 255) / 256), t256, 0, stream>>>(ei + E, E, dinv);
        rsqrt_k<<<dim3((n + 255) / 256), t256, 0, stream>>>(dinv, n);
        gcn_init_k<<<dim3((n * 64 + 255) / 256), t256, 0, stream>>>(bufA, dinv, prm + pb, bufB, n);
        gcn_edge_k<<<dim3((E * 64 + 255) / 256), t256, 0, stream>>>(bufA, dinv, ei, E, bufB);
        fill_k<<<dim3(4), t256, 0, stream>>>(st, 0.f, 1024);
        bn_stats_k<<<dim3((n + 127) / 128), t256, 0, stream>>>(bufB, n, st, st + 256);
        bn_fin_k<<<dim3(1), t256, 0, stream>>>(st, n, 256);
        bn_apply_k<<<dim3(n), t256, 0, stream>>>(bufB, st, prm + pg, prm + pbe, hout, n);
    };

    auto gat = [&](const float* xin, const void* W, int pas, int pad, int pb,
                   int do_relu, float* xout) {
        gemm8_k<<<dim3((NT + 7) / 8), t256, 0, stream>>>((const void*)xin, 0, W, flag, bufA, NT);
        gat_scores_k<<<dim3((NT + 3) / 4), t256, 0, stream>>>(bufA, prm + pas, prm + pad, es, edv, NT);
        gat_minit_k<<<dim3((NT + 255) / 256), t256, 0, stream>>>(es, edv, mb, NT);
        gat_emax_k<<<dim3((ED + 255) / 256), t256, 0, stream>>>(e_d, ED, es, edv, mb);
        gat_sinit_k<<<dim3((NT + 255) / 256), t256, 0, stream>>>(es, edv, mb, sb, NT);
        gat_esum_k<<<dim3((ED + 255) / 256), t256, 0, stream>>>(e_d, ED, es, edv, mb, sb);
        gat_agginit_k<<<dim3((NT * 64 + 255) / 256), t256, 0, stream>>>(bufA, es, edv, mb, sb, prm + pb, xout, NT);
        gat_aggedge_k<<<dim3(ED / 4), t256, 0, stream>>>(bufA, e_d, ED, es, edv, mb, sb, xout);
        if (do_relu) relu_k<<<dim3((NT * NF + 255) / 256), t256, 0, stream>>>(xout, NT * NF);
    };

    auto finstage = [&](const float* xp, const float* hp, int pg, int pbe,
                        int pw, int pbias, float* outp, int n) {
        fill_k<<<dim3(4), t256, 0, stream>>>(st, 0.f, 1024);
        bn_stats_cat_k<<<dim3((n + 127) / 128), t512, 0, stream>>>(xp, hp, n, st, st + 512);
        bn_fin_k<<<dim3(2), t256, 0, stream>>>(st, n, 512);
        final_k<<<dim3((n + 3) / 4), t256, 0, stream>>>(xp, hp, st, prm + pg, prm + pbe,
                                                        prm + pw, prm + pbias, outp, n);
    };

    gcn(x_ab, W_gcn, P_BGCN, P_G1, P_BE1, e_ab, EAB, NAB, hcat);
    gcn(x_ag, W_aggcn, P_BAGG, P_AGG1, P_AGBE1, e_ag, EAG, NAG, hcat + (size_t)NAB * NF);
    gat(hcat, W_gat, P_ASRC, P_ADST, P_BGAT, 1, bufB);
    gat(bufB, W_gat2, P_ASRC2, P_ADST2, P_BGAT2, 0, bufB);
    float* outp = (float*)d_out;
    finstage(bufB, hcat, P_G2, P_BE2, P_WFC, P_BFC, outp, NAB);
    finstage(bufB + (size_t)NAB * NF, hcat + (size_t)NAB * NF, P_AGG2, P_AGBE2,
             P_WAGFC, P_BAGFC, outp + NAB, NAG);
}

// Round 5
// 1605.505 us; speedup vs baseline: 4.7070x; 4.7070x over previous
//
#include <hip/hip_runtime.h>
#include <hip/hip_bf16.h>
#include <stdint.h>

#define NF 256
#define EPSV 1e-5f

typedef unsigned short u16;

// param block offsets (floats)
#define P_BGCN 0
#define P_G1 256
#define P_BE1 512
#define P_BAGG 768
#define P_AGG1 1024
#define P_AGBE1 1280
#define P_ASRC 1536
#define P_ADST 1792
#define P_BGAT 2048
#define P_ASRC2 2304
#define P_ADST2 2560
#define P_BGAT2 2816
#define P_G2 3072
#define P_BE2 3584
#define P_WFC 4096
#define P_AGG2 4608
#define P_AGBE2 5120
#define P_WAGFC 5632
#define P_BFC 6144
#define P_BAGFC 6145

__device__ __forceinline__ float bf2f(u16 u) {
    union { unsigned int i; float f; } v; v.i = ((unsigned int)u) << 16; return v.f;
}
__device__ __forceinline__ float sane(float f) {
    return (f == f && fabsf(f) < 1e30f) ? f : 0.f;
}
__device__ __forceinline__ float lrelu(float x) { return x > 0.f ? x : 0.2f * x; }

__device__ __forceinline__ float wredmax(float v) {
#pragma unroll
    for (int o = 32; o > 0; o >>= 1) v = fmaxf(v, __shfl_xor(v, o, 64));
    return v;
}
__device__ __forceinline__ float wredsum(float v) {
#pragma unroll
    for (int o = 32; o > 0; o >>= 1) v += __shfl_xor(v, o, 64);
    return v;
}

// ---------------- dtype detect: flag=1 -> float inputs are bf16, 0 -> fp32 ----------------
__global__ void detect_k(const u16* __restrict__ x, int* __restrict__ flag) {
    __shared__ int cnt;
    if (threadIdx.x == 0) cnt = 0;
    __syncthreads();
    int c = 0;
#pragma unroll
    for (int k = 0; k < 4; ++k) {
        unsigned int u = x[2 * (threadIdx.x + 256 * k)];
        int e = (int)((u >> 7) & 0xFFu);
        if (u == 0u || (e >= 100 && e <= 140)) c++;
    }
    atomicAdd(&cnt, c);
    __syncthreads();
    if (threadIdx.x == 0) flag[0] = (cnt >= 512) ? 1 : 0;
}

__global__ void cvt_k(const void* __restrict__ src, float* __restrict__ dst, int n,
                      const int* __restrict__ flagp) {
    int i = blockIdx.x * 256 + threadIdx.x;
    if (i >= n) return;
    float v = flagp[0] ? bf2f(((const u16*)src)[i]) : ((const float*)src)[i];
    dst[i] = sane(v);
}

// ---------------- utility ----------------
__global__ void fill_k(float* __restrict__ p, float v, int n) {
    int i = blockIdx.x * 256 + threadIdx.x;
    if (i < n) p[i] = v;
}
__global__ void zero_i_k(int* __restrict__ p, int n) {
    int i = blockIdx.x * 256 + threadIdx.x;
    if (i < n) p[i] = 0;
}

// ---------------- CSR build ----------------
__global__ void cnt_k(const int* __restrict__ dst, int E, int* __restrict__ cnt) {
    int e = blockIdx.x * 256 + threadIdx.x;
    if (e < E) atomicAdd(&cnt[dst[e]], 1);
}
// single-block exclusive scan: rp[0..n-1] = exclusive prefix of cnt, rp[n] = total
__global__ __launch_bounds__(256) void scan_k(const int* __restrict__ cnt,
                                              int* __restrict__ rp, int n) {
    __shared__ int wpart[4];
    __shared__ int sbase;
    int lane = threadIdx.x & 63, wave = threadIdx.x >> 6;
    if (threadIdx.x == 0) sbase = 0;
    __syncthreads();
    for (int c0 = 0; c0 < n; c0 += 256) {
        int i = c0 + threadIdx.x;
        int v = (i < n) ? cnt[i] : 0;
        int x = v;
#pragma unroll
        for (int o = 1; o < 64; o <<= 1) {
            int t = __shfl_up(x, o, 64);
            if (lane >= o) x += t;
        }
        if (lane == 63) wpart[wave] = x;
        __syncthreads();
        int woff = 0;
#pragma unroll
        for (int w = 0; w < 4; ++w) woff += (w < wave) ? wpart[w] : 0;
        int total = wpart[0] + wpart[1] + wpart[2] + wpart[3];
        if (i < n) rp[i] = sbase + woff + x - v;
        __syncthreads();
        if (threadIdx.x == 0) sbase += total;
        __syncthreads();
    }
    if (threadIdx.x == 0) rp[n] = sbase;
}
__global__ void scatter_k(const int* __restrict__ ei, int E, const int* __restrict__ rp,
                          int* __restrict__ cur, int* __restrict__ col) {
    int e = blockIdx.x * 256 + threadIdx.x;
    if (e >= E) return;
    int s = ei[e], d = ei[E + e];
    int p = atomicAdd(&cur[d], 1);
    col[rp[d] + p] = s;
}
// dinv[i] = rsqrt(indeg+1)
__global__ void dinv_k(const int* __restrict__ rp, float* __restrict__ dinv, int n) {
    int i = blockIdx.x * 256 + threadIdx.x;
    if (i < n) dinv[i] = rsqrtf((float)(rp[i + 1] - rp[i] + 1));
}

// ---------------- simple GEMM: C(Mx256) = A(Mx256) @ W(256x256) ----------------
__global__ __launch_bounds__(256) void gemm8_k(const void* __restrict__ Aptr, int amode,
                                               const void* __restrict__ Wptr,
                                               const int* __restrict__ flagp,
                                               float* __restrict__ C, int M) {
    __shared__ float As[8][256];
    int f = flagp[0];
    int abf = (amode == 2) ? f : 0;
    int r0 = blockIdx.x * 8;
    int j = threadIdx.x;
#pragma unroll
    for (int rr = 0; rr < 8; ++rr) {
        int r = r0 + rr;
        float v = 0.f;
        if (r < M) {
            v = abf ? bf2f(((const u16*)Aptr)[(size_t)r * NF + j])
                    : ((const float*)Aptr)[(size_t)r * NF + j];
        }
        As[rr][j] = sane(v);
    }
    __syncthreads();
    float a0 = 0.f, a1 = 0.f, a2 = 0.f, a3 = 0.f;
    float a4 = 0.f, a5 = 0.f, a6 = 0.f, a7 = 0.f;
    for (int k = 0; k < 256; ++k) {
        float w = f ? bf2f(((const u16*)Wptr)[k * NF + j]) : ((const float*)Wptr)[k * NF + j];
        w = sane(w);
        a0 += As[0][k] * w;
        a1 += As[1][k] * w;
        a2 += As[2][k] * w;
        a3 += As[3][k] * w;
        a4 += As[4][k] * w;
        a5 += As[5][k] * w;
        a6 += As[6][k] * w;
        a7 += As[7][k] * w;
    }
    float acc[8] = {a0, a1, a2, a3, a4, a5, a6, a7};
#pragma unroll
    for (int rr = 0; rr < 8; ++rr) {
        if (r0 + rr < M) C[(size_t)(r0 + rr) * NF + j] = acc[rr];
    }
}

// ---------------- GCN via CSR: one wave per node ----------------
__global__ __launch_bounds__(256) void gcn_csr_k(const float* __restrict__ h,
                                                 const int* __restrict__ rp,
                                                 const int* __restrict__ col,
                                                 const float* __restrict__ dinv,
                                                 const float* __restrict__ b,
                                                 float* __restrict__ out, int n) {
    int wave = threadIdx.x >> 6, lane = threadIdx.x & 63;
    int i = blockIdx.x * 4 + wave;
    if (i >= n) return;
    int c = lane * 4;
    int beg = rp[i], end = rp[i + 1];
    float di = dinv[i];
    float4 hv = *(const float4*)(h + (size_t)i * NF + c);
    float w = di * di;
    float4 acc;
    acc.x = hv.x * w + b[c + 0];
    acc.y = hv.y * w + b[c + 1];
    acc.z = hv.z * w + b[c + 2];
    acc.w = hv.w * w + b[c + 3];
    for (int j = beg; j < end; ++j) {
        int s = col[j];
        float nrm = dinv[s] * di;
        float4 hs = *(const float4*)(h + (size_t)s * NF + c);
        acc.x += hs.x * nrm;
        acc.y += hs.y * nrm;
        acc.z += hs.z * nrm;
        acc.w += hs.w * nrm;
    }
    *(float4*)(out + (size_t)i * NF + c) = acc;
}

// ---------------- BN ----------------
__global__ void bn_stats_k(const float* __restrict__ x, int n,
                           float* __restrict__ sum, float* __restrict__ sumsq) {
    int c = threadIdx.x;
    int r0 = blockIdx.x * 128;
    int rend = min(r0 + 128, n);
    float s = 0.f, qq = 0.f;
    for (int r = r0; r < rend; ++r) {
        float v = x[(size_t)r * NF + c];
        s += v; qq += v * v;
    }
    atomicAdd(&sum[c], s);
    atomicAdd(&sumsq[c], qq);
}
__global__ void bn_stats_cat_k(const float* __restrict__ xa, const float* __restrict__ xb,
                               int n, float* __restrict__ sum, float* __restrict__ sumsq) {
    int c = threadIdx.x;  // 512
    int r0 = blockIdx.x * 128;
    int rend = min(r0 + 128, n);
    const float* src = (c < 256) ? xa : xb;
    int cc = c & 255;
    float s = 0.f, qq = 0.f;
    for (int r = r0; r < rend; ++r) {
        float v = src[(size_t)r * NF + cc];
        s += v; qq += v * v;
    }
    atomicAdd(&sum[c], s);
    atomicAdd(&sumsq[c], qq);
}
__global__ void bn_fin_k(float* __restrict__ st, int n, int C) {
    int c = blockIdx.x * 256 + threadIdx.x;
    if (c >= C) return;
    float inv_n = 1.0f / (float)n;
    float mean = st[c] * inv_n;
    float var = fmaxf(st[C + c] * inv_n - mean * mean, 0.f);
    st[c] = mean;
    st[C + c] = rsqrtf(var + EPSV);
}
__global__ void bn_apply_k(const float* __restrict__ x, const float* __restrict__ st,
                           const float* __restrict__ g, const float* __restrict__ be,
                           float* __restrict__ out, int n) {
    int t = blockIdx.x * 256 + threadIdx.x;
    if (t >= n * NF) return;
    int c = t & 255;
    float v = (x[t] - st[c]) * st[256 + c] * g[c] + be[c];
    out[t] = fmaxf(v, 0.f);
}

// ---------------- GAT scores: es[i]=h[i]@a_src, ed[i]=h[i]@a_dst ----------------
__global__ void gat_scores_k(const float* __restrict__ h, const float* __restrict__ as_,
                             const float* __restrict__ ad_, float* __restrict__ es,
                             float* __restrict__ ed, int n) {
    int wave = threadIdx.x >> 6, lane = threadIdx.x & 63;
    int i = blockIdx.x * 4 + wave;
    if (i >= n) return;
    int c = lane * 4;
    float4 hv = *(const float4*)(h + (size_t)i * NF + c);
    float s1 = hv.x * as_[c] + hv.y * as_[c + 1] + hv.z * as_[c + 2] + hv.w * as_[c + 3];
    float s2 = hv.x * ad_[c] + hv.y * ad_[c + 1] + hv.z * ad_[c + 2] + hv.w * ad_[c + 3];
    s1 = wredsum(s1);
    s2 = wredsum(s2);
    if (lane == 0) { es[i] = s1; ed[i] = s2; }
}

// ---------------- fused GAT aggregation via CSR: one wave per node ----------------
__global__ __launch_bounds__(256) void gat_csr_k(const float* __restrict__ h,
                                                 const int* __restrict__ rp,
                                                 const int* __restrict__ col,
                                                 const float* __restrict__ es,
                                                 const float* __restrict__ ed,
                                                 const float* __restrict__ b,
                                                 float* __restrict__ out, int n,
                                                 int do_relu) {
    int wave = threadIdx.x >> 6, lane = threadIdx.x & 63;
    int i = blockIdx.x * 4 + wave;
    if (i >= n) return;
    int beg = rp[i], end = rp[i + 1];
    float edi = ed[i];
    float eself = lrelu(es[i] + edi);
    // pass 1: max (self + in-edges, striped over lanes)
    float m = eself;
    for (int j = beg + lane; j < end; j += 64) m = fmaxf(m, lrelu(es[col[j]] + edi));
    m = wredmax(m);
    // pass 2: sum of exp
    float ssum = (lane == 0) ? __expf(eself - m) : 0.f;
    for (int j = beg + lane; j < end; j += 64) ssum += __expf(lrelu(es[col[j]] + edi) - m);
    ssum = wredsum(ssum);
    float inv = 1.0f / ssum;
    // pass 3: aggregate features
    int c = lane * 4;
    float al = __expf(eself - m) * inv;
    float4 hv = *(const float4*)(h + (size_t)i * NF + c);
    float4 acc;
    acc.x = b[c + 0] + al * hv.x;
    acc.y = b[c + 1] + al * hv.y;
    acc.z = b[c + 2] + al * hv.z;
    acc.w = b[c + 3] + al * hv.w;
    for (int j = beg; j < end; ++j) {
        int s = col[j];
        float a = __expf(lrelu(es[s] + edi) - m) * inv;
        float4 hs = *(const float4*)(h + (size_t)s * NF + c);
        acc.x += a * hs.x;
        acc.y += a * hs.y;
        acc.z += a * hs.z;
        acc.w += a * hs.w;
    }
    if (do_relu) {
        acc.x = fmaxf(acc.x, 0.f); acc.y = fmaxf(acc.y, 0.f);
        acc.z = fmaxf(acc.z, 0.f); acc.w = fmaxf(acc.w, 0.f);
    }
    *(float4*)(out + (size_t)i * NF + c) = acc;
}

// ---------------- final: relu(bn(cat(x,h))) @ w + bias -> fp32 ----------------
__global__ void final_k(const float* __restrict__ xp, const float* __restrict__ hp,
                        const float* __restrict__ st, const float* __restrict__ g,
                        const float* __restrict__ be, const float* __restrict__ w,
                        const float* __restrict__ bias, float* __restrict__ out, int n) {
    int wave = threadIdx.x >> 6, lane = threadIdx.x & 63;
    int i = blockIdx.x * 4 + wave;
    if (i >= n) return;
    const float* src = (lane < 32) ? (xp + (size_t)i * NF + lane * 8)
                                   : (hp + (size_t)i * NF + (lane - 32) * 8);
    int c0 = lane * 8;
    float acc = 0.f;
#pragma unroll
    for (int j = 0; j < 8; ++j) {
        int c = c0 + j;
        float v = (src[j] - st[c]) * st[512 + c] * g[c] + be[c];
        v = fmaxf(v, 0.f);
        acc += v * w[c];
    }
    acc = wredsum(acc);
    if (lane == 0) out[i] = acc + bias[0];
}

// ---------------- host ----------------
extern "C" void kernel_launch(void* const* d_in, const int* in_sizes, int n_in,
                              void* d_out, int out_size, void* d_ws, size_t ws_size,
                              hipStream_t stream) {
    const void* x_ab = d_in[0];
    const void* x_ag = d_in[1];
    const void* W_gcn = d_in[2];
    const void* b_gcn = d_in[3];
    const void* g1 = d_in[4];
    const void* be1 = d_in[5];
    const void* W_aggcn = d_in[6];
    const void* b_aggcn = d_in[7];
    const void* ag_g1 = d_in[8];
    const void* ag_be1 = d_in[9];
    const void* W_gat = d_in[10];
    const void* a_src = d_in[11];
    const void* a_dst = d_in[12];
    const void* b_gat = d_in[13];
    const void* W_gat2 = d_in[14];
    const void* a_src2 = d_in[15];
    const void* a_dst2 = d_in[16];
    const void* b_gat2 = d_in[17];
    const void* ag_g2 = d_in[18];
    const void* ag_be2 = d_in[19];
    const void* W_agfc = d_in[20];
    const void* b_agfc = d_in[21];
    const void* g2 = d_in[22];
    const void* be2 = d_in[23];
    const void* W_fc = d_in[24];
    const void* b_fc = d_in[25];
    const int* e_ab = (const int*)d_in[26];
    const int* e_ag = (const int*)d_in[27];
    const int* e_d = (const int*)d_in[28];

    const int NAB = 20000, NAG = 20000, NT = 40000;
    const int EAB = 320000, EAG = 320000, ED = 640000;

    float* hcat = (float*)d_ws;                 // NT*NF
    float* bufA = hcat + (size_t)NT * NF;       // NT*NF
    float* bufB = bufA + (size_t)NT * NF;       // NT*NF
    float* dinv = bufB + (size_t)NT * NF;       // NT
    float* es = dinv + NT;                      // NT
    float* edv = es + NT;                       // NT
    float* st = edv + NT;                       // 2048
    float* prm = st + 2048;                     // 8192
    int* flag = (int*)(prm + 8192);             // 16
    int* rp_ab = flag + 16;                     // NAB+1
    int* rp_ag = rp_ab + NAB + 1;               // NAG+1
    int* rp_d = rp_ag + NAG + 1;                // NT+1
    int* cnt = rp_d + NT + 1;                   // NT+1
    int* col_ab = cnt + NT + 1;                 // EAB
    int* col_ag = col_ab + EAB;                 // EAG
    int* col_d = col_ag + EAG;                  // ED

    dim3 t256(256), t512(512);

    // dtype detect + param conversion
    detect_k<<<dim3(1), t256, 0, stream>>>((const u16*)x_ab, flag);
    auto cvt = [&](const void* s, int off, int n) {
        cvt_k<<<dim3((n + 255) / 256), t256, 0, stream>>>(s, prm + off, n, flag);
    };
    cvt(b_gcn, P_BGCN, 256);  cvt(g1, P_G1, 256);        cvt(be1, P_BE1, 256);
    cvt(b_aggcn, P_BAGG, 256); cvt(ag_g1, P_AGG1, 256);  cvt(ag_be1, P_AGBE1, 256);
    cvt(a_src, P_ASRC, 256);  cvt(a_dst, P_ADST, 256);   cvt(b_gat, P_BGAT, 256);
    cvt(a_src2, P_ASRC2, 256); cvt(a_dst2, P_ADST2, 256); cvt(b_gat2, P_BGAT2, 256);
    cvt(g2, P_G2, 512);       cvt(be2, P_BE2, 512);      cvt(W_fc, P_WFC, 512);
    cvt(ag_g2, P_AGG2, 512);  cvt(ag_be2, P_AGBE2, 512); cvt(W_agfc, P_WAGFC, 512);
    cvt(b_fc, P_BFC, 1);      cvt(b_agfc, P_BAGFC, 1);

    // CSR build for the three graphs
    auto build_csr = [&](const int* ei, int E, int n, int* rp, int* col) {
        zero_i_k<<<dim3((n + 256) / 256), t256, 0, stream>>>(cnt, n + 1);
        cnt_k<<<dim3((E + 255) / 256), t256, 0, stream>>>(ei + E, E, cnt);
        scan_k<<<dim3(1), t256, 0, stream>>>(cnt, rp, n);
        zero_i_k<<<dim3((n + 256) / 256), t256, 0, stream>>>(cnt, n + 1);
        scatter_k<<<dim3((E + 255) / 256), t256, 0, stream>>>(ei, E, rp, cnt, col);
    };
    build_csr(e_ab, EAB, NAB, rp_ab, col_ab);
    build_csr(e_ag, EAG, NAG, rp_ag, col_ag);
    build_csr(e_d, ED, NT, rp_d, col_d);

    auto gcn = [&](const void* x, const void* W, const int* rp, const int* col,
                   int pb, int pg, int pbe, int n, float* hout) {
        gemm8_k<<<dim3((n + 7) / 8), t256, 0, stream>>>(x, 2, W, flag, bufA, n);
        dinv_k<<<dim3((n + 255) / 256), t256, 0, stream>>>(rp, dinv, n);
        gcn_csr_k<<<dim3((n + 3) / 4), t256, 0, stream>>>(bufA, rp, col, dinv, prm + pb, bufB, n);
        fill_k<<<dim3(4), t256, 0, stream>>>(st, 0.f, 1024);
        bn_stats_k<<<dim3((n + 127) / 128), t256, 0, stream>>>(bufB, n, st, st + 256);
        bn_fin_k<<<dim3(1), t256, 0, stream>>>(st, n, 256);
        bn_apply_k<<<dim3(n), t256, 0, stream>>>(bufB, st, prm + pg, prm + pbe, hout, n);
    };

    auto gat = [&](const float* xin, const void* W, int pas, int pad, int pb,
                   int do_relu, float* xout) {
        gemm8_k<<<dim3((NT + 7) / 8), t256, 0, stream>>>((const void*)xin, 0, W, flag, bufA, NT);
        gat_scores_k<<<dim3((NT + 3) / 4), t256, 0, stream>>>(bufA, prm + pas, prm + pad, es, edv, NT);
        gat_csr_k<<<dim3((NT + 3) / 4), t256, 0, stream>>>(bufA, rp_d, col_d, es, edv,
                                                           prm + pb, xout, NT, do_relu);
    };

    auto finstage = [&](const float* xp, const float* hp, int pg, int pbe,
                        int pw, int pbias, float* outp, int n) {
        fill_k<<<dim3(4), t256, 0, stream>>>(st, 0.f, 1024);
        bn_stats_cat_k<<<dim3((n + 127) / 128), t512, 0, stream>>>(xp, hp, n, st, st + 512);
        bn_fin_k<<<dim3(2), t256, 0, stream>>>(st, n, 512);
        final_k<<<dim3((n + 3) / 4), t256, 0, stream>>>(xp, hp, st, prm + pg, prm + pbe,
                                                        prm + pw, prm + pbias, outp, n);
    };

    gcn(x_ab, W_gcn, rp_ab, col_ab, P_BGCN, P_G1, P_BE1, NAB, hcat);
    gcn(x_ag, W_aggcn, rp_ag, col_ag, P_BAGG, P_AGG1, P_AGBE1, NAG, hcat + (size_t)NAB * NF);
    gat(hcat, W_gat, P_ASRC, P_ADST, P_BGAT, 1, bufB);
    gat(bufB, W_gat2, P_ASRC2, P_ADST2, P_BGAT2, 0, bufB);
    float* outp = (float*)d_out;
    finstage(bufB, hcat, P_G2, P_BE2, P_WFC, P_BFC, outp, NAB);
    finstage(bufB + (size_t)NAB * NF, hcat + (size_t)NAB * NF, P_AGG2, P_AGBE2,
             P_WAGFC, P_BAGFC, outp + NAB, NAG);
}

// Round 6
// 1279.318 us; speedup vs baseline: 5.9071x; 1.2550x over previous
//
#include <hip/hip_runtime.h>
#include <hip/hip_bf16.h>
#include <stdint.h>

#define NF 256
#define EPSV 1e-5f

typedef unsigned short u16;
typedef short short8 __attribute__((ext_vector_type(8)));
typedef float floatx4 __attribute__((ext_vector_type(4)));

// param block offsets (floats)
#define P_BGCN 0
#define P_G1 256
#define P_BE1 512
#define P_BAGG 768
#define P_AGG1 1024
#define P_AGBE1 1280
#define P_ASRC 1536
#define P_ADST 1792
#define P_BGAT 2048
#define P_ASRC2 2304
#define P_ADST2 2560
#define P_BGAT2 2816
#define P_G2 3072
#define P_BE2 3584
#define P_WFC 4096
#define P_AGG2 4608
#define P_AGBE2 5120
#define P_WAGFC 5632
#define P_BFC 6144
#define P_BAGFC 6145

__device__ __forceinline__ float bf2f(u16 u) {
    union { unsigned int i; float f; } v; v.i = ((unsigned int)u) << 16; return v.f;
}
__device__ __forceinline__ u16 f2bf(float f) {
    unsigned int x = __float_as_uint(f);
    unsigned int r = x + 0x7fffu + ((x >> 16) & 1u);
    return (u16)(r >> 16);
}
__device__ __forceinline__ float sane(float f) {
    return (f == f && fabsf(f) < 1e30f) ? f : 0.f;
}
__device__ __forceinline__ unsigned int zap2(unsigned int w) {
    if ((w & 0x00007F80u) == 0x00007F80u) w &= 0xFFFF0000u;
    if ((w & 0x7F800000u) == 0x7F800000u) w &= 0x0000FFFFu;
    return w;
}
__device__ __forceinline__ float lrelu(float x) { return x > 0.f ? x : 0.2f * x; }

__device__ __forceinline__ float wredmax(float v) {
#pragma unroll
    for (int o = 32; o > 0; o >>= 1) v = fmaxf(v, __shfl_xor(v, o, 64));
    return v;
}
__device__ __forceinline__ float wredsum(float v) {
#pragma unroll
    for (int o = 32; o > 0; o >>= 1) v += __shfl_xor(v, o, 64);
    return v;
}

// ---------------- dtype detect: flag=1 -> float inputs are bf16, 0 -> fp32 ----------------
__global__ void detect_k(const u16* __restrict__ x, int* __restrict__ flag) {
    __shared__ int cnt;
    if (threadIdx.x == 0) cnt = 0;
    __syncthreads();
    int c = 0;
#pragma unroll
    for (int k = 0; k < 4; ++k) {
        unsigned int u = x[2 * (threadIdx.x + 256 * k)];
        int e = (int)((u >> 7) & 0xFFu);
        if (u == 0u || (e >= 100 && e <= 140)) c++;
    }
    atomicAdd(&cnt, c);
    __syncthreads();
    if (threadIdx.x == 0) flag[0] = (cnt >= 512) ? 1 : 0;
}

__global__ void cvt_k(const void* __restrict__ src, float* __restrict__ dst, int n,
                      const int* __restrict__ flagp) {
    int i = blockIdx.x * 256 + threadIdx.x;
    if (i >= n) return;
    float v = flagp[0] ? bf2f(((const u16*)src)[i]) : ((const float*)src)[i];
    dst[i] = sane(v);
}

// ---------------- utility ----------------
__global__ void fill_k(float* __restrict__ p, float v, int n) {
    int i = blockIdx.x * 256 + threadIdx.x;
    if (i < n) p[i] = v;
}
__global__ void zero_i_k(int* __restrict__ p, int n) {
    int i = blockIdx.x * 256 + threadIdx.x;
    if (i < n) p[i] = 0;
}

// ---------------- CSR build ----------------
__global__ void cnt_k(const int* __restrict__ dst, int E, int* __restrict__ cnt) {
    int e = blockIdx.x * 256 + threadIdx.x;
    if (e < E) atomicAdd(&cnt[dst[e]], 1);
}
__global__ __launch_bounds__(256) void scan_k(const int* __restrict__ cnt,
                                              int* __restrict__ rp, int n) {
    __shared__ int wpart[4];
    __shared__ int sbase;
    int lane = threadIdx.x & 63, wave = threadIdx.x >> 6;
    if (threadIdx.x == 0) sbase = 0;
    __syncthreads();
    for (int c0 = 0; c0 < n; c0 += 256) {
        int i = c0 + threadIdx.x;
        int v = (i < n) ? cnt[i] : 0;
        int x = v;
#pragma unroll
        for (int o = 1; o < 64; o <<= 1) {
            int t = __shfl_up(x, o, 64);
            if (lane >= o) x += t;
        }
        if (lane == 63) wpart[wave] = x;
        __syncthreads();
        int woff = 0;
#pragma unroll
        for (int w = 0; w < 4; ++w) woff += (w < wave) ? wpart[w] : 0;
        int total = wpart[0] + wpart[1] + wpart[2] + wpart[3];
        if (i < n) rp[i] = sbase + woff + x - v;
        __syncthreads();
        if (threadIdx.x == 0) sbase += total;
        __syncthreads();
    }
    if (threadIdx.x == 0) rp[n] = sbase;
}
__global__ void scatter_k(const int* __restrict__ ei, int E, const int* __restrict__ rp,
                          int* __restrict__ cur, int* __restrict__ col) {
    int e = blockIdx.x * 256 + threadIdx.x;
    if (e >= E) return;
    int s = ei[e], d = ei[E + e];
    int p = atomicAdd(&cur[d], 1);
    col[rp[d] + p] = s;
}
__global__ void dinv_k(const int* __restrict__ rp, float* __restrict__ dinv, int n) {
    int i = blockIdx.x * 256 + threadIdx.x;
    if (i < n) dinv[i] = rsqrtf((float)(rp[i + 1] - rp[i] + 1));
}

// ---------------- MFMA GEMM: C(Mx256 fp32) = A(Mx256) @ W(256x256) ----------------
// XOR-swizzled LDS, 16B granules. Verified numerically correct (R2==R3 evidence).
__device__ __forceinline__ int swz(int row, int k) {
    return row * 256 + ((((k >> 3) ^ (row & 7)) << 3) | (k & 7));
}

// amode: 2 = raw input (dtype per flag), 0 = fp32 ws buffer. W raw (dtype per flag).
__global__ __launch_bounds__(256) void gemm_mfma_k(const void* __restrict__ Aptr, int amode,
                                                   const void* __restrict__ Wptr,
                                                   const int* __restrict__ flagp,
                                                   float* __restrict__ C, int M) {
    __shared__ u16 As[64 * 256];
    __shared__ u16 Bs[64 * 256];
    int f = flagp[0];
    int abf = (amode == 2) ? f : 0;
    int row0 = blockIdx.x * 64;
    int col0 = blockIdx.y * 64;
    int tid = threadIdx.x;
    int r = tid >> 2, seg = tid & 3;
    int grow = row0 + r;
    // stage A (64 rows x 256 k), bf16
#pragma unroll
    for (int i = 0; i < 8; ++i) {
        int k = seg * 64 + i * 8;
        uint4 v = make_uint4(0u, 0u, 0u, 0u);
        if (grow < M) {
            if (abf) {
                v = *(const uint4*)((const u16*)Aptr + (size_t)grow * NF + k);
                v.x = zap2(v.x); v.y = zap2(v.y); v.z = zap2(v.z); v.w = zap2(v.w);
            } else {
                const float* A = (const float*)Aptr;
                float4 f0 = *(const float4*)(A + (size_t)grow * NF + k);
                float4 f1 = *(const float4*)(A + (size_t)grow * NF + k + 4);
                union { u16 s[8]; uint4 u; } tmp;
                tmp.s[0] = f2bf(f0.x); tmp.s[1] = f2bf(f0.y);
                tmp.s[2] = f2bf(f0.z); tmp.s[3] = f2bf(f0.w);
                tmp.s[4] = f2bf(f1.x); tmp.s[5] = f2bf(f1.y);
                tmp.s[6] = f2bf(f1.z); tmp.s[7] = f2bf(f1.w);
                v = tmp.u;
            }
        }
        *(uint4*)(As + swz(r, k)) = v;
    }
    // stage B^T: Bs row = output col n (64 of them), k contiguous. W is row-major [k][n]:
    // read W[k][col0+r] for all k — strided; instead stage via per-element reads (8 per thread
    // per iter, coalesced along n within a quarter-wave). Simpler: each thread loads 8 k's for
    // its n=r with stride NF.
#pragma unroll
    for (int i = 0; i < 8; ++i) {
        int k0 = seg * 64 + i * 8;
        union { u16 s[8]; uint4 u; } tmp;
        if (f) {
            const u16* W = (const u16*)Wptr;
#pragma unroll
            for (int j = 0; j < 8; ++j) {
                u16 w = W[(size_t)(k0 + j) * NF + col0 + r];
                // zap non-finite bf16
                if ((w & 0x7F80u) == 0x7F80u) w = 0;
                tmp.s[j] = w;
            }
        } else {
            const float* W = (const float*)Wptr;
#pragma unroll
            for (int j = 0; j < 8; ++j) tmp.s[j] = f2bf(sane(W[(size_t)(k0 + j) * NF + col0 + r]));
        }
        *(uint4*)(Bs + swz(r, k0)) = tmp.u;
    }
    __syncthreads();

    int wave = tid >> 6, lane = tid & 63;
    int m0 = wave * 16;
    int lr = lane & 15, q = lane >> 4;
    floatx4 acc[4];
#pragma unroll
    for (int nf = 0; nf < 4; ++nf) acc[nf] = (floatx4){0.f, 0.f, 0.f, 0.f};

#pragma unroll
    for (int k0 = 0; k0 < 256; k0 += 32) {
        int kk = k0 + q * 8;
        short8 a = *(const short8*)(As + swz(m0 + lr, kk));
#pragma unroll
        for (int nf = 0; nf < 4; ++nf) {
            short8 b = *(const short8*)(Bs + swz(nf * 16 + lr, kk));
            acc[nf] = __builtin_amdgcn_mfma_f32_16x16x32_bf16(a, b, acc[nf], 0, 0, 0);
        }
    }
#pragma unroll
    for (int nf = 0; nf < 4; ++nf) {
#pragma unroll
        for (int rr = 0; rr < 4; ++rr) {
            int gr = row0 + m0 + q * 4 + rr;
            if (gr < M) C[(size_t)gr * NF + col0 + nf * 16 + lr] = acc[nf][rr];
        }
    }
}

// ---------------- GCN via CSR: one wave per node ----------------
__global__ __launch_bounds__(256) void gcn_csr_k(const float* __restrict__ h,
                                                 const int* __restrict__ rp,
                                                 const int* __restrict__ col,
                                                 const float* __restrict__ dinv,
                                                 const float* __restrict__ b,
                                                 float* __restrict__ out, int n) {
    int wave = threadIdx.x >> 6, lane = threadIdx.x & 63;
    int i = blockIdx.x * 4 + wave;
    if (i >= n) return;
    int c = lane * 4;
    int beg = rp[i], end = rp[i + 1];
    float di = dinv[i];
    float4 hv = *(const float4*)(h + (size_t)i * NF + c);
    float w = di * di;
    float4 acc;
    acc.x = hv.x * w + b[c + 0];
    acc.y = hv.y * w + b[c + 1];
    acc.z = hv.z * w + b[c + 2];
    acc.w = hv.w * w + b[c + 3];
    for (int j = beg; j < end; ++j) {
        int s = col[j];
        float nrm = dinv[s] * di;
        float4 hs = *(const float4*)(h + (size_t)s * NF + c);
        acc.x += hs.x * nrm;
        acc.y += hs.y * nrm;
        acc.z += hs.z * nrm;
        acc.w += hs.w * nrm;
    }
    *(float4*)(out + (size_t)i * NF + c) = acc;
}

// ---------------- BN ----------------
__global__ void bn_stats_k(const float* __restrict__ x, int n,
                           float* __restrict__ sum, float* __restrict__ sumsq) {
    int c = threadIdx.x;
    int r0 = blockIdx.x * 128;
    int rend = min(r0 + 128, n);
    float s = 0.f, qq = 0.f;
    for (int r = r0; r < rend; ++r) {
        float v = x[(size_t)r * NF + c];
        s += v; qq += v * v;
    }
    atomicAdd(&sum[c], s);
    atomicAdd(&sumsq[c], qq);
}
__global__ void bn_stats_cat_k(const float* __restrict__ xa, const float* __restrict__ xb,
                               int n, float* __restrict__ sum, float* __restrict__ sumsq) {
    int c = threadIdx.x;  // 512
    int r0 = blockIdx.x * 128;
    int rend = min(r0 + 128, n);
    const float* src = (c < 256) ? xa : xb;
    int cc = c & 255;
    float s = 0.f, qq = 0.f;
    for (int r = r0; r < rend; ++r) {
        float v = src[(size_t)r * NF + cc];
        s += v; qq += v * v;
    }
    atomicAdd(&sum[c], s);
    atomicAdd(&sumsq[c], qq);
}
__global__ void bn_fin_k(float* __restrict__ st, int n, int C) {
    int c = blockIdx.x * 256 + threadIdx.x;
    if (c >= C) return;
    float inv_n = 1.0f / (float)n;
    float mean = st[c] * inv_n;
    float var = fmaxf(st[C + c] * inv_n - mean * mean, 0.f);
    st[c] = mean;
    st[C + c] = rsqrtf(var + EPSV);
}
__global__ void bn_apply_k(const float* __restrict__ x, const float* __restrict__ st,
                           const float* __restrict__ g, const float* __restrict__ be,
                           float* __restrict__ out, int n) {
    int t = blockIdx.x * 256 + threadIdx.x;
    if (t >= n * NF) return;
    int c = t & 255;
    float v = (x[t] - st[c]) * st[256 + c] * g[c] + be[c];
    out[t] = fmaxf(v, 0.f);
}

// ---------------- GAT scores ----------------
__global__ void gat_scores_k(const float* __restrict__ h, const float* __restrict__ as_,
                             const float* __restrict__ ad_, float* __restrict__ es,
                             float* __restrict__ ed, int n) {
    int wave = threadIdx.x >> 6, lane = threadIdx.x & 63;
    int i = blockIdx.x * 4 + wave;
    if (i >= n) return;
    int c = lane * 4;
    float4 hv = *(const float4*)(h + (size_t)i * NF + c);
    float s1 = hv.x * as_[c] + hv.y * as_[c + 1] + hv.z * as_[c + 2] + hv.w * as_[c + 3];
    float s2 = hv.x * ad_[c] + hv.y * ad_[c + 1] + hv.z * ad_[c + 2] + hv.w * ad_[c + 3];
    s1 = wredsum(s1);
    s2 = wredsum(s2);
    if (lane == 0) { es[i] = s1; ed[i] = s2; }
}

// ---------------- fused GAT aggregation via CSR ----------------
__global__ __launch_bounds__(256) void gat_csr_k(const float* __restrict__ h,
                                                 const int* __restrict__ rp,
                                                 const int* __restrict__ col,
                                                 const float* __restrict__ es,
                                                 const float* __restrict__ ed,
                                                 const float* __restrict__ b,
                                                 float* __restrict__ out, int n,
                                                 int do_relu) {
    int wave = threadIdx.x >> 6, lane = threadIdx.x & 63;
    int i = blockIdx.x * 4 + wave;
    if (i >= n) return;
    int beg = rp[i], end = rp[i + 1];
    float edi = ed[i];
    float eself = lrelu(es[i] + edi);
    float m = eself;
    for (int j = beg + lane; j < end; j += 64) m = fmaxf(m, lrelu(es[col[j]] + edi));
    m = wredmax(m);
    float ssum = (lane == 0) ? __expf(eself - m) : 0.f;
    for (int j = beg + lane; j < end; j += 64) ssum += __expf(lrelu(es[col[j]] + edi) - m);
    ssum = wredsum(ssum);
    float inv = 1.0f / ssum;
    int c = lane * 4;
    float al = __expf(eself - m) * inv;
    float4 hv = *(const float4*)(h + (size_t)i * NF + c);
    float4 acc;
    acc.x = b[c + 0] + al * hv.x;
    acc.y = b[c + 1] + al * hv.y;
    acc.z = b[c + 2] + al * hv.z;
    acc.w = b[c + 3] + al * hv.w;
    for (int j = beg; j < end; ++j) {
        int s = col[j];
        float a = __expf(lrelu(es[s] + edi) - m) * inv;
        float4 hs = *(const float4*)(h + (size_t)s * NF + c);
        acc.x += a * hs.x;
        acc.y += a * hs.y;
        acc.z += a * hs.z;
        acc.w += a * hs.w;
    }
    if (do_relu) {
        acc.x = fmaxf(acc.x, 0.f); acc.y = fmaxf(acc.y, 0.f);
        acc.z = fmaxf(acc.z, 0.f); acc.w = fmaxf(acc.w, 0.f);
    }
    *(float4*)(out + (size_t)i * NF + c) = acc;
}

// ---------------- final: relu(bn(cat(x,h))) @ w + bias -> fp32 ----------------
__global__ void final_k(const float* __restrict__ xp, const float* __restrict__ hp,
                        const float* __restrict__ st, const float* __restrict__ g,
                        const float* __restrict__ be, const float* __restrict__ w,
                        const float* __restrict__ bias, float* __restrict__ out, int n) {
    int wave = threadIdx.x >> 6, lane = threadIdx.x & 63;
    int i = blockIdx.x * 4 + wave;
    if (i >= n) return;
    const float* src = (lane < 32) ? (xp + (size_t)i * NF + lane * 8)
                                   : (hp + (size_t)i * NF + (lane - 32) * 8);
    int c0 = lane * 8;
    float acc = 0.f;
#pragma unroll
    for (int j = 0; j < 8; ++j) {
        int c = c0 + j;
        float v = (src[j] - st[c]) * st[512 + c] * g[c] + be[c];
        v = fmaxf(v, 0.f);
        acc += v * w[c];
    }
    acc = wredsum(acc);
    if (lane == 0) out[i] = acc + bias[0];
}

// ---------------- host ----------------
extern "C" void kernel_launch(void* const* d_in, const int* in_sizes, int n_in,
                              void* d_out, int out_size, void* d_ws, size_t ws_size,
                              hipStream_t stream) {
    const void* x_ab = d_in[0];
    const void* x_ag = d_in[1];
    const void* W_gcn = d_in[2];
    const void* b_gcn = d_in[3];
    const void* g1 = d_in[4];
    const void* be1 = d_in[5];
    const void* W_aggcn = d_in[6];
    const void* b_aggcn = d_in[7];
    const void* ag_g1 = d_in[8];
    const void* ag_be1 = d_in[9];
    const void* W_gat = d_in[10];
    const void* a_src = d_in[11];
    const void* a_dst = d_in[12];
    const void* b_gat = d_in[13];
    const void* W_gat2 = d_in[14];
    const void* a_src2 = d_in[15];
    const void* a_dst2 = d_in[16];
    const void* b_gat2 = d_in[17];
    const void* ag_g2 = d_in[18];
    const void* ag_be2 = d_in[19];
    const void* W_agfc = d_in[20];
    const void* b_agfc = d_in[21];
    const void* g2 = d_in[22];
    const void* be2 = d_in[23];
    const void* W_fc = d_in[24];
    const void* b_fc = d_in[25];
    const int* e_ab = (const int*)d_in[26];
    const int* e_ag = (const int*)d_in[27];
    const int* e_d = (const int*)d_in[28];

    const int NAB = 20000, NAG = 20000, NT = 40000;
    const int EAB = 320000, EAG = 320000, ED = 640000;

    float* hcat = (float*)d_ws;                 // NT*NF
    float* bufA = hcat + (size_t)NT * NF;       // NT*NF
    float* bufB = bufA + (size_t)NT * NF;       // NT*NF
    float* dinv = bufB + (size_t)NT * NF;       // NT
    float* es = dinv + NT;                      // NT
    float* edv = es + NT;                       // NT
    float* st = edv + NT;                       // 2048
    float* prm = st + 2048;                     // 8192
    int* flag = (int*)(prm + 8192);             // 16
    int* rp_ab = flag + 16;                     // NAB+1
    int* rp_ag = rp_ab + NAB + 1;               // NAG+1
    int* rp_d = rp_ag + NAG + 1;                // NT+1
    int* cnt = rp_d + NT + 1;                   // NT+1
    int* col_ab = cnt + NT + 1;                 // EAB
    int* col_ag = col_ab + EAB;                 // EAG
    int* col_d = col_ag + EAG;                  // ED

    dim3 t256(256), t512(512);

    detect_k<<<dim3(1), t256, 0, stream>>>((const u16*)x_ab, flag);
    auto cvt = [&](const void* s, int off, int n) {
        cvt_k<<<dim3((n + 255) / 256), t256, 0, stream>>>(s, prm + off, n, flag);
    };
    cvt(b_gcn, P_BGCN, 256);  cvt(g1, P_G1, 256);        cvt(be1, P_BE1, 256);
    cvt(b_aggcn, P_BAGG, 256); cvt(ag_g1, P_AGG1, 256);  cvt(ag_be1, P_AGBE1, 256);
    cvt(a_src, P_ASRC, 256);  cvt(a_dst, P_ADST, 256);   cvt(b_gat, P_BGAT, 256);
    cvt(a_src2, P_ASRC2, 256); cvt(a_dst2, P_ADST2, 256); cvt(b_gat2, P_BGAT2, 256);
    cvt(g2, P_G2, 512);       cvt(be2, P_BE2, 512);      cvt(W_fc, P_WFC, 512);
    cvt(ag_g2, P_AGG2, 512);  cvt(ag_be2, P_AGBE2, 512); cvt(W_agfc, P_WAGFC, 512);
    cvt(b_fc, P_BFC, 1);      cvt(b_agfc, P_BAGFC, 1);

    auto build_csr = [&](const int* ei, int E, int n, int* rp, int* col) {
        zero_i_k<<<dim3((n + 256) / 256), t256, 0, stream>>>(cnt, n + 1);
        cnt_k<<<dim3((E + 255) / 256), t256, 0, stream>>>(ei + E, E, cnt);
        scan_k<<<dim3(1), t256, 0, stream>>>(cnt, rp, n);
        zero_i_k<<<dim3((n + 256) / 256), t256, 0, stream>>>(cnt, n + 1);
        scatter_k<<<dim3((E + 255) / 256), t256, 0, stream>>>(ei, E, rp, cnt, col);
    };
    build_csr(e_ab, EAB, NAB, rp_ab, col_ab);
    build_csr(e_ag, EAG, NAG, rp_ag, col_ag);
    build_csr(e_d, ED, NT, rp_d, col_d);

    auto gemm = [&](const void* A, int amode, const void* W, float* C, int M) {
        gemm_mfma_k<<<dim3((M + 63) / 64, 4), t256, 0, stream>>>(A, amode, W, flag, C, M);
    };

    auto gcn = [&](const void* x, const void* W, const int* rp, const int* col,
                   int pb, int pg, int pbe, int n, float* hout) {
        gemm(x, 2, W, bufA, n);
        dinv_k<<<dim3((n + 255) / 256), t256, 0, stream>>>(rp, dinv, n);
        gcn_csr_k<<<dim3((n + 3) / 4), t256, 0, stream>>>(bufA, rp, col, dinv, prm + pb, bufB, n);
        fill_k<<<dim3(4), t256, 0, stream>>>(st, 0.f, 1024);
        bn_stats_k<<<dim3((n + 127) / 128), t256, 0, stream>>>(bufB, n, st, st + 256);
        bn_fin_k<<<dim3(1), t256, 0, stream>>>(st, n, 256);
        bn_apply_k<<<dim3(n), t256, 0, stream>>>(bufB, st, prm + pg, prm + pbe, hout, n);
    };

    auto gat = [&](const float* xin, const void* W, int pas, int pad, int pb,
                   int do_relu, float* xout) {
        gemm((const void*)xin, 0, W, bufA, NT);
        gat_scores_k<<<dim3((NT + 3) / 4), t256, 0, stream>>>(bufA, prm + pas, prm + pad, es, edv, NT);
        gat_csr_k<<<dim3((NT + 3) / 4), t256, 0, stream>>>(bufA, rp_d, col_d, es, edv,
                                                           prm + pb, xout, NT, do_relu);
    };

    auto finstage = [&](const float* xp, const float* hp, int pg, int pbe,
                        int pw, int pbias, float* outp, int n) {
        fill_k<<<dim3(4), t256, 0, stream>>>(st, 0.f, 1024);
        bn_stats_cat_k<<<dim3((n + 127) / 128), t512, 0, stream>>>(xp, hp, n, st, st + 512);
        bn_fin_k<<<dim3(2), t256, 0, stream>>>(st, n, 512);
        final_k<<<dim3((n + 3) / 4), t256, 0, stream>>>(xp, hp, st, prm + pg, prm + pbe,
                                                        prm + pw, prm + pbias, outp, n);
    };

    gcn(x_ab, W_gcn, rp_ab, col_ab, P_BGCN, P_G1, P_BE1, NAB, hcat);
    gcn(x_ag, W_aggcn, rp_ag, col_ag, P_BAGG, P_AGG1, P_AGBE1, NAG, hcat + (size_t)NAB * NF);
    gat(hcat, W_gat, P_ASRC, P_ADST, P_BGAT, 1, bufB);
    gat(bufB, W_gat2, P_ASRC2, P_ADST2, P_BGAT2, 0, bufB);
    float* outp = (float*)d_out;
    finstage(bufB, hcat, P_G2, P_BE2, P_WFC, P_BFC, outp, NAB);
    finstage(bufB + (size_t)NAB * NF, hcat + (size_t)NAB * NF, P_AGG2, P_AGBE2,
             P_WAGFC, P_BAGFC, outp + NAB, NAG);
}

// Round 7
// 1167.915 us; speedup vs baseline: 6.4706x; 1.0954x over previous
//
#include <hip/hip_runtime.h>
#include <hip/hip_bf16.h>
#include <stdint.h>

#define NF 256
#define EPSV 1e-5f

typedef unsigned short u16;
typedef short short8 __attribute__((ext_vector_type(8)));
typedef float floatx4 __attribute__((ext_vector_type(4)));

// param block offsets (floats): 12 x 256, then 6 x 512, then 2 x 1
#define P_BGCN 0
#define P_G1 256
#define P_BE1 512
#define P_BAGG 768
#define P_AGG1 1024
#define P_AGBE1 1280
#define P_ASRC 1536
#define P_ADST 1792
#define P_BGAT 2048
#define P_ASRC2 2304
#define P_ADST2 2560
#define P_BGAT2 2816
#define P_G2 3072
#define P_BE2 3584
#define P_WFC 4096
#define P_AGG2 4608
#define P_AGBE2 5120
#define P_WAGFC 5632
#define P_BFC 6144
#define P_BAGFC 6145

__device__ __forceinline__ float bf2f(u16 u) {
    union { unsigned int i; float f; } v; v.i = ((unsigned int)u) << 16; return v.f;
}
__device__ __forceinline__ u16 f2bf(float f) {
    unsigned int x = __float_as_uint(f);
    unsigned int r = x + 0x7fffu + ((x >> 16) & 1u);
    return (u16)(r >> 16);
}
__device__ __forceinline__ float sane(float f) {
    return (f == f && fabsf(f) < 1e30f) ? f : 0.f;
}
__device__ __forceinline__ unsigned int zap2(unsigned int w) {
    if ((w & 0x00007F80u) == 0x00007F80u) w &= 0xFFFF0000u;
    if ((w & 0x7F800000u) == 0x7F800000u) w &= 0x0000FFFFu;
    return w;
}
__device__ __forceinline__ float lrelu(float x) { return x > 0.f ? x : 0.2f * x; }

__device__ __forceinline__ float4 ld4h(const u16* p) {
    uint2 u = *(const uint2*)p;
    float4 r;
    r.x = bf2f((u16)(u.x & 0xFFFFu)); r.y = bf2f((u16)(u.x >> 16));
    r.z = bf2f((u16)(u.y & 0xFFFFu)); r.w = bf2f((u16)(u.y >> 16));
    return r;
}
__device__ __forceinline__ void st4h(u16* p, float4 v) {
    uint2 u;
    u.x = (unsigned)f2bf(v.x) | ((unsigned)f2bf(v.y) << 16);
    u.y = (unsigned)f2bf(v.z) | ((unsigned)f2bf(v.w) << 16);
    *(uint2*)p = u;
}

__device__ __forceinline__ float wredmax(float v) {
#pragma unroll
    for (int o = 32; o > 0; o >>= 1) v = fmaxf(v, __shfl_xor(v, o, 64));
    return v;
}
__device__ __forceinline__ float wredsum(float v) {
#pragma unroll
    for (int o = 32; o > 0; o >>= 1) v += __shfl_xor(v, o, 64);
    return v;
}

// ---------------- dtype detect ----------------
__global__ void detect_k(const u16* __restrict__ x, int* __restrict__ flag) {
    __shared__ int cnt;
    if (threadIdx.x == 0) cnt = 0;
    __syncthreads();
    int c = 0;
#pragma unroll
    for (int k = 0; k < 4; ++k) {
        unsigned int u = x[2 * (threadIdx.x + 256 * k)];
        int e = (int)((u >> 7) & 0xFFu);
        if (u == 0u || (e >= 100 && e <= 140)) c++;
    }
    atomicAdd(&cnt, c);
    __syncthreads();
    if (threadIdx.x == 0) flag[0] = (cnt >= 512) ? 1 : 0;
}

// ---------------- single param-conversion kernel ----------------
__global__ void cvt_all_k(const void* p0, const void* p1, const void* p2, const void* p3,
                          const void* p4, const void* p5, const void* p6, const void* p7,
                          const void* p8, const void* p9, const void* p10, const void* p11,
                          const void* p12, const void* p13, const void* p14, const void* p15,
                          const void* p16, const void* p17, const void* p18, const void* p19,
                          float* __restrict__ prm, const int* __restrict__ flagp) {
    const void* ptrs[20] = {p0, p1, p2, p3, p4, p5, p6, p7, p8, p9,
                            p10, p11, p12, p13, p14, p15, p16, p17, p18, p19};
    int idx = blockIdx.x * 256 + threadIdx.x;
    if (idx >= 6146) return;
    int t, j;
    if (idx < 3072) { t = idx >> 8; j = idx & 255; }
    else if (idx < 6144) { t = 12 + ((idx - 3072) >> 9); j = (idx - 3072) & 511; }
    else { t = 18 + (idx - 6144); j = 0; }
    const void* src = ptrs[t];
    float v = flagp[0] ? bf2f(((const u16*)src)[j]) : ((const float*)src)[j];
    prm[idx] = sane(v);
}

// ---------------- utility ----------------
__global__ void fill_k(float* __restrict__ p, float v, int n) {
    int i = blockIdx.x * 256 + threadIdx.x;
    if (i < n) p[i] = v;
}
__global__ void zero_i_k(int* __restrict__ p, int n) {
    int i = blockIdx.x * 256 + threadIdx.x;
    if (i < n) p[i] = 0;
}

// ---------------- CSR build ----------------
__global__ void cnt_k(const int* __restrict__ dst, int E, int* __restrict__ cnt) {
    int e = blockIdx.x * 256 + threadIdx.x;
    if (e < E) atomicAdd(&cnt[dst[e]], 1);
}
__global__ __launch_bounds__(256) void scan_k(const int* __restrict__ cnt,
                                              int* __restrict__ rp, int n) {
    __shared__ int wpart[4];
    __shared__ int sbase;
    int lane = threadIdx.x & 63, wave = threadIdx.x >> 6;
    if (threadIdx.x == 0) sbase = 0;
    __syncthreads();
    for (int c0 = 0; c0 < n; c0 += 256) {
        int i = c0 + threadIdx.x;
        int v = (i < n) ? cnt[i] : 0;
        int x = v;
#pragma unroll
        for (int o = 1; o < 64; o <<= 1) {
            int t = __shfl_up(x, o, 64);
            if (lane >= o) x += t;
        }
        if (lane == 63) wpart[wave] = x;
        __syncthreads();
        int woff = 0;
#pragma unroll
        for (int w = 0; w < 4; ++w) woff += (w < wave) ? wpart[w] : 0;
        int total = wpart[0] + wpart[1] + wpart[2] + wpart[3];
        if (i < n) rp[i] = sbase + woff + x - v;
        __syncthreads();
        if (threadIdx.x == 0) sbase += total;
        __syncthreads();
    }
    if (threadIdx.x == 0) rp[n] = sbase;
}
__global__ void scatter_k(const int* __restrict__ ei, int E, const int* __restrict__ rp,
                          int* __restrict__ cur, int* __restrict__ col) {
    int e = blockIdx.x * 256 + threadIdx.x;
    if (e >= E) return;
    int s = ei[e], d = ei[E + e];
    int p = atomicAdd(&cur[d], 1);
    col[rp[d] + p] = s;
}
__global__ void dinv_k(const int* __restrict__ rp, float* __restrict__ dinv, int n) {
    int i = blockIdx.x * 256 + threadIdx.x;
    if (i < n) dinv[i] = rsqrtf((float)(rp[i + 1] - rp[i] + 1));
}

// ---------------- MFMA GEMM: C(Mx256 bf16) = A(Mx256) @ W(256x256) ----------------
__device__ __forceinline__ int swz(int row, int k) {
    return row * 256 + ((((k >> 3) ^ (row & 7)) << 3) | (k & 7));
}

// amode: 2 = raw input (dtype per flag), 1 = bf16 ws buffer. W raw (dtype per flag).
__global__ __launch_bounds__(256) void gemm_mfma_k(const void* __restrict__ Aptr, int amode,
                                                   const void* __restrict__ Wptr,
                                                   const int* __restrict__ flagp,
                                                   u16* __restrict__ C, int M) {
    __shared__ u16 As[64 * 256];
    __shared__ u16 Bs[64 * 256];
    int f = flagp[0];
    int row0 = blockIdx.x * 64;
    int col0 = blockIdx.y * 64;
    int tid = threadIdx.x;
    int r = tid >> 2, seg = tid & 3;
    int grow = row0 + r;
#pragma unroll
    for (int i = 0; i < 8; ++i) {
        int k = seg * 64 + i * 8;
        uint4 v = make_uint4(0u, 0u, 0u, 0u);
        if (grow < M) {
            if (amode == 1) {
                v = *(const uint4*)((const u16*)Aptr + (size_t)grow * NF + k);
            } else if (f) {
                v = *(const uint4*)((const u16*)Aptr + (size_t)grow * NF + k);
                v.x = zap2(v.x); v.y = zap2(v.y); v.z = zap2(v.z); v.w = zap2(v.w);
            } else {
                const float* A = (const float*)Aptr;
                float4 f0 = *(const float4*)(A + (size_t)grow * NF + k);
                float4 f1 = *(const float4*)(A + (size_t)grow * NF + k + 4);
                union { u16 s[8]; uint4 u; } tmp;
                tmp.s[0] = f2bf(sane(f0.x)); tmp.s[1] = f2bf(sane(f0.y));
                tmp.s[2] = f2bf(sane(f0.z)); tmp.s[3] = f2bf(sane(f0.w));
                tmp.s[4] = f2bf(sane(f1.x)); tmp.s[5] = f2bf(sane(f1.y));
                tmp.s[6] = f2bf(sane(f1.z)); tmp.s[7] = f2bf(sane(f1.w));
                v = tmp.u;
            }
        }
        *(uint4*)(As + swz(r, k)) = v;
    }
    // stage B^T: Bs row = output col (64), k contiguous
#pragma unroll
    for (int i = 0; i < 8; ++i) {
        int k0 = seg * 64 + i * 8;
        union { u16 s[8]; uint4 u; } tmp;
        if (f) {
            const u16* W = (const u16*)Wptr;
#pragma unroll
            for (int j = 0; j < 8; ++j) {
                u16 w = W[(size_t)(k0 + j) * NF + col0 + r];
                if ((w & 0x7F80u) == 0x7F80u) w = 0;
                tmp.s[j] = w;
            }
        } else {
            const float* W = (const float*)Wptr;
#pragma unroll
            for (int j = 0; j < 8; ++j) tmp.s[j] = f2bf(sane(W[(size_t)(k0 + j) * NF + col0 + r]));
        }
        *(uint4*)(Bs + swz(r, k0)) = tmp.u;
    }
    __syncthreads();

    int wave = tid >> 6, lane = tid & 63;
    int m0 = wave * 16;
    int lr = lane & 15, q = lane >> 4;
    floatx4 acc[4];
#pragma unroll
    for (int nf = 0; nf < 4; ++nf) acc[nf] = (floatx4){0.f, 0.f, 0.f, 0.f};

#pragma unroll
    for (int k0 = 0; k0 < 256; k0 += 32) {
        int kk = k0 + q * 8;
        short8 a = *(const short8*)(As + swz(m0 + lr, kk));
#pragma unroll
        for (int nf = 0; nf < 4; ++nf) {
            short8 b = *(const short8*)(Bs + swz(nf * 16 + lr, kk));
            acc[nf] = __builtin_amdgcn_mfma_f32_16x16x32_bf16(a, b, acc[nf], 0, 0, 0);
        }
    }
#pragma unroll
    for (int nf = 0; nf < 4; ++nf) {
#pragma unroll
        for (int rr = 0; rr < 4; ++rr) {
            int gr = row0 + m0 + q * 4 + rr;
            if (gr < M) C[(size_t)gr * NF + col0 + nf * 16 + lr] = f2bf(acc[nf][rr]);
        }
    }
}

// ---------------- GCN via CSR: one wave per node (bf16 h, bf16 out) ----------------
__global__ __launch_bounds__(256) void gcn_csr_k(const u16* __restrict__ h,
                                                 const int* __restrict__ rp,
                                                 const int* __restrict__ col,
                                                 const float* __restrict__ dinv,
                                                 const float* __restrict__ b,
                                                 u16* __restrict__ out, int n) {
    int wave = threadIdx.x >> 6, lane = threadIdx.x & 63;
    int i = blockIdx.x * 4 + wave;
    if (i >= n) return;
    int c = lane * 4;
    int beg = rp[i], end = rp[i + 1];
    float di = dinv[i];
    float4 hv = ld4h(h + (size_t)i * NF + c);
    float w = di * di;
    float4 acc;
    acc.x = hv.x * w + b[c + 0];
    acc.y = hv.y * w + b[c + 1];
    acc.z = hv.z * w + b[c + 2];
    acc.w = hv.w * w + b[c + 3];
    for (int j = beg; j < end; ++j) {
        int s = col[j];
        float nrm = dinv[s] * di;
        float4 hs = ld4h(h + (size_t)s * NF + c);
        acc.x += hs.x * nrm;
        acc.y += hs.y * nrm;
        acc.z += hs.z * nrm;
        acc.w += hs.w * nrm;
    }
    st4h(out + (size_t)i * NF + c, acc);
}

// ---------------- BN (bf16 inputs) ----------------
__global__ void bn_stats_k(const u16* __restrict__ x, int n,
                           float* __restrict__ sum, float* __restrict__ sumsq) {
    int c = threadIdx.x;
    int r0 = blockIdx.x * 128;
    int rend = min(r0 + 128, n);
    float s = 0.f, qq = 0.f;
    for (int r = r0; r < rend; ++r) {
        float v = bf2f(x[(size_t)r * NF + c]);
        s += v; qq += v * v;
    }
    atomicAdd(&sum[c], s);
    atomicAdd(&sumsq[c], qq);
}
__global__ void bn_stats_cat_k(const u16* __restrict__ xa, const u16* __restrict__ xb,
                               int n, float* __restrict__ sum, float* __restrict__ sumsq) {
    int c = threadIdx.x;  // 512
    int r0 = blockIdx.x * 128;
    int rend = min(r0 + 128, n);
    const u16* src = (c < 256) ? xa : xb;
    int cc = c & 255;
    float s = 0.f, qq = 0.f;
    for (int r = r0; r < rend; ++r) {
        float v = bf2f(src[(size_t)r * NF + cc]);
        s += v; qq += v * v;
    }
    atomicAdd(&sum[c], s);
    atomicAdd(&sumsq[c], qq);
}
__global__ void bn_fin_k(float* __restrict__ st, int n, int C) {
    int c = blockIdx.x * 256 + threadIdx.x;
    if (c >= C) return;
    float inv_n = 1.0f / (float)n;
    float mean = st[c] * inv_n;
    float var = fmaxf(st[C + c] * inv_n - mean * mean, 0.f);
    st[c] = mean;
    st[C + c] = rsqrtf(var + EPSV);
}
__global__ void bn_apply_k(const u16* __restrict__ x, const float* __restrict__ st,
                           const float* __restrict__ g, const float* __restrict__ be,
                           u16* __restrict__ out, int n) {
    int t = blockIdx.x * 256 + threadIdx.x;
    if (t >= n * NF) return;
    int c = t & 255;
    float v = (bf2f(x[t]) - st[c]) * st[256 + c] * g[c] + be[c];
    out[t] = f2bf(fmaxf(v, 0.f));
}

// ---------------- GAT scores (bf16 h) ----------------
__global__ void gat_scores_k(const u16* __restrict__ h, const float* __restrict__ as_,
                             const float* __restrict__ ad_, float* __restrict__ es,
                             float* __restrict__ ed, int n) {
    int wave = threadIdx.x >> 6, lane = threadIdx.x & 63;
    int i = blockIdx.x * 4 + wave;
    if (i >= n) return;
    int c = lane * 4;
    float4 hv = ld4h(h + (size_t)i * NF + c);
    float s1 = hv.x * as_[c] + hv.y * as_[c + 1] + hv.z * as_[c + 2] + hv.w * as_[c + 3];
    float s2 = hv.x * ad_[c] + hv.y * ad_[c + 1] + hv.z * ad_[c + 2] + hv.w * ad_[c + 3];
    s1 = wredsum(s1);
    s2 = wredsum(s2);
    if (lane == 0) { es[i] = s1; ed[i] = s2; }
}

// ---------------- fused GAT aggregation via CSR (bf16 h/out) ----------------
__global__ __launch_bounds__(256) void gat_csr_k(const u16* __restrict__ h,
                                                 const int* __restrict__ rp,
                                                 const int* __restrict__ col,
                                                 const float* __restrict__ es,
                                                 const float* __restrict__ ed,
                                                 const float* __restrict__ b,
                                                 u16* __restrict__ out, int n,
                                                 int do_relu) {
    int wave = threadIdx.x >> 6, lane = threadIdx.x & 63;
    int i = blockIdx.x * 4 + wave;
    if (i >= n) return;
    int beg = rp[i], end = rp[i + 1];
    float edi = ed[i];
    float eself = lrelu(es[i] + edi);
    float m = eself;
    for (int j = beg + lane; j < end; j += 64) m = fmaxf(m, lrelu(es[col[j]] + edi));
    m = wredmax(m);
    float ssum = (lane == 0) ? __expf(eself - m) : 0.f;
    for (int j = beg + lane; j < end; j += 64) ssum += __expf(lrelu(es[col[j]] + edi) - m);
    ssum = wredsum(ssum);
    float inv = 1.0f / ssum;
    int c = lane * 4;
    float al = __expf(eself - m) * inv;
    float4 hv = ld4h(h + (size_t)i * NF + c);
    float4 acc;
    acc.x = b[c + 0] + al * hv.x;
    acc.y = b[c + 1] + al * hv.y;
    acc.z = b[c + 2] + al * hv.z;
    acc.w = b[c + 3] + al * hv.w;
    for (int j = beg; j < end; ++j) {
        int s = col[j];
        float a = __expf(lrelu(es[s] + edi) - m) * inv;
        float4 hs = ld4h(h + (size_t)s * NF + c);
        acc.x += a * hs.x;
        acc.y += a * hs.y;
        acc.z += a * hs.z;
        acc.w += a * hs.w;
    }
    if (do_relu) {
        acc.x = fmaxf(acc.x, 0.f); acc.y = fmaxf(acc.y, 0.f);
        acc.z = fmaxf(acc.z, 0.f); acc.w = fmaxf(acc.w, 0.f);
    }
    st4h(out + (size_t)i * NF + c, acc);
}

// ---------------- final: relu(bn(cat(x,h))) @ w + bias -> fp32 out ----------------
__global__ void final_k(const u16* __restrict__ xp, const u16* __restrict__ hp,
                        const float* __restrict__ st, const float* __restrict__ g,
                        const float* __restrict__ be, const float* __restrict__ w,
                        const float* __restrict__ bias, float* __restrict__ out, int n) {
    int wave = threadIdx.x >> 6, lane = threadIdx.x & 63;
    int i = blockIdx.x * 4 + wave;
    if (i >= n) return;
    const u16* src = (lane < 32) ? (xp + (size_t)i * NF + lane * 8)
                                 : (hp + (size_t)i * NF + (lane - 32) * 8);
    uint4 u = *(const uint4*)src;
    float vv[8];
    vv[0] = bf2f((u16)(u.x & 0xFFFFu)); vv[1] = bf2f((u16)(u.x >> 16));
    vv[2] = bf2f((u16)(u.y & 0xFFFFu)); vv[3] = bf2f((u16)(u.y >> 16));
    vv[4] = bf2f((u16)(u.z & 0xFFFFu)); vv[5] = bf2f((u16)(u.z >> 16));
    vv[6] = bf2f((u16)(u.w & 0xFFFFu)); vv[7] = bf2f((u16)(u.w >> 16));
    int c0 = lane * 8;
    float acc = 0.f;
#pragma unroll
    for (int j = 0; j < 8; ++j) {
        int c = c0 + j;
        float v = (vv[j] - st[c]) * st[512 + c] * g[c] + be[c];
        v = fmaxf(v, 0.f);
        acc += v * w[c];
    }
    acc = wredsum(acc);
    if (lane == 0) out[i] = acc + bias[0];
}

// ---------------- host ----------------
extern "C" void kernel_launch(void* const* d_in, const int* in_sizes, int n_in,
                              void* d_out, int out_size, void* d_ws, size_t ws_size,
                              hipStream_t stream) {
    const void* x_ab = d_in[0];
    const void* x_ag = d_in[1];
    const void* W_gcn = d_in[2];
    const void* W_aggcn = d_in[6];
    const void* W_gat = d_in[10];
    const void* W_gat2 = d_in[14];
    const int* e_ab = (const int*)d_in[26];
    const int* e_ag = (const int*)d_in[27];
    const int* e_d = (const int*)d_in[28];

    const int NAB = 20000, NAG = 20000, NT = 40000;
    const int EAB = 320000, EAG = 320000, ED = 640000;

    u16* hcat = (u16*)d_ws;                     // NT*NF u16
    u16* bufA = hcat + (size_t)NT * NF;         // NT*NF u16
    u16* bufB = bufA + (size_t)NT * NF;         // NT*NF u16
    float* dinv = (float*)(bufB + (size_t)NT * NF);  // NT
    float* es = dinv + NT;                      // NT
    float* edv = es + NT;                       // NT
    float* st = edv + NT;                       // 2048
    float* prm = st + 2048;                     // 8192
    int* flag = (int*)(prm + 8192);             // 16
    int* rp_ab = flag + 16;                     // NAB+1
    int* rp_ag = rp_ab + NAB + 1;               // NAG+1
    int* rp_d = rp_ag + NAG + 1;                // NT+1
    int* cnt = rp_d + NT + 1;                   // NT+1
    int* col_ab = cnt + NT + 1;                 // EAB
    int* col_ag = col_ab + EAB;                 // EAG
    int* col_d = col_ag + EAG;                  // ED

    dim3 t256(256), t512(512);

    detect_k<<<dim3(1), t256, 0, stream>>>((const u16*)x_ab, flag);
    cvt_all_k<<<dim3(25), t256, 0, stream>>>(
        d_in[3], d_in[4], d_in[5], d_in[7], d_in[8], d_in[9],
        d_in[11], d_in[12], d_in[13], d_in[15], d_in[16], d_in[17],
        d_in[22], d_in[23], d_in[24], d_in[18], d_in[19], d_in[20],
        d_in[25], d_in[21], prm, flag);

    auto build_csr = [&](const int* ei, int E, int n, int* rp, int* col) {
        zero_i_k<<<dim3((n + 256) / 256), t256, 0, stream>>>(cnt, n + 1);
        cnt_k<<<dim3((E + 255) / 256), t256, 0, stream>>>(ei + E, E, cnt);
        scan_k<<<dim3(1), t256, 0, stream>>>(cnt, rp, n);
        zero_i_k<<<dim3((n + 256) / 256), t256, 0, stream>>>(cnt, n + 1);
        scatter_k<<<dim3((E + 255) / 256), t256, 0, stream>>>(ei, E, rp, cnt, col);
    };
    build_csr(e_ab, EAB, NAB, rp_ab, col_ab);
    build_csr(e_ag, EAG, NAG, rp_ag, col_ag);
    build_csr(e_d, ED, NT, rp_d, col_d);

    auto gemm = [&](const void* A, int amode, const void* W, u16* C, int M) {
        gemm_mfma_k<<<dim3((M + 63) / 64, 4), t256, 0, stream>>>(A, amode, W, flag, C, M);
    };

    auto gcn = [&](const void* x, const void* W, const int* rp, const int* col,
                   int pb, int pg, int pbe, int n, u16* hout) {
        gemm(x, 2, W, bufA, n);
        dinv_k<<<dim3((n + 255) / 256), t256, 0, stream>>>(rp, dinv, n);
        gcn_csr_k<<<dim3((n + 3) / 4), t256, 0, stream>>>(bufA, rp, col, dinv, prm + pb, bufB, n);
        fill_k<<<dim3(4), t256, 0, stream>>>(st, 0.f, 1024);
        bn_stats_k<<<dim3((n + 127) / 128), t256, 0, stream>>>(bufB, n, st, st + 256);
        bn_fin_k<<<dim3(1), t256, 0, stream>>>(st, n, 256);
        bn_apply_k<<<dim3(n), t256, 0, stream>>>(bufB, st, prm + pg, prm + pbe, hout, n);
    };

    auto gat = [&](const u16* xin, const void* W, int pas, int pad, int pb,
                   int do_relu, u16* xout) {
        gemm((const void*)xin, 1, W, bufA, NT);
        gat_scores_k<<<dim3((NT + 3) / 4), t256, 0, stream>>>(bufA, prm + pas, prm + pad, es, edv, NT);
        gat_csr_k<<<dim3((NT + 3) / 4), t256, 0, stream>>>(bufA, rp_d, col_d, es, edv,
                                                           prm + pb, xout, NT, do_relu);
    };

    auto finstage = [&](const u16* xp, const u16* hp, int pg, int pbe,
                        int pw, int pbias, float* outp, int n) {
        fill_k<<<dim3(4), t256, 0, stream>>>(st, 0.f, 1024);
        bn_stats_cat_k<<<dim3((n + 127) / 128), t512, 0, stream>>>(xp, hp, n, st, st + 512);
        bn_fin_k<<<dim3(2), t256, 0, stream>>>(st, n, 512);
        final_k<<<dim3((n + 3) / 4), t256, 0, stream>>>(xp, hp, st, prm + pg, prm + pbe,
                                                        prm + pw, prm + pbias, outp, n);
    };

    gcn(x_ab, W_gcn, rp_ab, col_ab, P_BGCN, P_G1, P_BE1, NAB, hcat);
    gcn(x_ag, W_aggcn, rp_ag, col_ag, P_BAGG, P_AGG1, P_AGBE1, NAG, hcat + (size_t)NAB * NF);
    gat(hcat, W_gat, P_ASRC, P_ADST, P_BGAT, 1, bufB);
    gat(bufB, W_gat2, P_ASRC2, P_ADST2, P_BGAT2, 0, bufB);
    float* outp = (float*)d_out;
    finstage(bufB, hcat, P_G2, P_BE2, P_WFC, P_BFC, outp, NAB);
    finstage(bufB + (size_t)NAB * NF, hcat + (size_t)NAB * NF, P_AGG2, P_AGBE2,
             P_WAGFC, P_BAGFC, outp + NAB, NAG);
}

// Round 8
// 978.085 us; speedup vs baseline: 7.7264x; 1.1941x over previous
//
#include <hip/hip_runtime.h>
#include <hip/hip_bf16.h>
#include <stdint.h>

#define NF 256
#define EPSV 1e-5f

typedef unsigned short u16;
typedef short short8 __attribute__((ext_vector_type(8)));
typedef float floatx4 __attribute__((ext_vector_type(4)));

// param block offsets (floats): 12 x 256, then 6 x 512, then 2 x 1
#define P_BGCN 0
#define P_G1 256
#define P_BE1 512
#define P_BAGG 768
#define P_AGG1 1024
#define P_AGBE1 1280
#define P_ASRC 1536
#define P_ADST 1792
#define P_BGAT 2048
#define P_ASRC2 2304
#define P_ADST2 2560
#define P_BGAT2 2816
#define P_G2 3072
#define P_BE2 3584
#define P_WFC 4096
#define P_AGG2 4608
#define P_AGBE2 5120
#define P_WAGFC 5632
#define P_BFC 6144
#define P_BAGFC 6145

__device__ __forceinline__ float bf2f(u16 u) {
    union { unsigned int i; float f; } v; v.i = ((unsigned int)u) << 16; return v.f;
}
__device__ __forceinline__ u16 f2bf(float f) {
    unsigned int x = __float_as_uint(f);
    unsigned int r = x + 0x7fffu + ((x >> 16) & 1u);
    return (u16)(r >> 16);
}
__device__ __forceinline__ float sane(float f) {
    return (f == f && fabsf(f) < 1e30f) ? f : 0.f;
}
__device__ __forceinline__ unsigned int zap2(unsigned int w) {
    if ((w & 0x00007F80u) == 0x00007F80u) w &= 0xFFFF0000u;
    if ((w & 0x7F800000u) == 0x7F800000u) w &= 0x0000FFFFu;
    return w;
}
__device__ __forceinline__ float lrelu(float x) { return x > 0.f ? x : 0.2f * x; }

__device__ __forceinline__ float4 ld4h(const u16* p) {
    uint2 u = *(const uint2*)p;
    float4 r;
    r.x = bf2f((u16)(u.x & 0xFFFFu)); r.y = bf2f((u16)(u.x >> 16));
    r.z = bf2f((u16)(u.y & 0xFFFFu)); r.w = bf2f((u16)(u.y >> 16));
    return r;
}
__device__ __forceinline__ void st4h(u16* p, float4 v) {
    uint2 u;
    u.x = (unsigned)f2bf(v.x) | ((unsigned)f2bf(v.y) << 16);
    u.y = (unsigned)f2bf(v.z) | ((unsigned)f2bf(v.w) << 16);
    *(uint2*)p = u;
}

__device__ __forceinline__ float wredmax(float v) {
#pragma unroll
    for (int o = 32; o > 0; o >>= 1) v = fmaxf(v, __shfl_xor(v, o, 64));
    return v;
}
__device__ __forceinline__ float wredsum(float v) {
#pragma unroll
    for (int o = 32; o > 0; o >>= 1) v += __shfl_xor(v, o, 64);
    return v;
}
__device__ __forceinline__ int wscan_incl(int x, int lane) {
#pragma unroll
    for (int o = 1; o < 64; o <<= 1) {
        int t = __shfl_up(x, o, 64);
        if (lane >= o) x += t;
    }
    return x;
}

// ---------------- dtype detect ----------------
__global__ void detect_k(const u16* __restrict__ x, int* __restrict__ flag) {
    __shared__ int cnt;
    if (threadIdx.x == 0) cnt = 0;
    __syncthreads();
    int c = 0;
#pragma unroll
    for (int k = 0; k < 4; ++k) {
        unsigned int u = x[2 * (threadIdx.x + 256 * k)];
        int e = (int)((u >> 7) & 0xFFu);
        if (u == 0u || (e >= 100 && e <= 140)) c++;
    }
    atomicAdd(&cnt, c);
    __syncthreads();
    if (threadIdx.x == 0) flag[0] = (cnt >= 512) ? 1 : 0;
}

// ---------------- single param-conversion kernel ----------------
__global__ void cvt_all_k(const void* p0, const void* p1, const void* p2, const void* p3,
                          const void* p4, const void* p5, const void* p6, const void* p7,
                          const void* p8, const void* p9, const void* p10, const void* p11,
                          const void* p12, const void* p13, const void* p14, const void* p15,
                          const void* p16, const void* p17, const void* p18, const void* p19,
                          float* __restrict__ prm, const int* __restrict__ flagp) {
    const void* ptrs[20] = {p0, p1, p2, p3, p4, p5, p6, p7, p8, p9,
                            p10, p11, p12, p13, p14, p15, p16, p17, p18, p19};
    int idx = blockIdx.x * 256 + threadIdx.x;
    if (idx >= 6146) return;
    int t, j;
    if (idx < 3072) { t = idx >> 8; j = idx & 255; }
    else if (idx < 6144) { t = 12 + ((idx - 3072) >> 9); j = (idx - 3072) & 511; }
    else { t = 18 + (idx - 6144); j = 0; }
    const void* src = ptrs[t];
    float v = flagp[0] ? bf2f(((const u16*)src)[j]) : ((const float*)src)[j];
    prm[idx] = sane(v);
}

// ---------------- utility ----------------
__global__ void fill_k(float* __restrict__ p, float v, int n) {
    int i = blockIdx.x * 256 + threadIdx.x;
    if (i < n) p[i] = v;
}
__global__ void zero_i_k(int* __restrict__ p, int n) {
    int i = blockIdx.x * 256 + threadIdx.x;
    if (i < n) p[i] = 0;
}

// ---------------- CSR build ----------------
__global__ void cnt_k(const int* __restrict__ dst, int E, int* __restrict__ cnt) {
    int e = blockIdx.x * 256 + threadIdx.x;
    if (e < E) atomicAdd(&cnt[dst[e]], 1);
}
// phase 1: per-block (256-chunk) sums
__global__ __launch_bounds__(256) void scan_sum_k(const int* __restrict__ cnt,
                                                  int* __restrict__ bsum, int n) {
    __shared__ int wp[4];
    int i = blockIdx.x * 256 + threadIdx.x;
    int lane = threadIdx.x & 63, wave = threadIdx.x >> 6;
    int v = (i < n) ? cnt[i] : 0;
#pragma unroll
    for (int o = 32; o > 0; o >>= 1) v += __shfl_xor(v, o, 64);
    if (lane == 0) wp[wave] = v;
    __syncthreads();
    if (threadIdx.x == 0) bsum[blockIdx.x] = wp[0] + wp[1] + wp[2] + wp[3];
}
// phase 2: single block exclusive-scans bsum (nb <= 256) in place; writes total to *rp_n
__global__ __launch_bounds__(256) void scan_base_k(int* __restrict__ bsum, int nb,
                                                   int* __restrict__ rp_n) {
    __shared__ int wp[4];
    int lane = threadIdx.x & 63, wave = threadIdx.x >> 6;
    int v = (threadIdx.x < nb) ? bsum[threadIdx.x] : 0;
    int x = wscan_incl(v, lane);
    if (lane == 63) wp[wave] = x;
    __syncthreads();
    int off = 0;
#pragma unroll
    for (int w = 0; w < 4; ++w) off += (w < wave) ? wp[w] : 0;
    if (threadIdx.x < nb) bsum[threadIdx.x] = off + x - v;
    if (threadIdx.x == 0) *rp_n = wp[0] + wp[1] + wp[2] + wp[3];
}
// phase 3: per-chunk exclusive scan + block base
__global__ __launch_bounds__(256) void scan_fin_k(const int* __restrict__ cnt,
                                                  const int* __restrict__ bsum,
                                                  int* __restrict__ rp, int n) {
    __shared__ int wp[4];
    int i = blockIdx.x * 256 + threadIdx.x;
    int lane = threadIdx.x & 63, wave = threadIdx.x >> 6;
    int v = (i < n) ? cnt[i] : 0;
    int x = wscan_incl(v, lane);
    if (lane == 63) wp[wave] = x;
    __syncthreads();
    int off = 0;
#pragma unroll
    for (int w = 0; w < 4; ++w) off += (w < wave) ? wp[w] : 0;
    if (i < n) rp[i] = bsum[blockIdx.x] + off + x - v;
}
__global__ void scatter_k(const int* __restrict__ ei, int E, const int* __restrict__ rp,
                          int* __restrict__ cur, int* __restrict__ col) {
    int e = blockIdx.x * 256 + threadIdx.x;
    if (e >= E) return;
    int s = ei[e], d = ei[E + e];
    int p = atomicAdd(&cur[d], 1);
    col[rp[d] + p] = s;
}
__global__ void dinv_k(const int* __restrict__ rp, float* __restrict__ dinv, int n) {
    int i = blockIdx.x * 256 + threadIdx.x;
    if (i < n) dinv[i] = rsqrtf((float)(rp[i + 1] - rp[i] + 1));
}

// ---------------- MFMA GEMM: C(Mx256 bf16) = A(Mx256) @ W(256x256) ----------------
__device__ __forceinline__ int swz(int row, int k) {
    return row * 256 + ((((k >> 3) ^ (row & 7)) << 3) | (k & 7));
}

// amode: 2 = raw input (dtype per flag), 1 = bf16 ws buffer. W raw (dtype per flag).
__global__ __launch_bounds__(256) void gemm_mfma_k(const void* __restrict__ Aptr, int amode,
                                                   const void* __restrict__ Wptr,
                                                   const int* __restrict__ flagp,
                                                   u16* __restrict__ C, int M) {
    __shared__ u16 As[64 * 256];
    __shared__ u16 Bs[64 * 256];
    int f = flagp[0];
    int row0 = blockIdx.x * 64;
    int col0 = blockIdx.y * 64;
    int tid = threadIdx.x;
    int r = tid >> 2, seg = tid & 3;
    int grow = row0 + r;
#pragma unroll
    for (int i = 0; i < 8; ++i) {
        int k = seg * 64 + i * 8;
        uint4 v = make_uint4(0u, 0u, 0u, 0u);
        if (grow < M) {
            if (amode == 1) {
                v = *(const uint4*)((const u16*)Aptr + (size_t)grow * NF + k);
            } else if (f) {
                v = *(const uint4*)((const u16*)Aptr + (size_t)grow * NF + k);
                v.x = zap2(v.x); v.y = zap2(v.y); v.z = zap2(v.z); v.w = zap2(v.w);
            } else {
                const float* A = (const float*)Aptr;
                float4 f0 = *(const float4*)(A + (size_t)grow * NF + k);
                float4 f1 = *(const float4*)(A + (size_t)grow * NF + k + 4);
                union { u16 s[8]; uint4 u; } tmp;
                tmp.s[0] = f2bf(sane(f0.x)); tmp.s[1] = f2bf(sane(f0.y));
                tmp.s[2] = f2bf(sane(f0.z)); tmp.s[3] = f2bf(sane(f0.w));
                tmp.s[4] = f2bf(sane(f1.x)); tmp.s[5] = f2bf(sane(f1.y));
                tmp.s[6] = f2bf(sane(f1.z)); tmp.s[7] = f2bf(sane(f1.w));
                v = tmp.u;
            }
        }
        *(uint4*)(As + swz(r, k)) = v;
    }
    // stage B^T: Bs row = output col (64), k contiguous
#pragma unroll
    for (int i = 0; i < 8; ++i) {
        int k0 = seg * 64 + i * 8;
        union { u16 s[8]; uint4 u; } tmp;
        if (f) {
            const u16* W = (const u16*)Wptr;
#pragma unroll
            for (int j = 0; j < 8; ++j) {
                u16 w = W[(size_t)(k0 + j) * NF + col0 + r];
                if ((w & 0x7F80u) == 0x7F80u) w = 0;
                tmp.s[j] = w;
            }
        } else {
            const float* W = (const float*)Wptr;
#pragma unroll
            for (int j = 0; j < 8; ++j) tmp.s[j] = f2bf(sane(W[(size_t)(k0 + j) * NF + col0 + r]));
        }
        *(uint4*)(Bs + swz(r, k0)) = tmp.u;
    }
    __syncthreads();

    int wave = tid >> 6, lane = tid & 63;
    int m0 = wave * 16;
    int lr = lane & 15, q = lane >> 4;
    floatx4 acc[4];
#pragma unroll
    for (int nf = 0; nf < 4; ++nf) acc[nf] = (floatx4){0.f, 0.f, 0.f, 0.f};

#pragma unroll
    for (int k0 = 0; k0 < 256; k0 += 32) {
        int kk = k0 + q * 8;
        short8 a = *(const short8*)(As + swz(m0 + lr, kk));
#pragma unroll
        for (int nf = 0; nf < 4; ++nf) {
            short8 b = *(const short8*)(Bs + swz(nf * 16 + lr, kk));
            acc[nf] = __builtin_amdgcn_mfma_f32_16x16x32_bf16(a, b, acc[nf], 0, 0, 0);
        }
    }
#pragma unroll
    for (int nf = 0; nf < 4; ++nf) {
#pragma unroll
        for (int rr = 0; rr < 4; ++rr) {
            int gr = row0 + m0 + q * 4 + rr;
            if (gr < M) C[(size_t)gr * NF + col0 + nf * 16 + lr] = f2bf(acc[nf][rr]);
        }
    }
}

// ---------------- GCN via CSR: one wave per node (bf16 h, bf16 out) ----------------
__global__ __launch_bounds__(256) void gcn_csr_k(const u16* __restrict__ h,
                                                 const int* __restrict__ rp,
                                                 const int* __restrict__ col,
                                                 const float* __restrict__ dinv,
                                                 const float* __restrict__ b,
                                                 u16* __restrict__ out, int n) {
    int wave = threadIdx.x >> 6, lane = threadIdx.x & 63;
    int i = blockIdx.x * 4 + wave;
    if (i >= n) return;
    int c = lane * 4;
    int beg = rp[i], end = rp[i + 1];
    float di = dinv[i];
    float4 hv = ld4h(h + (size_t)i * NF + c);
    float w = di * di;
    float4 acc;
    acc.x = hv.x * w + b[c + 0];
    acc.y = hv.y * w + b[c + 1];
    acc.z = hv.z * w + b[c + 2];
    acc.w = hv.w * w + b[c + 3];
    for (int j = beg; j < end; ++j) {
        int s = col[j];
        float nrm = dinv[s] * di;
        float4 hs = ld4h(h + (size_t)s * NF + c);
        acc.x += hs.x * nrm;
        acc.y += hs.y * nrm;
        acc.z += hs.z * nrm;
        acc.w += hs.w * nrm;
    }
    st4h(out + (size_t)i * NF + c, acc);
}

// ---------------- BN (bf16 inputs) ----------------
__global__ void bn_stats_k(const u16* __restrict__ x, int n,
                           float* __restrict__ sum, float* __restrict__ sumsq) {
    int c = threadIdx.x;
    int r0 = blockIdx.x * 128;
    int rend = min(r0 + 128, n);
    float s = 0.f, qq = 0.f;
    for (int r = r0; r < rend; ++r) {
        float v = bf2f(x[(size_t)r * NF + c]);
        s += v; qq += v * v;
    }
    atomicAdd(&sum[c], s);
    atomicAdd(&sumsq[c], qq);
}
__global__ void bn_stats_cat_k(const u16* __restrict__ xa, const u16* __restrict__ xb,
                               int n, float* __restrict__ sum, float* __restrict__ sumsq) {
    int c = threadIdx.x;  // 512
    int r0 = blockIdx.x * 128;
    int rend = min(r0 + 128, n);
    const u16* src = (c < 256) ? xa : xb;
    int cc = c & 255;
    float s = 0.f, qq = 0.f;
    for (int r = r0; r < rend; ++r) {
        float v = bf2f(src[(size_t)r * NF + cc]);
        s += v; qq += v * v;
    }
    atomicAdd(&sum[c], s);
    atomicAdd(&sumsq[c], qq);
}
__global__ void bn_fin_k(float* __restrict__ st, int n, int C) {
    int c = blockIdx.x * 256 + threadIdx.x;
    if (c >= C) return;
    float inv_n = 1.0f / (float)n;
    float mean = st[c] * inv_n;
    float var = fmaxf(st[C + c] * inv_n - mean * mean, 0.f);
    st[c] = mean;
    st[C + c] = rsqrtf(var + EPSV);
}
__global__ void bn_apply_k(const u16* __restrict__ x, const float* __restrict__ st,
                           const float* __restrict__ g, const float* __restrict__ be,
                           u16* __restrict__ out, int n) {
    int t = blockIdx.x * 256 + threadIdx.x;
    if (t >= n * NF) return;
    int c = t & 255;
    float v = (bf2f(x[t]) - st[c]) * st[256 + c] * g[c] + be[c];
    out[t] = f2bf(fmaxf(v, 0.f));
}

// ---------------- GAT scores (bf16 h) ----------------
__global__ void gat_scores_k(const u16* __restrict__ h, const float* __restrict__ as_,
                             const float* __restrict__ ad_, float* __restrict__ es,
                             float* __restrict__ ed, int n) {
    int wave = threadIdx.x >> 6, lane = threadIdx.x & 63;
    int i = blockIdx.x * 4 + wave;
    if (i >= n) return;
    int c = lane * 4;
    float4 hv = ld4h(h + (size_t)i * NF + c);
    float s1 = hv.x * as_[c] + hv.y * as_[c + 1] + hv.z * as_[c + 2] + hv.w * as_[c + 3];
    float s2 = hv.x * ad_[c] + hv.y * ad_[c + 1] + hv.z * ad_[c + 2] + hv.w * ad_[c + 3];
    s1 = wredsum(s1);
    s2 = wredsum(s2);
    if (lane == 0) { es[i] = s1; ed[i] = s2; }
}

// ---------------- fused GAT aggregation via CSR (bf16 h/out) ----------------
__global__ __launch_bounds__(256) void gat_csr_k(const u16* __restrict__ h,
                                                 const int* __restrict__ rp,
                                                 const int* __restrict__ col,
                                                 const float* __restrict__ es,
                                                 const float* __restrict__ ed,
                                                 const float* __restrict__ b,
                                                 u16* __restrict__ out, int n,
                                                 int do_relu) {
    int wave = threadIdx.x >> 6, lane = threadIdx.x & 63;
    int i = blockIdx.x * 4 + wave;
    if (i >= n) return;
    int beg = rp[i], end = rp[i + 1];
    float edi = ed[i];
    float eself = lrelu(es[i] + edi);
    float m = eself;
    for (int j = beg + lane; j < end; j += 64) m = fmaxf(m, lrelu(es[col[j]] + edi));
    m = wredmax(m);
    float ssum = (lane == 0) ? __expf(eself - m) : 0.f;
    for (int j = beg + lane; j < end; j += 64) ssum += __expf(lrelu(es[col[j]] + edi) - m);
    ssum = wredsum(ssum);
    float inv = 1.0f / ssum;
    int c = lane * 4;
    float al = __expf(eself - m) * inv;
    float4 hv = ld4h(h + (size_t)i * NF + c);
    float4 acc;
    acc.x = b[c + 0] + al * hv.x;
    acc.y = b[c + 1] + al * hv.y;
    acc.z = b[c + 2] + al * hv.z;
    acc.w = b[c + 3] + al * hv.w;
    for (int j = beg; j < end; ++j) {
        int s = col[j];
        float a = __expf(lrelu(es[s] + edi) - m) * inv;
        float4 hs = ld4h(h + (size_t)s * NF + c);
        acc.x += a * hs.x;
        acc.y += a * hs.y;
        acc.z += a * hs.z;
        acc.w += a * hs.w;
    }
    if (do_relu) {
        acc.x = fmaxf(acc.x, 0.f); acc.y = fmaxf(acc.y, 0.f);
        acc.z = fmaxf(acc.z, 0.f); acc.w = fmaxf(acc.w, 0.f);
    }
    st4h(out + (size_t)i * NF + c, acc);
}

// ---------------- final: relu(bn(cat(x,h))) @ w + bias -> fp32 out ----------------
__global__ void final_k(const u16* __restrict__ xp, const u16* __restrict__ hp,
                        const float* __restrict__ st, const float* __restrict__ g,
                        const float* __restrict__ be, const float* __restrict__ w,
                        const float* __restrict__ bias, float* __restrict__ out, int n) {
    int wave = threadIdx.x >> 6, lane = threadIdx.x & 63;
    int i = blockIdx.x * 4 + wave;
    if (i >= n) return;
    const u16* src = (lane < 32) ? (xp + (size_t)i * NF + lane * 8)
                                 : (hp + (size_t)i * NF + (lane - 32) * 8);
    uint4 u = *(const uint4*)src;
    float vv[8];
    vv[0] = bf2f((u16)(u.x & 0xFFFFu)); vv[1] = bf2f((u16)(u.x >> 16));
    vv[2] = bf2f((u16)(u.y & 0xFFFFu)); vv[3] = bf2f((u16)(u.y >> 16));
    vv[4] = bf2f((u16)(u.z & 0xFFFFu)); vv[5] = bf2f((u16)(u.z >> 16));
    vv[6] = bf2f((u16)(u.w & 0xFFFFu)); vv[7] = bf2f((u16)(u.w >> 16));
    int c0 = lane * 8;
    float acc = 0.f;
#pragma unroll
    for (int j = 0; j < 8; ++j) {
        int c = c0 + j;
        float v = (vv[j] - st[c]) * st[512 + c] * g[c] + be[c];
        v = fmaxf(v, 0.f);
        acc += v * w[c];
    }
    acc = wredsum(acc);
    if (lane == 0) out[i] = acc + bias[0];
}

// ---------------- host ----------------
extern "C" void kernel_launch(void* const* d_in, const int* in_sizes, int n_in,
                              void* d_out, int out_size, void* d_ws, size_t ws_size,
                              hipStream_t stream) {
    const void* x_ab = d_in[0];
    const void* x_ag = d_in[1];
    const void* W_gcn = d_in[2];
    const void* W_aggcn = d_in[6];
    const void* W_gat = d_in[10];
    const void* W_gat2 = d_in[14];
    const int* e_ab = (const int*)d_in[26];
    const int* e_ag = (const int*)d_in[27];
    const int* e_d = (const int*)d_in[28];

    const int NAB = 20000, NAG = 20000, NT = 40000;
    const int EAB = 320000, EAG = 320000, ED = 640000;

    u16* hcat = (u16*)d_ws;                     // NT*NF u16
    u16* bufA = hcat + (size_t)NT * NF;         // NT*NF u16
    u16* bufB = bufA + (size_t)NT * NF;         // NT*NF u16
    float* dinv = (float*)(bufB + (size_t)NT * NF);  // NT
    float* es = dinv + NT;                      // NT
    float* edv = es + NT;                       // NT
    float* st = edv + NT;                       // 2048
    float* prm = st + 2048;                     // 8192
    int* flag = (int*)(prm + 8192);             // 16
    int* rp_ab = flag + 16;                     // NAB+1
    int* rp_ag = rp_ab + NAB + 1;               // NAG+1
    int* rp_d = rp_ag + NAG + 1;                // NT+1
    int* cnt = rp_d + NT + 1;                   // NT+1
    int* bsum = cnt + NT + 1;                   // 256
    int* col_ab = bsum + 256;                   // EAB
    int* col_ag = col_ab + EAB;                 // EAG
    int* col_d = col_ag + EAG;                  // ED

    dim3 t256(256), t512(512);

    detect_k<<<dim3(1), t256, 0, stream>>>((const u16*)x_ab, flag);
    cvt_all_k<<<dim3(25), t256, 0, stream>>>(
        d_in[3], d_in[4], d_in[5], d_in[7], d_in[8], d_in[9],
        d_in[11], d_in[12], d_in[13], d_in[15], d_in[16], d_in[17],
        d_in[22], d_in[23], d_in[24], d_in[18], d_in[19], d_in[20],
        d_in[25], d_in[21], prm, flag);

    auto build_csr = [&](const int* ei, int E, int n, int* rp, int* col) {
        int nb = (n + 255) / 256;
        zero_i_k<<<dim3((n + 256) / 256), t256, 0, stream>>>(cnt, n + 1);
        cnt_k<<<dim3((E + 255) / 256), t256, 0, stream>>>(ei + E, E, cnt);
        scan_sum_k<<<dim3(nb), t256, 0, stream>>>(cnt, bsum, n);
        scan_base_k<<<dim3(1), t256, 0, stream>>>(bsum, nb, rp + n);
        scan_fin_k<<<dim3(nb), t256, 0, stream>>>(cnt, bsum, rp, n);
        zero_i_k<<<dim3((n + 256) / 256), t256, 0, stream>>>(cnt, n + 1);
        scatter_k<<<dim3((E + 255) / 256), t256, 0, stream>>>(ei, E, rp, cnt, col);
    };
    build_csr(e_ab, EAB, NAB, rp_ab, col_ab);
    build_csr(e_ag, EAG, NAG, rp_ag, col_ag);
    build_csr(e_d, ED, NT, rp_d, col_d);

    auto gemm = [&](const void* A, int amode, const void* W, u16* C, int M) {
        gemm_mfma_k<<<dim3((M + 63) / 64, 4), t256, 0, stream>>>(A, amode, W, flag, C, M);
    };

    auto gcn = [&](const void* x, const void* W, const int* rp, const int* col,
                   int pb, int pg, int pbe, int n, u16* hout) {
        gemm(x, 2, W, bufA, n);
        dinv_k<<<dim3((n + 255) / 256), t256, 0, stream>>>(rp, dinv, n);
        gcn_csr_k<<<dim3((n + 3) / 4), t256, 0, stream>>>(bufA, rp, col, dinv, prm + pb, bufB, n);
        fill_k<<<dim3(4), t256, 0, stream>>>(st, 0.f, 1024);
        bn_stats_k<<<dim3((n + 127) / 128), t256, 0, stream>>>(bufB, n, st, st + 256);
        bn_fin_k<<<dim3(1), t256, 0, stream>>>(st, n, 256);
        bn_apply_k<<<dim3(n), t256, 0, stream>>>(bufB, st, prm + pg, prm + pbe, hout, n);
    };

    auto gat = [&](const u16* xin, const void* W, int pas, int pad, int pb,
                   int do_relu, u16* xout) {
        gemm((const void*)xin, 1, W, bufA, NT);
        gat_scores_k<<<dim3((NT + 3) / 4), t256, 0, stream>>>(bufA, prm + pas, prm + pad, es, edv, NT);
        gat_csr_k<<<dim3((NT + 3) / 4), t256, 0, stream>>>(bufA, rp_d, col_d, es, edv,
                                                           prm + pb, xout, NT, do_relu);
    };

    auto finstage = [&](const u16* xp, const u16* hp, int pg, int pbe,
                        int pw, int pbias, float* outp, int n) {
        fill_k<<<dim3(4), t256, 0, stream>>>(st, 0.f, 1024);
        bn_stats_cat_k<<<dim3((n + 127) / 128), t512, 0, stream>>>(xp, hp, n, st, st + 512);
        bn_fin_k<<<dim3(2), t256, 0, stream>>>(st, n, 512);
        final_k<<<dim3((n + 3) / 4), t256, 0, stream>>>(xp, hp, st, prm + pg, prm + pbe,
                                                        prm + pw, prm + pbias, outp, n);
    };

    gcn(x_ab, W_gcn, rp_ab, col_ab, P_BGCN, P_G1, P_BE1, NAB, hcat);
    gcn(x_ag, W_aggcn, rp_ag, col_ag, P_BAGG, P_AGG1, P_AGBE1, NAG, hcat + (size_t)NAB * NF);
    gat(hcat, W_gat, P_ASRC, P_ADST, P_BGAT, 1, bufB);
    gat(bufB, W_gat2, P_ASRC2, P_ADST2, P_BGAT2, 0, bufB);
    float* outp = (float*)d_out;
    finstage(bufB, hcat, P_G2, P_BE2, P_WFC, P_BFC, outp, NAB);
    finstage(bufB + (size_t)NAB * NF, hcat + (size_t)NAB * NF, P_AGG2, P_AGBE2,
             P_WAGFC, P_BAGFC, outp + NAB, NAG);
}

// Round 9
// 973.217 us; speedup vs baseline: 7.7651x; 1.0050x over previous
//
#include <hip/hip_runtime.h>
#include <hip/hip_bf16.h>
#include <stdint.h>

#define NF 256
#define EPSV 1e-5f

typedef unsigned short u16;
typedef short short8 __attribute__((ext_vector_type(8)));
typedef float floatx4 __attribute__((ext_vector_type(4)));

// param block offsets (floats): 12 x 256, then 6 x 512, then 2 x 1
#define P_BGCN 0
#define P_G1 256
#define P_BE1 512
#define P_BAGG 768
#define P_AGG1 1024
#define P_AGBE1 1280
#define P_ASRC 1536
#define P_ADST 1792
#define P_BGAT 2048
#define P_ASRC2 2304
#define P_ADST2 2560
#define P_BGAT2 2816
#define P_G2 3072
#define P_BE2 3584
#define P_WFC 4096
#define P_AGG2 4608
#define P_AGBE2 5120
#define P_WAGFC 5632
#define P_BFC 6144
#define P_BAGFC 6145

__device__ __forceinline__ float bf2f(u16 u) {
    union { unsigned int i; float f; } v; v.i = ((unsigned int)u) << 16; return v.f;
}
__device__ __forceinline__ u16 f2bf(float f) {
    unsigned int x = __float_as_uint(f);
    unsigned int r = x + 0x7fffu + ((x >> 16) & 1u);
    return (u16)(r >> 16);
}
__device__ __forceinline__ float sane(float f) {
    return (f == f && fabsf(f) < 1e30f) ? f : 0.f;
}
__device__ __forceinline__ unsigned int zap2(unsigned int w) {
    if ((w & 0x00007F80u) == 0x00007F80u) w &= 0xFFFF0000u;
    if ((w & 0x7F800000u) == 0x7F800000u) w &= 0x0000FFFFu;
    return w;
}
__device__ __forceinline__ float lrelu(float x) { return x > 0.f ? x : 0.2f * x; }

__device__ __forceinline__ float4 ld4h(const u16* p) {
    uint2 u = *(const uint2*)p;
    float4 r;
    r.x = bf2f((u16)(u.x & 0xFFFFu)); r.y = bf2f((u16)(u.x >> 16));
    r.z = bf2f((u16)(u.y & 0xFFFFu)); r.w = bf2f((u16)(u.y >> 16));
    return r;
}
__device__ __forceinline__ void st4h(u16* p, float4 v) {
    uint2 u;
    u.x = (unsigned)f2bf(v.x) | ((unsigned)f2bf(v.y) << 16);
    u.y = (unsigned)f2bf(v.z) | ((unsigned)f2bf(v.w) << 16);
    *(uint2*)p = u;
}

__device__ __forceinline__ float wredmax(float v) {
#pragma unroll
    for (int o = 32; o > 0; o >>= 1) v = fmaxf(v, __shfl_xor(v, o, 64));
    return v;
}
__device__ __forceinline__ float wredsum(float v) {
#pragma unroll
    for (int o = 32; o > 0; o >>= 1) v += __shfl_xor(v, o, 64);
    return v;
}
__device__ __forceinline__ int wscan_incl(int x, int lane) {
#pragma unroll
    for (int o = 1; o < 64; o <<= 1) {
        int t = __shfl_up(x, o, 64);
        if (lane >= o) x += t;
    }
    return x;
}

// ---------------- dtype detect ----------------
__global__ void detect_k(const u16* __restrict__ x, int* __restrict__ flag) {
    __shared__ int cnt;
    if (threadIdx.x == 0) cnt = 0;
    __syncthreads();
    int c = 0;
#pragma unroll
    for (int k = 0; k < 4; ++k) {
        unsigned int u = x[2 * (threadIdx.x + 256 * k)];
        int e = (int)((u >> 7) & 0xFFu);
        if (u == 0u || (e >= 100 && e <= 140)) c++;
    }
    atomicAdd(&cnt, c);
    __syncthreads();
    if (threadIdx.x == 0) flag[0] = (cnt >= 512) ? 1 : 0;
}

// ---------------- single param-conversion kernel ----------------
__global__ void cvt_all_k(const void* p0, const void* p1, const void* p2, const void* p3,
                          const void* p4, const void* p5, const void* p6, const void* p7,
                          const void* p8, const void* p9, const void* p10, const void* p11,
                          const void* p12, const void* p13, const void* p14, const void* p15,
                          const void* p16, const void* p17, const void* p18, const void* p19,
                          float* __restrict__ prm, const int* __restrict__ flagp) {
    const void* ptrs[20] = {p0, p1, p2, p3, p4, p5, p6, p7, p8, p9,
                            p10, p11, p12, p13, p14, p15, p16, p17, p18, p19};
    int idx = blockIdx.x * 256 + threadIdx.x;
    if (idx >= 6146) return;
    int t, j;
    if (idx < 3072) { t = idx >> 8; j = idx & 255; }
    else if (idx < 6144) { t = 12 + ((idx - 3072) >> 9); j = (idx - 3072) & 511; }
    else { t = 18 + (idx - 6144); j = 0; }
    const void* src = ptrs[t];
    float v = flagp[0] ? bf2f(((const u16*)src)[j]) : ((const float*)src)[j];
    prm[idx] = sane(v);
}

// ---------------- weight transpose: Wt[n][k] = bf16(W[k][n]), all 4 weights ----------------
__global__ void transpose4_k(const void* w0, const void* w1, const void* w2, const void* w3,
                             u16* __restrict__ wt, const int* __restrict__ flagp) {
    __shared__ u16 tile[16][17];
    const void* ws[4] = {w0, w1, w2, w3};
    int f = flagp[0];
    int wi = blockIdx.z;
    const void* W = ws[wi];
    int tx = threadIdx.x, ty = threadIdx.y;
    int bx = blockIdx.x, by = blockIdx.y;
    int idx = (by * 16 + ty) * NF + bx * 16 + tx;
    u16 v;
    if (f) {
        v = ((const u16*)W)[idx];
        if ((v & 0x7F80u) == 0x7F80u) v = 0;
    } else {
        v = f2bf(sane(((const float*)W)[idx]));
    }
    tile[ty][tx] = v;
    __syncthreads();
    wt[(size_t)wi * NF * NF + (bx * 16 + ty) * NF + by * 16 + tx] = tile[tx][ty];
}

// ---------------- utility ----------------
__global__ void fill_k(float* __restrict__ p, float v, int n) {
    int i = blockIdx.x * 256 + threadIdx.x;
    if (i < n) p[i] = v;
}
__global__ void zero_i_k(int* __restrict__ p, int n) {
    int i = blockIdx.x * 256 + threadIdx.x;
    if (i < n) p[i] = 0;
}

// ---------------- CSR build ----------------
__global__ void cnt_k(const int* __restrict__ dst, int E, int* __restrict__ cnt) {
    int e = blockIdx.x * 256 + threadIdx.x;
    if (e < E) atomicAdd(&cnt[dst[e]], 1);
}
__global__ __launch_bounds__(256) void scan_sum_k(const int* __restrict__ cnt,
                                                  int* __restrict__ bsum, int n) {
    __shared__ int wp[4];
    int i = blockIdx.x * 256 + threadIdx.x;
    int lane = threadIdx.x & 63, wave = threadIdx.x >> 6;
    int v = (i < n) ? cnt[i] : 0;
#pragma unroll
    for (int o = 32; o > 0; o >>= 1) v += __shfl_xor(v, o, 64);
    if (lane == 0) wp[wave] = v;
    __syncthreads();
    if (threadIdx.x == 0) bsum[blockIdx.x] = wp[0] + wp[1] + wp[2] + wp[3];
}
__global__ __launch_bounds__(256) void scan_base_k(int* __restrict__ bsum, int nb,
                                                   int* __restrict__ rp_n) {
    __shared__ int wp[4];
    int lane = threadIdx.x & 63, wave = threadIdx.x >> 6;
    int v = (threadIdx.x < nb) ? bsum[threadIdx.x] : 0;
    int x = wscan_incl(v, lane);
    if (lane == 63) wp[wave] = x;
    __syncthreads();
    int off = 0;
#pragma unroll
    for (int w = 0; w < 4; ++w) off += (w < wave) ? wp[w] : 0;
    if (threadIdx.x < nb) bsum[threadIdx.x] = off + x - v;
    if (threadIdx.x == 0) *rp_n = wp[0] + wp[1] + wp[2] + wp[3];
}
__global__ __launch_bounds__(256) void scan_fin_k(const int* __restrict__ cnt,
                                                  const int* __restrict__ bsum,
                                                  int* __restrict__ rp, int n) {
    __shared__ int wp[4];
    int i = blockIdx.x * 256 + threadIdx.x;
    int lane = threadIdx.x & 63, wave = threadIdx.x >> 6;
    int v = (i < n) ? cnt[i] : 0;
    int x = wscan_incl(v, lane);
    if (lane == 63) wp[wave] = x;
    __syncthreads();
    int off = 0;
#pragma unroll
    for (int w = 0; w < 4; ++w) off += (w < wave) ? wp[w] : 0;
    if (i < n) rp[i] = bsum[blockIdx.x] + off + x - v;
}
__global__ void scatter_k(const int* __restrict__ ei, int E, const int* __restrict__ rp,
                          int* __restrict__ cur, int* __restrict__ col) {
    int e = blockIdx.x * 256 + threadIdx.x;
    if (e >= E) return;
    int s = ei[e], d = ei[E + e];
    int p = atomicAdd(&cur[d], 1);
    col[rp[d] + p] = s;
}
__global__ void dinv_k(const int* __restrict__ rp, float* __restrict__ dinv, int n) {
    int i = blockIdx.x * 256 + threadIdx.x;
    if (i < n) dinv[i] = rsqrtf((float)(rp[i + 1] - rp[i] + 1));
}

// ---------------- LDS-free MFMA GEMM: C(Mx256 bf16) = A(Mx256) @ W(256x256) ----------------
// One block = 64 rows x 256 cols. Wave w: rows 64*bx + 16*w + {frag}. B-frags direct from
// Wt (L1/L2-resident, 16KB working set per k-strip). No LDS, no barriers.
// amode: 2 = raw input (dtype per flag), 1 = bf16 ws buffer.
__global__ __launch_bounds__(256) void gemm_n_k(const void* __restrict__ Aptr, int amode,
                                                const u16* __restrict__ Wt,
                                                const int* __restrict__ flagp,
                                                u16* __restrict__ C, int M) {
    int f = flagp[0];
    int abf = (amode == 1) ? 1 : f;
    int wave = threadIdx.x >> 6, lane = threadIdx.x & 63;
    int lr = lane & 15, q = lane >> 4;
    int arow = blockIdx.x * 64 + wave * 16 + lr;
    bool rok = arow < M;
    floatx4 acc[16];
#pragma unroll
    for (int nf = 0; nf < 16; ++nf) acc[nf] = (floatx4){0.f, 0.f, 0.f, 0.f};

    const u16* a16 = (const u16*)Aptr + (size_t)arow * NF;
    const float* a32 = (const float*)Aptr + (size_t)arow * NF;

#pragma unroll
    for (int k0 = 0; k0 < 256; k0 += 32) {
        int kk = k0 + q * 8;
        union { u16 s[8]; uint4 u; short8 v; } a;
        if (!rok) {
            a.u = make_uint4(0u, 0u, 0u, 0u);
        } else if (abf) {
            a.u = *(const uint4*)(a16 + kk);
            if (amode == 2) { a.u.x = zap2(a.u.x); a.u.y = zap2(a.u.y);
                              a.u.z = zap2(a.u.z); a.u.w = zap2(a.u.w); }
        } else {
            float4 f0 = *(const float4*)(a32 + kk);
            float4 f1 = *(const float4*)(a32 + kk + 4);
            a.s[0] = f2bf(sane(f0.x)); a.s[1] = f2bf(sane(f0.y));
            a.s[2] = f2bf(sane(f0.z)); a.s[3] = f2bf(sane(f0.w));
            a.s[4] = f2bf(sane(f1.x)); a.s[5] = f2bf(sane(f1.y));
            a.s[6] = f2bf(sane(f1.z)); a.s[7] = f2bf(sane(f1.w));
        }
#pragma unroll
        for (int nf = 0; nf < 16; ++nf) {
            short8 b = *(const short8*)(Wt + (size_t)(nf * 16 + lr) * NF + kk);
            acc[nf] = __builtin_amdgcn_mfma_f32_16x16x32_bf16(a.v, b, acc[nf], 0, 0, 0);
        }
    }
#pragma unroll
    for (int nf = 0; nf < 16; ++nf) {
#pragma unroll
        for (int rr = 0; rr < 4; ++rr) {
            int gr = blockIdx.x * 64 + wave * 16 + q * 4 + rr;
            if (gr < M) C[(size_t)gr * NF + nf * 16 + lr] = f2bf(acc[nf][rr]);
        }
    }
}

// ---------------- GCN via CSR: one wave per node (bf16 h, bf16 out) ----------------
__global__ __launch_bounds__(256) void gcn_csr_k(const u16* __restrict__ h,
                                                 const int* __restrict__ rp,
                                                 const int* __restrict__ col,
                                                 const float* __restrict__ dinv,
                                                 const float* __restrict__ b,
                                                 u16* __restrict__ out, int n) {
    int wave = threadIdx.x >> 6, lane = threadIdx.x & 63;
    int i = blockIdx.x * 4 + wave;
    if (i >= n) return;
    int c = lane * 4;
    int beg = rp[i], end = rp[i + 1];
    float di = dinv[i];
    float4 hv = ld4h(h + (size_t)i * NF + c);
    float w = di * di;
    float4 acc;
    acc.x = hv.x * w + b[c + 0];
    acc.y = hv.y * w + b[c + 1];
    acc.z = hv.z * w + b[c + 2];
    acc.w = hv.w * w + b[c + 3];
    for (int j = beg; j < end; ++j) {
        int s = col[j];
        float nrm = dinv[s] * di;
        float4 hs = ld4h(h + (size_t)s * NF + c);
        acc.x += hs.x * nrm;
        acc.y += hs.y * nrm;
        acc.z += hs.z * nrm;
        acc.w += hs.w * nrm;
    }
    st4h(out + (size_t)i * NF + c, acc);
}

// ---------------- BN (bf16 inputs) ----------------
__global__ void bn_stats_k(const u16* __restrict__ x, int n,
                           float* __restrict__ sum, float* __restrict__ sumsq) {
    int c = threadIdx.x;
    int r0 = blockIdx.x * 128;
    int rend = min(r0 + 128, n);
    float s = 0.f, qq = 0.f;
    for (int r = r0; r < rend; ++r) {
        float v = bf2f(x[(size_t)r * NF + c]);
        s += v; qq += v * v;
    }
    atomicAdd(&sum[c], s);
    atomicAdd(&sumsq[c], qq);
}
__global__ void bn_stats_cat_k(const u16* __restrict__ xa, const u16* __restrict__ xb,
                               int n, float* __restrict__ sum, float* __restrict__ sumsq) {
    int c = threadIdx.x;  // 512
    int r0 = blockIdx.x * 128;
    int rend = min(r0 + 128, n);
    const u16* src = (c < 256) ? xa : xb;
    int cc = c & 255;
    float s = 0.f, qq = 0.f;
    for (int r = r0; r < rend; ++r) {
        float v = bf2f(src[(size_t)r * NF + cc]);
        s += v; qq += v * v;
    }
    atomicAdd(&sum[c], s);
    atomicAdd(&sumsq[c], qq);
}
__global__ void bn_fin_k(float* __restrict__ st, int n, int C) {
    int c = blockIdx.x * 256 + threadIdx.x;
    if (c >= C) return;
    float inv_n = 1.0f / (float)n;
    float mean = st[c] * inv_n;
    float var = fmaxf(st[C + c] * inv_n - mean * mean, 0.f);
    st[c] = mean;
    st[C + c] = rsqrtf(var + EPSV);
}
__global__ void bn_apply_k(const u16* __restrict__ x, const float* __restrict__ st,
                           const float* __restrict__ g, const float* __restrict__ be,
                           u16* __restrict__ out, int n) {
    int t = blockIdx.x * 256 + threadIdx.x;
    if (t >= n * NF) return;
    int c = t & 255;
    float v = (bf2f(x[t]) - st[c]) * st[256 + c] * g[c] + be[c];
    out[t] = f2bf(fmaxf(v, 0.f));
}

// ---------------- GAT scores (bf16 h) ----------------
__global__ void gat_scores_k(const u16* __restrict__ h, const float* __restrict__ as_,
                             const float* __restrict__ ad_, float* __restrict__ es,
                             float* __restrict__ ed, int n) {
    int wave = threadIdx.x >> 6, lane = threadIdx.x & 63;
    int i = blockIdx.x * 4 + wave;
    if (i >= n) return;
    int c = lane * 4;
    float4 hv = ld4h(h + (size_t)i * NF + c);
    float s1 = hv.x * as_[c] + hv.y * as_[c + 1] + hv.z * as_[c + 2] + hv.w * as_[c + 3];
    float s2 = hv.x * ad_[c] + hv.y * ad_[c + 1] + hv.z * ad_[c + 2] + hv.w * ad_[c + 3];
    s1 = wredsum(s1);
    s2 = wredsum(s2);
    if (lane == 0) { es[i] = s1; ed[i] = s2; }
}

// ---------------- fused GAT aggregation via CSR (bf16 h/out) ----------------
__global__ __launch_bounds__(256) void gat_csr_k(const u16* __restrict__ h,
                                                 const int* __restrict__ rp,
                                                 const int* __restrict__ col,
                                                 const float* __restrict__ es,
                                                 const float* __restrict__ ed,
                                                 const float* __restrict__ b,
                                                 u16* __restrict__ out, int n,
                                                 int do_relu) {
    int wave = threadIdx.x >> 6, lane = threadIdx.x & 63;
    int i = blockIdx.x * 4 + wave;
    if (i >= n) return;
    int beg = rp[i], end = rp[i + 1];
    float edi = ed[i];
    float eself = lrelu(es[i] + edi);
    float m = eself;
    for (int j = beg + lane; j < end; j += 64) m = fmaxf(m, lrelu(es[col[j]] + edi));
    m = wredmax(m);
    float ssum = (lane == 0) ? __expf(eself - m) : 0.f;
    for (int j = beg + lane; j < end; j += 64) ssum += __expf(lrelu(es[col[j]] + edi) - m);
    ssum = wredsum(ssum);
    float inv = 1.0f / ssum;
    int c = lane * 4;
    float al = __expf(eself - m) * inv;
    float4 hv = ld4h(h + (size_t)i * NF + c);
    float4 acc;
    acc.x = b[c + 0] + al * hv.x;
    acc.y = b[c + 1] + al * hv.y;
    acc.z = b[c + 2] + al * hv.z;
    acc.w = b[c + 3] + al * hv.w;
    for (int j = beg; j < end; ++j) {
        int s = col[j];
        float a = __expf(lrelu(es[s] + edi) - m) * inv;
        float4 hs = ld4h(h + (size_t)s * NF + c);
        acc.x += a * hs.x;
        acc.y += a * hs.y;
        acc.z += a * hs.z;
        acc.w += a * hs.w;
    }
    if (do_relu) {
        acc.x = fmaxf(acc.x, 0.f); acc.y = fmaxf(acc.y, 0.f);
        acc.z = fmaxf(acc.z, 0.f); acc.w = fmaxf(acc.w, 0.f);
    }
    st4h(out + (size_t)i * NF + c, acc);
}

// ---------------- final: relu(bn(cat(x,h))) @ w + bias -> fp32 out ----------------
__global__ void final_k(const u16* __restrict__ xp, const u16* __restrict__ hp,
                        const float* __restrict__ st, const float* __restrict__ g,
                        const float* __restrict__ be, const float* __restrict__ w,
                        const float* __restrict__ bias, float* __restrict__ out, int n) {
    int wave = threadIdx.x >> 6, lane = threadIdx.x & 63;
    int i = blockIdx.x * 4 + wave;
    if (i >= n) return;
    const u16* src = (lane < 32) ? (xp + (size_t)i * NF + lane * 8)
                                 : (hp + (size_t)i * NF + (lane - 32) * 8);
    uint4 u = *(const uint4*)src;
    float vv[8];
    vv[0] = bf2f((u16)(u.x & 0xFFFFu)); vv[1] = bf2f((u16)(u.x >> 16));
    vv[2] = bf2f((u16)(u.y & 0xFFFFu)); vv[3] = bf2f((u16)(u.y >> 16));
    vv[4] = bf2f((u16)(u.z & 0xFFFFu)); vv[5] = bf2f((u16)(u.z >> 16));
    vv[6] = bf2f((u16)(u.w & 0xFFFFu)); vv[7] = bf2f((u16)(u.w >> 16));
    int c0 = lane * 8;
    float acc = 0.f;
#pragma unroll
    for (int j = 0; j < 8; ++j) {
        int c = c0 + j;
        float v = (vv[j] - st[c]) * st[512 + c] * g[c] + be[c];
        v = fmaxf(v, 0.f);
        acc += v * w[c];
    }
    acc = wredsum(acc);
    if (lane == 0) out[i] = acc + bias[0];
}

// ---------------- host ----------------
extern "C" void kernel_launch(void* const* d_in, const int* in_sizes, int n_in,
                              void* d_out, int out_size, void* d_ws, size_t ws_size,
                              hipStream_t stream) {
    const void* x_ab = d_in[0];
    const void* x_ag = d_in[1];
    const int* e_ab = (const int*)d_in[26];
    const int* e_ag = (const int*)d_in[27];
    const int* e_d = (const int*)d_in[28];

    const int NAB = 20000, NAG = 20000, NT = 40000;
    const int EAB = 320000, EAG = 320000, ED = 640000;

    u16* hcat = (u16*)d_ws;                     // NT*NF u16
    u16* bufA = hcat + (size_t)NT * NF;         // NT*NF u16
    u16* bufB = bufA + (size_t)NT * NF;         // NT*NF u16
    u16* wt4 = bufB + (size_t)NT * NF;          // 4*NF*NF u16
    float* dinv = (float*)(wt4 + 4 * NF * NF);  // NT
    float* es = dinv + NT;                      // NT
    float* edv = es + NT;                       // NT
    float* st = edv + NT;                       // 2048
    float* prm = st + 2048;                     // 8192
    int* flag = (int*)(prm + 8192);             // 16
    int* rp_ab = flag + 16;                     // NAB+1
    int* rp_ag = rp_ab + NAB + 1;               // NAG+1
    int* rp_d = rp_ag + NAG + 1;                // NT+1
    int* cnt = rp_d + NT + 1;                   // NT+1
    int* bsum = cnt + NT + 1;                   // 256
    int* col_ab = bsum + 256;                   // EAB
    int* col_ag = col_ab + EAB;                 // EAG
    int* col_d = col_ag + EAG;                  // ED

    u16* wt_gcn = wt4;
    u16* wt_aggcn = wt4 + NF * NF;
    u16* wt_gat = wt4 + 2 * NF * NF;
    u16* wt_gat2 = wt4 + 3 * NF * NF;

    dim3 t256(256), t512(512), t16(16, 16);

    detect_k<<<dim3(1), t256, 0, stream>>>((const u16*)x_ab, flag);
    cvt_all_k<<<dim3(25), t256, 0, stream>>>(
        d_in[3], d_in[4], d_in[5], d_in[7], d_in[8], d_in[9],
        d_in[11], d_in[12], d_in[13], d_in[15], d_in[16], d_in[17],
        d_in[22], d_in[23], d_in[24], d_in[18], d_in[19], d_in[20],
        d_in[25], d_in[21], prm, flag);
    transpose4_k<<<dim3(16, 16, 4), t16, 0, stream>>>(d_in[2], d_in[6], d_in[10], d_in[14],
                                                      wt4, flag);

    auto build_csr = [&](const int* ei, int E, int n, int* rp, int* col) {
        int nb = (n + 255) / 256;
        zero_i_k<<<dim3((n + 256) / 256), t256, 0, stream>>>(cnt, n + 1);
        cnt_k<<<dim3((E + 255) / 256), t256, 0, stream>>>(ei + E, E, cnt);
        scan_sum_k<<<dim3(nb), t256, 0, stream>>>(cnt, bsum, n);
        scan_base_k<<<dim3(1), t256, 0, stream>>>(bsum, nb, rp + n);
        scan_fin_k<<<dim3(nb), t256, 0, stream>>>(cnt, bsum, rp, n);
        zero_i_k<<<dim3((n + 256) / 256), t256, 0, stream>>>(cnt, n + 1);
        scatter_k<<<dim3((E + 255) / 256), t256, 0, stream>>>(ei, E, rp, cnt, col);
    };
    build_csr(e_ab, EAB, NAB, rp_ab, col_ab);
    build_csr(e_ag, EAG, NAG, rp_ag, col_ag);
    build_csr(e_d, ED, NT, rp_d, col_d);

    auto gemm = [&](const void* A, int amode, const u16* Wt, u16* C, int M) {
        gemm_n_k<<<dim3((M + 63) / 64), t256, 0, stream>>>(A, amode, Wt, flag, C, M);
    };

    auto gcn = [&](const void* x, const u16* Wt, const int* rp, const int* col,
                   int pb, int pg, int pbe, int n, u16* hout) {
        gemm(x, 2, Wt, bufA, n);
        dinv_k<<<dim3((n + 255) / 256), t256, 0, stream>>>(rp, dinv, n);
        gcn_csr_k<<<dim3((n + 3) / 4), t256, 0, stream>>>(bufA, rp, col, dinv, prm + pb, bufB, n);
        fill_k<<<dim3(4), t256, 0, stream>>>(st, 0.f, 1024);
        bn_stats_k<<<dim3((n + 127) / 128), t256, 0, stream>>>(bufB, n, st, st + 256);
        bn_fin_k<<<dim3(1), t256, 0, stream>>>(st, n, 256);
        bn_apply_k<<<dim3(n), t256, 0, stream>>>(bufB, st, prm + pg, prm + pbe, hout, n);
    };

    auto gat = [&](const u16* xin, const u16* Wt, int pas, int pad, int pb,
                   int do_relu, u16* xout) {
        gemm((const void*)xin, 1, Wt, bufA, NT);
        gat_scores_k<<<dim3((NT + 3) / 4), t256, 0, stream>>>(bufA, prm + pas, prm + pad, es, edv, NT);
        gat_csr_k<<<dim3((NT + 3) / 4), t256, 0, stream>>>(bufA, rp_d, col_d, es, edv,
                                                           prm + pb, xout, NT, do_relu);
    };

    auto finstage = [&](const u16* xp, const u16* hp, int pg, int pbe,
                        int pw, int pbias, float* outp, int n) {
        fill_k<<<dim3(4), t256, 0, stream>>>(st, 0.f, 1024);
        bn_stats_cat_k<<<dim3((n + 127) / 128), t512, 0, stream>>>(xp, hp, n, st, st + 512);
        bn_fin_k<<<dim3(2), t256, 0, stream>>>(st, n, 512);
        final_k<<<dim3((n + 3) / 4), t256, 0, stream>>>(xp, hp, st, prm + pg, prm + pbe,
                                                        prm + pw, prm + pbias, outp, n);
    };

    gcn(x_ab, wt_gcn, rp_ab, col_ab, P_BGCN, P_G1, P_BE1, NAB, hcat);
    gcn(x_ag, wt_aggcn, rp_ag, col_ag, P_BAGG, P_AGG1, P_AGBE1, NAG, hcat + (size_t)NAB * NF);
    gat(hcat, wt_gat, P_ASRC, P_ADST, P_BGAT, 1, bufB);
    gat(bufB, wt_gat2, P_ASRC2, P_ADST2, P_BGAT2, 0, bufB);
    float* outp = (float*)d_out;
    finstage(bufB, hcat, P_G2, P_BE2, P_WFC, P_BFC, outp, NAB);
    finstage(bufB + (size_t)NAB * NF, hcat + (size_t)NAB * NF, P_AGG2, P_AGBE2,
             P_WAGFC, P_BAGFC, outp + NAB, NAG);
}

// Round 10
// 755.070 us; speedup vs baseline: 10.0085x; 1.2889x over previous
//
#include <hip/hip_runtime.h>
#include <hip/hip_bf16.h>
#include <stdint.h>

#define NF 256
#define EPSV 1e-5f

typedef unsigned short u16;
typedef short short8 __attribute__((ext_vector_type(8)));
typedef float floatx4 __attribute__((ext_vector_type(4)));

// param block offsets (floats): 12 x 256, then 6 x 512, then 2 x 1
#define P_BGCN 0
#define P_G1 256
#define P_BE1 512
#define P_BAGG 768
#define P_AGG1 1024
#define P_AGBE1 1280
#define P_ASRC 1536
#define P_ADST 1792
#define P_BGAT 2048
#define P_ASRC2 2304
#define P_ADST2 2560
#define P_BGAT2 2816
#define P_G2 3072
#define P_BE2 3584
#define P_WFC 4096
#define P_AGG2 4608
#define P_AGBE2 5120
#define P_WAGFC 5632
#define P_BFC 6144
#define P_BAGFC 6145

__device__ __forceinline__ float bf2f(u16 u) {
    union { unsigned int i; float f; } v; v.i = ((unsigned int)u) << 16; return v.f;
}
__device__ __forceinline__ u16 f2bf(float f) {
    unsigned int x = __float_as_uint(f);
    unsigned int r = x + 0x7fffu + ((x >> 16) & 1u);
    return (u16)(r >> 16);
}
__device__ __forceinline__ float sane(float f) {
    return (f == f && fabsf(f) < 1e30f) ? f : 0.f;
}
__device__ __forceinline__ unsigned int zap2(unsigned int w) {
    if ((w & 0x00007F80u) == 0x00007F80u) w &= 0xFFFF0000u;
    if ((w & 0x7F800000u) == 0x7F800000u) w &= 0x0000FFFFu;
    return w;
}
__device__ __forceinline__ float lrelu(float x) { return x > 0.f ? x : 0.2f * x; }

__device__ __forceinline__ float4 ld4h(const u16* p) {
    uint2 u = *(const uint2*)p;
    float4 r;
    r.x = bf2f((u16)(u.x & 0xFFFFu)); r.y = bf2f((u16)(u.x >> 16));
    r.z = bf2f((u16)(u.y & 0xFFFFu)); r.w = bf2f((u16)(u.y >> 16));
    return r;
}
__device__ __forceinline__ void st4h(u16* p, float4 v) {
    uint2 u;
    u.x = (unsigned)f2bf(v.x) | ((unsigned)f2bf(v.y) << 16);
    u.y = (unsigned)f2bf(v.z) | ((unsigned)f2bf(v.w) << 16);
    *(uint2*)p = u;
}

__device__ __forceinline__ float wredmax(float v) {
#pragma unroll
    for (int o = 32; o > 0; o >>= 1) v = fmaxf(v, __shfl_xor(v, o, 64));
    return v;
}
__device__ __forceinline__ float wredsum(float v) {
#pragma unroll
    for (int o = 32; o > 0; o >>= 1) v += __shfl_xor(v, o, 64);
    return v;
}
__device__ __forceinline__ int wscan_incl(int x, int lane) {
#pragma unroll
    for (int o = 1; o < 64; o <<= 1) {
        int t = __shfl_up(x, o, 64);
        if (lane >= o) x += t;
    }
    return x;
}

// ---------------- dtype detect ----------------
__global__ void detect_k(const u16* __restrict__ x, int* __restrict__ flag) {
    __shared__ int cnt;
    if (threadIdx.x == 0) cnt = 0;
    __syncthreads();
    int c = 0;
#pragma unroll
    for (int k = 0; k < 4; ++k) {
        unsigned int u = x[2 * (threadIdx.x + 256 * k)];
        int e = (int)((u >> 7) & 0xFFu);
        if (u == 0u || (e >= 100 && e <= 140)) c++;
    }
    atomicAdd(&cnt, c);
    __syncthreads();
    if (threadIdx.x == 0) flag[0] = (cnt >= 512) ? 1 : 0;
}

// ---------------- single param-conversion kernel ----------------
__global__ void cvt_all_k(const void* p0, const void* p1, const void* p2, const void* p3,
                          const void* p4, const void* p5, const void* p6, const void* p7,
                          const void* p8, const void* p9, const void* p10, const void* p11,
                          const void* p12, const void* p13, const void* p14, const void* p15,
                          const void* p16, const void* p17, const void* p18, const void* p19,
                          float* __restrict__ prm, const int* __restrict__ flagp) {
    const void* ptrs[20] = {p0, p1, p2, p3, p4, p5, p6, p7, p8, p9,
                            p10, p11, p12, p13, p14, p15, p16, p17, p18, p19};
    int idx = blockIdx.x * 256 + threadIdx.x;
    if (idx >= 6146) return;
    int t, j;
    if (idx < 3072) { t = idx >> 8; j = idx & 255; }
    else if (idx < 6144) { t = 12 + ((idx - 3072) >> 9); j = (idx - 3072) & 511; }
    else { t = 18 + (idx - 6144); j = 0; }
    const void* src = ptrs[t];
    float v = flagp[0] ? bf2f(((const u16*)src)[j]) : ((const float*)src)[j];
    prm[idx] = sane(v);
}

// ---------------- weight fragment-pack: Wtf[wi][ks][nf][lane][j] ----------------
// Wtf element (ks,nf,lane=q*16+lr,j) := bf16(W[k][n]) with n=nf*16+lr, k=ks*32+q*8+j.
// B-fragment for (ks,nf) is then lane-contiguous: Wtf + ks*8192 + nf*512 + lane*8.
__global__ void wfrag_k(const void* w0, const void* w1, const void* w2, const void* w3,
                        u16* __restrict__ wtf, const int* __restrict__ flagp) {
    const void* ws[4] = {w0, w1, w2, w3};
    int f = flagp[0];
    int idx = blockIdx.x * 256 + threadIdx.x;   // 0 .. 4*65536-1
    int wi = idx >> 16;
    int rest = idx & 65535;
    int j = rest & 7;
    int lr = (rest >> 3) & 15;
    int q = (rest >> 7) & 3;
    int nf = (rest >> 9) & 15;
    int ks = (rest >> 13) & 7;
    int n = nf * 16 + lr;
    int k = ks * 32 + q * 8 + j;
    const void* W = ws[wi];
    u16 v;
    if (f) {
        v = ((const u16*)W)[k * NF + n];
        if ((v & 0x7F80u) == 0x7F80u) v = 0;
    } else {
        v = f2bf(sane(((const float*)W)[k * NF + n]));
    }
    wtf[idx] = v;
}

// ---------------- utility ----------------
__global__ void fill_k(float* __restrict__ p, float v, int n) {
    int i = blockIdx.x * 256 + threadIdx.x;
    if (i < n) p[i] = v;
}
__global__ void zero_i_k(int* __restrict__ p, int n) {
    int i = blockIdx.x * 256 + threadIdx.x;
    if (i < n) p[i] = 0;
}

// ---------------- CSR build ----------------
__global__ void cnt_k(const int* __restrict__ dst, int E, int* __restrict__ cnt) {
    int e = blockIdx.x * 256 + threadIdx.x;
    if (e < E) atomicAdd(&cnt[dst[e]], 1);
}
__global__ __launch_bounds__(256) void scan_sum_k(const int* __restrict__ cnt,
                                                  int* __restrict__ bsum, int n) {
    __shared__ int wp[4];
    int i = blockIdx.x * 256 + threadIdx.x;
    int lane = threadIdx.x & 63, wave = threadIdx.x >> 6;
    int v = (i < n) ? cnt[i] : 0;
#pragma unroll
    for (int o = 32; o > 0; o >>= 1) v += __shfl_xor(v, o, 64);
    if (lane == 0) wp[wave] = v;
    __syncthreads();
    if (threadIdx.x == 0) bsum[blockIdx.x] = wp[0] + wp[1] + wp[2] + wp[3];
}
__global__ __launch_bounds__(256) void scan_base_k(int* __restrict__ bsum, int nb,
                                                   int* __restrict__ rp_n) {
    __shared__ int wp[4];
    int lane = threadIdx.x & 63, wave = threadIdx.x >> 6;
    int v = (threadIdx.x < nb) ? bsum[threadIdx.x] : 0;
    int x = wscan_incl(v, lane);
    if (lane == 63) wp[wave] = x;
    __syncthreads();
    int off = 0;
#pragma unroll
    for (int w = 0; w < 4; ++w) off += (w < wave) ? wp[w] : 0;
    if (threadIdx.x < nb) bsum[threadIdx.x] = off + x - v;
    if (threadIdx.x == 0) *rp_n = wp[0] + wp[1] + wp[2] + wp[3];
}
__global__ __launch_bounds__(256) void scan_fin_k(const int* __restrict__ cnt,
                                                  const int* __restrict__ bsum,
                                                  int* __restrict__ rp, int n) {
    __shared__ int wp[4];
    int i = blockIdx.x * 256 + threadIdx.x;
    int lane = threadIdx.x & 63, wave = threadIdx.x >> 6;
    int v = (i < n) ? cnt[i] : 0;
    int x = wscan_incl(v, lane);
    if (lane == 63) wp[wave] = x;
    __syncthreads();
    int off = 0;
#pragma unroll
    for (int w = 0; w < 4; ++w) off += (w < wave) ? wp[w] : 0;
    if (i < n) rp[i] = bsum[blockIdx.x] + off + x - v;
}
__global__ void scatter_k(const int* __restrict__ ei, int E, const int* __restrict__ rp,
                          int* __restrict__ cur, int* __restrict__ col) {
    int e = blockIdx.x * 256 + threadIdx.x;
    if (e >= E) return;
    int s = ei[e], d = ei[E + e];
    int p = atomicAdd(&cur[d], 1);
    col[rp[d] + p] = s;
}
__global__ void dinv_k(const int* __restrict__ rp, float* __restrict__ dinv, int n) {
    int i = blockIdx.x * 256 + threadIdx.x;
    if (i < n) dinv[i] = rsqrtf((float)(rp[i + 1] - rp[i] + 1));
}

// ---------------- LDS-free MFMA GEMM, fragment-ordered B (coalesced) ----------------
// One block = 64 rows x 256 cols. B-frag load: lane-contiguous 1KB from Wtf (L1-resident).
// amode: 2 = raw input (dtype per flag), 1 = bf16 ws buffer.
__global__ __launch_bounds__(256) void gemm_n_k(const void* __restrict__ Aptr, int amode,
                                                const u16* __restrict__ Wtf,
                                                const int* __restrict__ flagp,
                                                u16* __restrict__ C, int M) {
    int f = flagp[0];
    int abf = (amode == 1) ? 1 : f;
    int wave = threadIdx.x >> 6, lane = threadIdx.x & 63;
    int lr = lane & 15, q = lane >> 4;
    int arow = blockIdx.x * 64 + wave * 16 + lr;
    bool rok = arow < M;
    floatx4 acc[16];
#pragma unroll
    for (int nf = 0; nf < 16; ++nf) acc[nf] = (floatx4){0.f, 0.f, 0.f, 0.f};

    const u16* a16 = (const u16*)Aptr + (size_t)arow * NF;
    const float* a32 = (const float*)Aptr + (size_t)arow * NF;

#pragma unroll
    for (int ks = 0; ks < 8; ++ks) {
        int kk = ks * 32 + q * 8;
        union { u16 s[8]; uint4 u; short8 v; } a;
        if (!rok) {
            a.u = make_uint4(0u, 0u, 0u, 0u);
        } else if (abf) {
            a.u = *(const uint4*)(a16 + kk);
            if (amode == 2) { a.u.x = zap2(a.u.x); a.u.y = zap2(a.u.y);
                              a.u.z = zap2(a.u.z); a.u.w = zap2(a.u.w); }
        } else {
            float4 f0 = *(const float4*)(a32 + kk);
            float4 f1 = *(const float4*)(a32 + kk + 4);
            a.s[0] = f2bf(sane(f0.x)); a.s[1] = f2bf(sane(f0.y));
            a.s[2] = f2bf(sane(f0.z)); a.s[3] = f2bf(sane(f0.w));
            a.s[4] = f2bf(sane(f1.x)); a.s[5] = f2bf(sane(f1.y));
            a.s[6] = f2bf(sane(f1.z)); a.s[7] = f2bf(sane(f1.w));
        }
        const u16* bbase = Wtf + ks * 8192 + lane * 8;
#pragma unroll
        for (int nf = 0; nf < 16; ++nf) {
            short8 b = *(const short8*)(bbase + nf * 512);
            acc[nf] = __builtin_amdgcn_mfma_f32_16x16x32_bf16(a.v, b, acc[nf], 0, 0, 0);
        }
    }
#pragma unroll
    for (int nf = 0; nf < 16; ++nf) {
#pragma unroll
        for (int rr = 0; rr < 4; ++rr) {
            int gr = blockIdx.x * 64 + wave * 16 + q * 4 + rr;
            if (gr < M) C[(size_t)gr * NF + nf * 16 + lr] = f2bf(acc[nf][rr]);
        }
    }
}

// ---------------- GCN via CSR: one wave per node, 4-way unrolled gather ----------------
__global__ __launch_bounds__(256) void gcn_csr_k(const u16* __restrict__ h,
                                                 const int* __restrict__ rp,
                                                 const int* __restrict__ col,
                                                 const float* __restrict__ dinv,
                                                 const float* __restrict__ b,
                                                 u16* __restrict__ out, int n) {
    int wave = threadIdx.x >> 6, lane = threadIdx.x & 63;
    int i = blockIdx.x * 4 + wave;
    if (i >= n) return;
    int c = lane * 4;
    int beg = rp[i], end = rp[i + 1];
    float di = dinv[i];
    float4 hv = ld4h(h + (size_t)i * NF + c);
    float w = di * di;
    float4 acc;
    acc.x = hv.x * w + b[c + 0];
    acc.y = hv.y * w + b[c + 1];
    acc.z = hv.z * w + b[c + 2];
    acc.w = hv.w * w + b[c + 3];
    int j = beg;
    for (; j + 3 < end; j += 4) {
        int s0 = col[j], s1 = col[j + 1], s2 = col[j + 2], s3 = col[j + 3];
        float n0 = dinv[s0] * di, n1 = dinv[s1] * di, n2 = dinv[s2] * di, n3 = dinv[s3] * di;
        float4 h0 = ld4h(h + (size_t)s0 * NF + c);
        float4 h1 = ld4h(h + (size_t)s1 * NF + c);
        float4 h2 = ld4h(h + (size_t)s2 * NF + c);
        float4 h3 = ld4h(h + (size_t)s3 * NF + c);
        acc.x += h0.x * n0 + h1.x * n1 + h2.x * n2 + h3.x * n3;
        acc.y += h0.y * n0 + h1.y * n1 + h2.y * n2 + h3.y * n3;
        acc.z += h0.z * n0 + h1.z * n1 + h2.z * n2 + h3.z * n3;
        acc.w += h0.w * n0 + h1.w * n1 + h2.w * n2 + h3.w * n3;
    }
    for (; j < end; ++j) {
        int s = col[j];
        float nrm = dinv[s] * di;
        float4 hs = ld4h(h + (size_t)s * NF + c);
        acc.x += hs.x * nrm;
        acc.y += hs.y * nrm;
        acc.z += hs.z * nrm;
        acc.w += hs.w * nrm;
    }
    st4h(out + (size_t)i * NF + c, acc);
}

// ---------------- BN (bf16 inputs) ----------------
__global__ void bn_stats_k(const u16* __restrict__ x, int n,
                           float* __restrict__ sum, float* __restrict__ sumsq) {
    int c = threadIdx.x;
    int r0 = blockIdx.x * 128;
    int rend = min(r0 + 128, n);
    float s = 0.f, qq = 0.f;
    for (int r = r0; r < rend; ++r) {
        float v = bf2f(x[(size_t)r * NF + c]);
        s += v; qq += v * v;
    }
    atomicAdd(&sum[c], s);
    atomicAdd(&sumsq[c], qq);
}
__global__ void bn_stats_cat_k(const u16* __restrict__ xa, const u16* __restrict__ xb,
                               int n, float* __restrict__ sum, float* __restrict__ sumsq) {
    int c = threadIdx.x;  // 512
    int r0 = blockIdx.x * 128;
    int rend = min(r0 + 128, n);
    const u16* src = (c < 256) ? xa : xb;
    int cc = c & 255;
    float s = 0.f, qq = 0.f;
    for (int r = r0; r < rend; ++r) {
        float v = bf2f(src[(size_t)r * NF + cc]);
        s += v; qq += v * v;
    }
    atomicAdd(&sum[c], s);
    atomicAdd(&sumsq[c], qq);
}
__global__ void bn_fin_k(float* __restrict__ st, int n, int C) {
    int c = blockIdx.x * 256 + threadIdx.x;
    if (c >= C) return;
    float inv_n = 1.0f / (float)n;
    float mean = st[c] * inv_n;
    float var = fmaxf(st[C + c] * inv_n - mean * mean, 0.f);
    st[c] = mean;
    st[C + c] = rsqrtf(var + EPSV);
}
__global__ void bn_apply_k(const u16* __restrict__ x, const float* __restrict__ st,
                           const float* __restrict__ g, const float* __restrict__ be,
                           u16* __restrict__ out, int n) {
    int t = blockIdx.x * 256 + threadIdx.x;
    if (t >= n * NF) return;
    int c = t & 255;
    float v = (bf2f(x[t]) - st[c]) * st[256 + c] * g[c] + be[c];
    out[t] = f2bf(fmaxf(v, 0.f));
}

// ---------------- GAT scores (bf16 h) ----------------
__global__ void gat_scores_k(const u16* __restrict__ h, const float* __restrict__ as_,
                             const float* __restrict__ ad_, float* __restrict__ es,
                             float* __restrict__ ed, int n) {
    int wave = threadIdx.x >> 6, lane = threadIdx.x & 63;
    int i = blockIdx.x * 4 + wave;
    if (i >= n) return;
    int c = lane * 4;
    float4 hv = ld4h(h + (size_t)i * NF + c);
    float s1 = hv.x * as_[c] + hv.y * as_[c + 1] + hv.z * as_[c + 2] + hv.w * as_[c + 3];
    float s2 = hv.x * ad_[c] + hv.y * ad_[c + 1] + hv.z * ad_[c + 2] + hv.w * ad_[c + 3];
    s1 = wredsum(s1);
    s2 = wredsum(s2);
    if (lane == 0) { es[i] = s1; ed[i] = s2; }
}

// ---------------- fused GAT aggregation via CSR, 4-way unrolled pass 3 ----------------
__global__ __launch_bounds__(256) void gat_csr_k(const u16* __restrict__ h,
                                                 const int* __restrict__ rp,
                                                 const int* __restrict__ col,
                                                 const float* __restrict__ es,
                                                 const float* __restrict__ ed,
                                                 const float* __restrict__ b,
                                                 u16* __restrict__ out, int n,
                                                 int do_relu) {
    int wave = threadIdx.x >> 6, lane = threadIdx.x & 63;
    int i = blockIdx.x * 4 + wave;
    if (i >= n) return;
    int beg = rp[i], end = rp[i + 1];
    float edi = ed[i];
    float eself = lrelu(es[i] + edi);
    float m = eself;
    for (int j = beg + lane; j < end; j += 64) m = fmaxf(m, lrelu(es[col[j]] + edi));
    m = wredmax(m);
    float ssum = (lane == 0) ? __expf(eself - m) : 0.f;
    for (int j = beg + lane; j < end; j += 64) ssum += __expf(lrelu(es[col[j]] + edi) - m);
    ssum = wredsum(ssum);
    float inv = 1.0f / ssum;
    int c = lane * 4;
    float al = __expf(eself - m) * inv;
    float4 hv = ld4h(h + (size_t)i * NF + c);
    float4 acc;
    acc.x = b[c + 0] + al * hv.x;
    acc.y = b[c + 1] + al * hv.y;
    acc.z = b[c + 2] + al * hv.z;
    acc.w = b[c + 3] + al * hv.w;
    int j = beg;
    for (; j + 3 < end; j += 4) {
        int s0 = col[j], s1 = col[j + 1], s2 = col[j + 2], s3 = col[j + 3];
        float e0 = es[s0], e1 = es[s1], e2 = es[s2], e3 = es[s3];
        float4 h0 = ld4h(h + (size_t)s0 * NF + c);
        float4 h1 = ld4h(h + (size_t)s1 * NF + c);
        float4 h2 = ld4h(h + (size_t)s2 * NF + c);
        float4 h3 = ld4h(h + (size_t)s3 * NF + c);
        float a0 = __expf(lrelu(e0 + edi) - m) * inv;
        float a1 = __expf(lrelu(e1 + edi) - m) * inv;
        float a2 = __expf(lrelu(e2 + edi) - m) * inv;
        float a3 = __expf(lrelu(e3 + edi) - m) * inv;
        acc.x += h0.x * a0 + h1.x * a1 + h2.x * a2 + h3.x * a3;
        acc.y += h0.y * a0 + h1.y * a1 + h2.y * a2 + h3.y * a3;
        acc.z += h0.z * a0 + h1.z * a1 + h2.z * a2 + h3.z * a3;
        acc.w += h0.w * a0 + h1.w * a1 + h2.w * a2 + h3.w * a3;
    }
    for (; j < end; ++j) {
        int s = col[j];
        float a = __expf(lrelu(es[s] + edi) - m) * inv;
        float4 hs = ld4h(h + (size_t)s * NF + c);
        acc.x += a * hs.x;
        acc.y += a * hs.y;
        acc.z += a * hs.z;
        acc.w += a * hs.w;
    }
    if (do_relu) {
        acc.x = fmaxf(acc.x, 0.f); acc.y = fmaxf(acc.y, 0.f);
        acc.z = fmaxf(acc.z, 0.f); acc.w = fmaxf(acc.w, 0.f);
    }
    st4h(out + (size_t)i * NF + c, acc);
}

// ---------------- final: relu(bn(cat(x,h))) @ w + bias -> fp32 out ----------------
__global__ void final_k(const u16* __restrict__ xp, const u16* __restrict__ hp,
                        const float* __restrict__ st, const float* __restrict__ g,
                        const float* __restrict__ be, const float* __restrict__ w,
                        const float* __restrict__ bias, float* __restrict__ out, int n) {
    int wave = threadIdx.x >> 6, lane = threadIdx.x & 63;
    int i = blockIdx.x * 4 + wave;
    if (i >= n) return;
    const u16* src = (lane < 32) ? (xp + (size_t)i * NF + lane * 8)
                                 : (hp + (size_t)i * NF + (lane - 32) * 8);
    uint4 u = *(const uint4*)src;
    float vv[8];
    vv[0] = bf2f((u16)(u.x & 0xFFFFu)); vv[1] = bf2f((u16)(u.x >> 16));
    vv[2] = bf2f((u16)(u.y & 0xFFFFu)); vv[3] = bf2f((u16)(u.y >> 16));
    vv[4] = bf2f((u16)(u.z & 0xFFFFu)); vv[5] = bf2f((u16)(u.z >> 16));
    vv[6] = bf2f((u16)(u.w & 0xFFFFu)); vv[7] = bf2f((u16)(u.w >> 16));
    int c0 = lane * 8;
    float acc = 0.f;
#pragma unroll
    for (int j = 0; j < 8; ++j) {
        int c = c0 + j;
        float v = (vv[j] - st[c]) * st[512 + c] * g[c] + be[c];
        v = fmaxf(v, 0.f);
        acc += v * w[c];
    }
    acc = wredsum(acc);
    if (lane == 0) out[i] = acc + bias[0];
}

// ---------------- host ----------------
extern "C" void kernel_launch(void* const* d_in, const int* in_sizes, int n_in,
                              void* d_out, int out_size, void* d_ws, size_t ws_size,
                              hipStream_t stream) {
    const void* x_ab = d_in[0];
    const void* x_ag = d_in[1];
    const int* e_ab = (const int*)d_in[26];
    const int* e_ag = (const int*)d_in[27];
    const int* e_d = (const int*)d_in[28];

    const int NAB = 20000, NAG = 20000, NT = 40000;
    const int EAB = 320000, EAG = 320000, ED = 640000;

    u16* hcat = (u16*)d_ws;                     // NT*NF u16
    u16* bufA = hcat + (size_t)NT * NF;         // NT*NF u16
    u16* bufB = bufA + (size_t)NT * NF;         // NT*NF u16
    u16* wt4 = bufB + (size_t)NT * NF;          // 4*NF*NF u16 (fragment-ordered)
    float* dinv = (float*)(wt4 + 4 * NF * NF);  // NT
    float* es = dinv + NT;                      // NT
    float* edv = es + NT;                       // NT
    float* st = edv + NT;                       // 2048
    float* prm = st + 2048;                     // 8192
    int* flag = (int*)(prm + 8192);             // 16
    int* rp_ab = flag + 16;                     // NAB+1
    int* rp_ag = rp_ab + NAB + 1;               // NAG+1
    int* rp_d = rp_ag + NAG + 1;                // NT+1
    int* cnt = rp_d + NT + 1;                   // NT+1
    int* bsum = cnt + NT + 1;                   // 256
    int* col_ab = bsum + 256;                   // EAB
    int* col_ag = col_ab + EAB;                 // EAG
    int* col_d = col_ag + EAG;                  // ED

    u16* wt_gcn = wt4;
    u16* wt_aggcn = wt4 + NF * NF;
    u16* wt_gat = wt4 + 2 * NF * NF;
    u16* wt_gat2 = wt4 + 3 * NF * NF;

    dim3 t256(256), t512(512);

    detect_k<<<dim3(1), t256, 0, stream>>>((const u16*)x_ab, flag);
    cvt_all_k<<<dim3(25), t256, 0, stream>>>(
        d_in[3], d_in[4], d_in[5], d_in[7], d_in[8], d_in[9],
        d_in[11], d_in[12], d_in[13], d_in[15], d_in[16], d_in[17],
        d_in[22], d_in[23], d_in[24], d_in[18], d_in[19], d_in[20],
        d_in[25], d_in[21], prm, flag);
    wfrag_k<<<dim3(1024), t256, 0, stream>>>(d_in[2], d_in[6], d_in[10], d_in[14], wt4, flag);

    auto build_csr = [&](const int* ei, int E, int n, int* rp, int* col) {
        int nb = (n + 255) / 256;
        zero_i_k<<<dim3((n + 256) / 256), t256, 0, stream>>>(cnt, n + 1);
        cnt_k<<<dim3((E + 255) / 256), t256, 0, stream>>>(ei + E, E, cnt);
        scan_sum_k<<<dim3(nb), t256, 0, stream>>>(cnt, bsum, n);
        scan_base_k<<<dim3(1), t256, 0, stream>>>(bsum, nb, rp + n);
        scan_fin_k<<<dim3(nb), t256, 0, stream>>>(cnt, bsum, rp, n);
        zero_i_k<<<dim3((n + 256) / 256), t256, 0, stream>>>(cnt, n + 1);
        scatter_k<<<dim3((E + 255) / 256), t256, 0, stream>>>(ei, E, rp, cnt, col);
    };
    build_csr(e_ab, EAB, NAB, rp_ab, col_ab);
    build_csr(e_ag, EAG, NAG, rp_ag, col_ag);
    build_csr(e_d, ED, NT, rp_d, col_d);

    auto gemm = [&](const void* A, int amode, const u16* Wt, u16* C, int M) {
        gemm_n_k<<<dim3((M + 63) / 64), t256, 0, stream>>>(A, amode, Wt, flag, C, M);
    };

    auto gcn = [&](const void* x, const u16* Wt, const int* rp, const int* col,
                   int pb, int pg, int pbe, int n, u16* hout) {
        gemm(x, 2, Wt, bufA, n);
        dinv_k<<<dim3((n + 255) / 256), t256, 0, stream>>>(rp, dinv, n);
        gcn_csr_k<<<dim3((n + 3) / 4), t256, 0, stream>>>(bufA, rp, col, dinv, prm + pb, bufB, n);
        fill_k<<<dim3(4), t256, 0, stream>>>(st, 0.f, 1024);
        bn_stats_k<<<dim3((n + 127) / 128), t256, 0, stream>>>(bufB, n, st, st + 256);
        bn_fin_k<<<dim3(1), t256, 0, stream>>>(st, n, 256);
        bn_apply_k<<<dim3(n), t256, 0, stream>>>(bufB, st, prm + pg, prm + pbe, hout, n);
    };

    auto gat = [&](const u16* xin, const u16* Wt, int pas, int pad, int pb,
                   int do_relu, u16* xout) {
        gemm((const void*)xin, 1, Wt, bufA, NT);
        gat_scores_k<<<dim3((NT + 3) / 4), t256, 0, stream>>>(bufA, prm + pas, prm + pad, es, edv, NT);
        gat_csr_k<<<dim3((NT + 3) / 4), t256, 0, stream>>>(bufA, rp_d, col_d, es, edv,
                                                           prm + pb, xout, NT, do_relu);
    };

    auto finstage = [&](const u16* xp, const u16* hp, int pg, int pbe,
                        int pw, int pbias, float* outp, int n) {
        fill_k<<<dim3(4), t256, 0, stream>>>(st, 0.f, 1024);
        bn_stats_cat_k<<<dim3((n + 127) / 128), t512, 0, stream>>>(xp, hp, n, st, st + 512);
        bn_fin_k<<<dim3(2), t256, 0, stream>>>(st, n, 512);
        final_k<<<dim3((n + 3) / 4), t256, 0, stream>>>(xp, hp, st, prm + pg, prm + pbe,
                                                        prm + pw, prm + pbias, outp, n);
    };

    gcn(x_ab, wt_gcn, rp_ab, col_ab, P_BGCN, P_G1, P_BE1, NAB, hcat);
    gcn(x_ag, wt_aggcn, rp_ag, col_ag, P_BAGG, P_AGG1, P_AGBE1, NAG, hcat + (size_t)NAB * NF);
    gat(hcat, wt_gat, P_ASRC, P_ADST, P_BGAT, 1, bufB);
    gat(bufB, wt_gat2, P_ASRC2, P_ADST2, P_BGAT2, 0, bufB);
    float* outp = (float*)d_out;
    finstage(bufB, hcat, P_G2, P_BE2, P_WFC, P_BFC, outp, NAB);
    finstage(bufB + (size_t)NAB * NF, hcat + (size_t)NAB * NF, P_AGG2, P_AGBE2,
             P_WAGFC, P_BAGFC, outp + NAB, NAG);
}

// Round 11
// 719.721 us; speedup vs baseline: 10.5000x; 1.0491x over previous
//
#include <hip/hip_runtime.h>
#include <hip/hip_bf16.h>
#include <stdint.h>

#define NF 256
#define EPSV 1e-5f
#define PB 160   // max bn partial blocks

typedef unsigned short u16;
typedef short short8 __attribute__((ext_vector_type(8)));
typedef float floatx4 __attribute__((ext_vector_type(4)));

// param block offsets (floats): 12 x 256, then 6 x 512, then 2 x 1
#define P_BGCN 0
#define P_G1 256
#define P_BE1 512
#define P_BAGG 768
#define P_AGG1 1024
#define P_AGBE1 1280
#define P_ASRC 1536
#define P_ADST 1792
#define P_BGAT 2048
#define P_ASRC2 2304
#define P_ADST2 2560
#define P_BGAT2 2816
#define P_G2 3072
#define P_BE2 3584
#define P_WFC 4096
#define P_AGG2 4608
#define P_AGBE2 5120
#define P_WAGFC 5632
#define P_BFC 6144
#define P_BAGFC 6145

__device__ __forceinline__ float bf2f(u16 u) {
    union { unsigned int i; float f; } v; v.i = ((unsigned int)u) << 16; return v.f;
}
__device__ __forceinline__ u16 f2bf(float f) {
    unsigned int x = __float_as_uint(f);
    unsigned int r = x + 0x7fffu + ((x >> 16) & 1u);
    return (u16)(r >> 16);
}
__device__ __forceinline__ float sane(float f) {
    return (f == f && fabsf(f) < 1e30f) ? f : 0.f;
}
__device__ __forceinline__ unsigned int zap2(unsigned int w) {
    if ((w & 0x00007F80u) == 0x00007F80u) w &= 0xFFFF0000u;
    if ((w & 0x7F800000u) == 0x7F800000u) w &= 0x0000FFFFu;
    return w;
}
__device__ __forceinline__ float lrelu(float x) { return x > 0.f ? x : 0.2f * x; }

__device__ __forceinline__ float4 ld4h(const u16* p) {
    uint2 u = *(const uint2*)p;
    float4 r;
    r.x = bf2f((u16)(u.x & 0xFFFFu)); r.y = bf2f((u16)(u.x >> 16));
    r.z = bf2f((u16)(u.y & 0xFFFFu)); r.w = bf2f((u16)(u.y >> 16));
    return r;
}
__device__ __forceinline__ void st4h(u16* p, float4 v) {
    uint2 u;
    u.x = (unsigned)f2bf(v.x) | ((unsigned)f2bf(v.y) << 16);
    u.y = (unsigned)f2bf(v.z) | ((unsigned)f2bf(v.w) << 16);
    *(uint2*)p = u;
}

__device__ __forceinline__ float wredmax(float v) {
#pragma unroll
    for (int o = 32; o > 0; o >>= 1) v = fmaxf(v, __shfl_xor(v, o, 64));
    return v;
}
__device__ __forceinline__ float wredsum(float v) {
#pragma unroll
    for (int o = 32; o > 0; o >>= 1) v += __shfl_xor(v, o, 64);
    return v;
}
__device__ __forceinline__ int wscan_incl(int x, int lane) {
#pragma unroll
    for (int o = 1; o < 64; o <<= 1) {
        int t = __shfl_up(x, o, 64);
        if (lane >= o) x += t;
    }
    return x;
}

// ---------------- dtype detect ----------------
__global__ void detect_k(const u16* __restrict__ x, int* __restrict__ flag) {
    __shared__ int cnt;
    if (threadIdx.x == 0) cnt = 0;
    __syncthreads();
    int c = 0;
#pragma unroll
    for (int k = 0; k < 4; ++k) {
        unsigned int u = x[2 * (threadIdx.x + 256 * k)];
        int e = (int)((u >> 7) & 0xFFu);
        if (u == 0u || (e >= 100 && e <= 140)) c++;
    }
    atomicAdd(&cnt, c);
    __syncthreads();
    if (threadIdx.x == 0) flag[0] = (cnt >= 512) ? 1 : 0;
}

// ---------------- prep: weight fragment-pack (idx<262144) + param cvt ----------------
__global__ void prep_k(const void* w0, const void* w1, const void* w2, const void* w3,
                       const void* p0, const void* p1, const void* p2, const void* p3,
                       const void* p4, const void* p5, const void* p6, const void* p7,
                       const void* p8, const void* p9, const void* p10, const void* p11,
                       const void* p12, const void* p13, const void* p14, const void* p15,
                       const void* p16, const void* p17, const void* p18, const void* p19,
                       u16* __restrict__ wtf, float* __restrict__ prm,
                       const int* __restrict__ flagp) {
    int f = flagp[0];
    int idx = blockIdx.x * 256 + threadIdx.x;
    if (idx < 262144) {
        const void* ws[4] = {w0, w1, w2, w3};
        int wi = idx >> 16;
        int rest = idx & 65535;
        int j = rest & 7;
        int lr = (rest >> 3) & 15;
        int q = (rest >> 7) & 3;
        int nf = (rest >> 9) & 15;
        int ks = (rest >> 13) & 7;
        int n = nf * 16 + lr;
        int k = ks * 32 + q * 8 + j;
        const void* W = ws[wi];
        u16 v;
        if (f) {
            v = ((const u16*)W)[k * NF + n];
            if ((v & 0x7F80u) == 0x7F80u) v = 0;
        } else {
            v = f2bf(sane(((const float*)W)[k * NF + n]));
        }
        wtf[idx] = v;
        return;
    }
    int pidx = idx - 262144;
    if (pidx >= 6146) return;
    const void* ptrs[20] = {p0, p1, p2, p3, p4, p5, p6, p7, p8, p9,
                            p10, p11, p12, p13, p14, p15, p16, p17, p18, p19};
    int t, j;
    if (pidx < 3072) { t = pidx >> 8; j = pidx & 255; }
    else if (pidx < 6144) { t = 12 + ((pidx - 3072) >> 9); j = (pidx - 3072) & 511; }
    else { t = 18 + (pidx - 6144); j = 0; }
    float v = f ? bf2f(((const u16*)ptrs[t])[j]) : ((const float*)ptrs[t])[j];
    prm[pidx] = sane(v);
}

// ---------------- utility ----------------
__global__ void zero_i_k(int* __restrict__ p, int n) {
    int i = blockIdx.x * 256 + threadIdx.x;
    if (i < n) p[i] = 0;
}

// ---------------- batched CSR build (y = graph: 0=ab, 1=ag, 2=d) ----------------
__global__ void cnt3_k(const int* e0, const int* e1, const int* e2,
                       int* __restrict__ cnt3, int NTp1) {
    int y = blockIdx.y;
    const int* ei = (y == 0) ? e0 : (y == 1) ? e1 : e2;
    int E = (y == 2) ? 640000 : 320000;
    int e = blockIdx.x * 256 + threadIdx.x;
    if (e < E) atomicAdd(&cnt3[y * NTp1 + ei[E + e]], 1);
}
__global__ __launch_bounds__(256) void scan_sum3_k(const int* __restrict__ cnt3,
                                                   int* __restrict__ bsum3, int NTp1) {
    __shared__ int wp[4];
    int y = blockIdx.y;
    int n = (y == 2) ? 40000 : 20000;
    int i = blockIdx.x * 256 + threadIdx.x;
    int lane = threadIdx.x & 63, wave = threadIdx.x >> 6;
    int v = (i < n) ? cnt3[y * NTp1 + i] : 0;
#pragma unroll
    for (int o = 32; o > 0; o >>= 1) v += __shfl_xor(v, o, 64);
    if (lane == 0) wp[wave] = v;
    __syncthreads();
    if (threadIdx.x == 0) bsum3[y * 256 + blockIdx.x] = wp[0] + wp[1] + wp[2] + wp[3];
}
__global__ __launch_bounds__(256) void scan_base3_k(int* __restrict__ bsum3,
                                                    int* rp0, int* rp1, int* rp2) {
    __shared__ int wp[4];
    int y = blockIdx.y;
    int n = (y == 2) ? 40000 : 20000;
    int nb = (n + 255) / 256;
    int* rp = (y == 0) ? rp0 : (y == 1) ? rp1 : rp2;
    int lane = threadIdx.x & 63, wave = threadIdx.x >> 6;
    int v = (threadIdx.x < nb) ? bsum3[y * 256 + threadIdx.x] : 0;
    int x = wscan_incl(v, lane);
    if (lane == 63) wp[wave] = x;
    __syncthreads();
    int off = 0;
#pragma unroll
    for (int w = 0; w < 4; ++w) off += (w < wave) ? wp[w] : 0;
    if (threadIdx.x < nb) bsum3[y * 256 + threadIdx.x] = off + x - v;
    if (threadIdx.x == 0) rp[n] = wp[0] + wp[1] + wp[2] + wp[3];
}
// also writes dinv for graphs 0,1 (dinv = rsqrt(indeg+1))
__global__ __launch_bounds__(256) void scan_fin3_k(const int* __restrict__ cnt3,
                                                   const int* __restrict__ bsum3,
                                                   int* rp0, int* rp1, int* rp2,
                                                   float* dv0, float* dv1, int NTp1) {
    __shared__ int wp[4];
    int y = blockIdx.y;
    int n = (y == 2) ? 40000 : 20000;
    int* rp = (y == 0) ? rp0 : (y == 1) ? rp1 : rp2;
    int i = blockIdx.x * 256 + threadIdx.x;
    int lane = threadIdx.x & 63, wave = threadIdx.x >> 6;
    int v = (i < n) ? cnt3[y * NTp1 + i] : 0;
    int x = wscan_incl(v, lane);
    if (lane == 63) wp[wave] = x;
    __syncthreads();
    int off = 0;
#pragma unroll
    for (int w = 0; w < 4; ++w) off += (w < wave) ? wp[w] : 0;
    if (i < n) {
        rp[i] = bsum3[y * 256 + blockIdx.x] + off + x - v;
        if (y == 0) dv0[i] = rsqrtf((float)(v + 1));
        else if (y == 1) dv1[i] = rsqrtf((float)(v + 1));
    }
}
__global__ void scatter3_k(const int* e0, const int* e1, const int* e2,
                           const int* rp0, const int* rp1, const int* rp2,
                           int* __restrict__ cnt3,
                           int* c0, int* c1, int* c2, int NTp1) {
    int y = blockIdx.y;
    const int* ei = (y == 0) ? e0 : (y == 1) ? e1 : e2;
    const int* rp = (y == 0) ? rp0 : (y == 1) ? rp1 : rp2;
    int* col = (y == 0) ? c0 : (y == 1) ? c1 : c2;
    int E = (y == 2) ? 640000 : 320000;
    int e = blockIdx.x * 256 + threadIdx.x;
    if (e >= E) return;
    int s = ei[e], d = ei[E + e];
    int p = atomicAdd(&cnt3[y * NTp1 + d], 1);
    col[rp[d] + p] = s;
}

// ---------------- batched GCN GEMM (y = graph), LDS-free, fragment-ordered B ----------------
__global__ __launch_bounds__(256) void gemm2_k(const void* A0, const void* A1,
                                               const u16* __restrict__ Wtf0,
                                               const u16* __restrict__ Wtf1,
                                               const int* __restrict__ flagp,
                                               u16* __restrict__ C, int M) {
    int f = flagp[0];
    int y = blockIdx.y;
    const void* Aptr = y ? A1 : A0;
    const u16* Wtf = y ? Wtf1 : Wtf0;
    u16* Cp = C + (size_t)y * M * NF;
    int wave = threadIdx.x >> 6, lane = threadIdx.x & 63;
    int lr = lane & 15, q = lane >> 4;
    int arow = blockIdx.x * 64 + wave * 16 + lr;
    bool rok = arow < M;
    floatx4 acc[16];
#pragma unroll
    for (int nf = 0; nf < 16; ++nf) acc[nf] = (floatx4){0.f, 0.f, 0.f, 0.f};
    const u16* a16 = (const u16*)Aptr + (size_t)arow * NF;
    const float* a32 = (const float*)Aptr + (size_t)arow * NF;
#pragma unroll
    for (int ks = 0; ks < 8; ++ks) {
        int kk = ks * 32 + q * 8;
        union { u16 s[8]; uint4 u; short8 v; } a;
        if (!rok) {
            a.u = make_uint4(0u, 0u, 0u, 0u);
        } else if (f) {
            a.u = *(const uint4*)(a16 + kk);
            a.u.x = zap2(a.u.x); a.u.y = zap2(a.u.y);
            a.u.z = zap2(a.u.z); a.u.w = zap2(a.u.w);
        } else {
            float4 f0 = *(const float4*)(a32 + kk);
            float4 f1 = *(const float4*)(a32 + kk + 4);
            a.s[0] = f2bf(sane(f0.x)); a.s[1] = f2bf(sane(f0.y));
            a.s[2] = f2bf(sane(f0.z)); a.s[3] = f2bf(sane(f0.w));
            a.s[4] = f2bf(sane(f1.x)); a.s[5] = f2bf(sane(f1.y));
            a.s[6] = f2bf(sane(f1.z)); a.s[7] = f2bf(sane(f1.w));
        }
        const u16* bbase = Wtf + ks * 8192 + lane * 8;
#pragma unroll
        for (int nf = 0; nf < 16; ++nf) {
            short8 b = *(const short8*)(bbase + nf * 512);
            acc[nf] = __builtin_amdgcn_mfma_f32_16x16x32_bf16(a.v, b, acc[nf], 0, 0, 0);
        }
    }
#pragma unroll
    for (int nf = 0; nf < 16; ++nf) {
#pragma unroll
        for (int rr = 0; rr < 4; ++rr) {
            int gr = blockIdx.x * 64 + wave * 16 + q * 4 + rr;
            if (gr < M) Cp[(size_t)gr * NF + nf * 16 + lr] = f2bf(acc[nf][rr]);
        }
    }
}

// ---------------- GAT GEMM with fused scores epilogue (bf16 ws input) ----------------
__global__ __launch_bounds__(256) void gemm_gat_k(const u16* __restrict__ Aptr,
                                                  const u16* __restrict__ Wtf,
                                                  u16* __restrict__ C, int M,
                                                  const float* __restrict__ as_,
                                                  const float* __restrict__ ad_,
                                                  float* __restrict__ es,
                                                  float* __restrict__ ed) {
    int wave = threadIdx.x >> 6, lane = threadIdx.x & 63;
    int lr = lane & 15, q = lane >> 4;
    int arow = blockIdx.x * 64 + wave * 16 + lr;
    bool rok = arow < M;
    floatx4 acc[16];
#pragma unroll
    for (int nf = 0; nf < 16; ++nf) acc[nf] = (floatx4){0.f, 0.f, 0.f, 0.f};
    const u16* a16 = Aptr + (size_t)arow * NF;
#pragma unroll
    for (int ks = 0; ks < 8; ++ks) {
        int kk = ks * 32 + q * 8;
        union { uint4 u; short8 v; } a;
        a.u = rok ? *(const uint4*)(a16 + kk) : make_uint4(0u, 0u, 0u, 0u);
        const u16* bbase = Wtf + ks * 8192 + lane * 8;
#pragma unroll
        for (int nf = 0; nf < 16; ++nf) {
            short8 b = *(const short8*)(bbase + nf * 512);
            acc[nf] = __builtin_amdgcn_mfma_f32_16x16x32_bf16(a.v, b, acc[nf], 0, 0, 0);
        }
    }
#pragma unroll
    for (int nf = 0; nf < 16; ++nf) {
#pragma unroll
        for (int rr = 0; rr < 4; ++rr) {
            int gr = blockIdx.x * 64 + wave * 16 + q * 4 + rr;
            if (gr < M) C[(size_t)gr * NF + nf * 16 + lr] = f2bf(acc[nf][rr]);
        }
    }
    // fused scores: s1[row] = sum_c h[row][c]*as_[c], s2 likewise (fp32 acc)
    float asl[16], adl[16];
#pragma unroll
    for (int nf = 0; nf < 16; ++nf) { asl[nf] = as_[nf * 16 + lr]; adl[nf] = ad_[nf * 16 + lr]; }
#pragma unroll
    for (int rr = 0; rr < 4; ++rr) {
        float s1 = 0.f, s2 = 0.f;
#pragma unroll
        for (int nf = 0; nf < 16; ++nf) {
            s1 += acc[nf][rr] * asl[nf];
            s2 += acc[nf][rr] * adl[nf];
        }
#pragma unroll
        for (int o = 1; o < 16; o <<= 1) {
            s1 += __shfl_xor(s1, o, 64);
            s2 += __shfl_xor(s2, o, 64);
        }
        int gr = blockIdx.x * 64 + wave * 16 + q * 4 + rr;
        if (lr == 0 && gr < M) { es[gr] = s1; ed[gr] = s2; }
    }
}

// ---------------- batched GCN aggregation via CSR (y = graph) ----------------
__global__ __launch_bounds__(256) void gcn_csr2_k(const u16* __restrict__ h,
                                                  const int* rp0, const int* rp1,
                                                  const int* c0, const int* c1,
                                                  const float* dv0, const float* dv1,
                                                  const float* __restrict__ prm,
                                                  u16* __restrict__ out, int n) {
    int y = blockIdx.y;
    const int* rp = y ? rp1 : rp0;
    const int* col = y ? c1 : c0;
    const float* dinv = y ? dv1 : dv0;
    const float* b = prm + (y ? P_BAGG : P_BGCN);
    const u16* hb = h + (size_t)y * n * NF;
    u16* ob = out + (size_t)y * n * NF;
    int wave = threadIdx.x >> 6, lane = threadIdx.x & 63;
    int i = blockIdx.x * 4 + wave;
    if (i >= n) return;
    int c = lane * 4;
    int beg = rp[i], end = rp[i + 1];
    float di = dinv[i];
    float4 hv = ld4h(hb + (size_t)i * NF + c);
    float w = di * di;
    float4 acc;
    acc.x = hv.x * w + b[c + 0];
    acc.y = hv.y * w + b[c + 1];
    acc.z = hv.z * w + b[c + 2];
    acc.w = hv.w * w + b[c + 3];
    int j = beg;
    for (; j + 3 < end; j += 4) {
        int s0 = col[j], s1 = col[j + 1], s2 = col[j + 2], s3 = col[j + 3];
        float n0 = dinv[s0] * di, n1 = dinv[s1] * di, n2 = dinv[s2] * di, n3 = dinv[s3] * di;
        float4 h0 = ld4h(hb + (size_t)s0 * NF + c);
        float4 h1 = ld4h(hb + (size_t)s1 * NF + c);
        float4 h2 = ld4h(hb + (size_t)s2 * NF + c);
        float4 h3 = ld4h(hb + (size_t)s3 * NF + c);
        acc.x += h0.x * n0 + h1.x * n1 + h2.x * n2 + h3.x * n3;
        acc.y += h0.y * n0 + h1.y * n1 + h2.y * n2 + h3.y * n3;
        acc.z += h0.z * n0 + h1.z * n1 + h2.z * n2 + h3.z * n3;
        acc.w += h0.w * n0 + h1.w * n1 + h2.w * n2 + h3.w * n3;
    }
    for (; j < end; ++j) {
        int s = col[j];
        float nrm = dinv[s] * di;
        float4 hs = ld4h(hb + (size_t)s * NF + c);
        acc.x += hs.x * nrm;
        acc.y += hs.y * nrm;
        acc.z += hs.z * nrm;
        acc.w += hs.w * nrm;
    }
    st4h(ob + (size_t)i * NF + c, acc);
}

// ---------------- BN partial stats (no atomics): psum/psq[(y*PB+b)*512 + c] ----------------
__global__ void bn_stats2_k(const u16* __restrict__ x, int n,
                            float* __restrict__ psum, float* __restrict__ psq) {
    int y = blockIdx.y;
    int c = threadIdx.x;  // 256
    int r0 = blockIdx.x * 128;
    int rend = min(r0 + 128, n);
    const u16* xb = x + (size_t)y * n * NF;
    float s = 0.f, qq = 0.f;
    for (int r = r0; r < rend; ++r) {
        float v = bf2f(xb[(size_t)r * NF + c]);
        s += v; qq += v * v;
    }
    size_t o = (size_t)(y * PB + blockIdx.x) * 512 + c;
    psum[o] = s; psq[o] = qq;
}
__global__ void bn_fin2_k(const float* __restrict__ psum, const float* __restrict__ psq,
                          float* __restrict__ stg, int n, int nb) {
    int y = blockIdx.y;
    int c = threadIdx.x;  // 256
    float s = 0.f, qq = 0.f;
    for (int b = 0; b < nb; ++b) {
        size_t o = (size_t)(y * PB + b) * 512 + c;
        s += psum[o]; qq += psq[o];
    }
    float inv_n = 1.0f / (float)n;
    float mean = s * inv_n;
    float var = fmaxf(qq * inv_n - mean * mean, 0.f);
    stg[y * 512 + c] = mean;
    stg[y * 512 + 256 + c] = rsqrtf(var + EPSV);
}
__global__ void bn_apply2_k(const u16* __restrict__ x, const float* __restrict__ stg,
                            const float* __restrict__ prm, u16* __restrict__ out, int n) {
    int y = blockIdx.y;
    int t = blockIdx.x * 256 + threadIdx.x;
    if (t >= n * NF) return;
    int c = t & 255;
    const float* st = stg + y * 512;
    const float* g = prm + (y ? P_AGG1 : P_G1);
    const float* be = prm + (y ? P_AGBE1 : P_BE1);
    float v = (bf2f(x[(size_t)y * n * NF + t]) - st[c]) * st[256 + c] * g[c] + be[c];
    out[(size_t)y * n * NF + t] = f2bf(fmaxf(v, 0.f));
}

// ---------------- fused GAT aggregation via CSR, 4-way unrolled pass 3 ----------------
__global__ __launch_bounds__(256) void gat_csr_k(const u16* __restrict__ h,
                                                 const int* __restrict__ rp,
                                                 const int* __restrict__ col,
                                                 const float* __restrict__ es,
                                                 const float* __restrict__ ed,
                                                 const float* __restrict__ b,
                                                 u16* __restrict__ out, int n,
                                                 int do_relu) {
    int wave = threadIdx.x >> 6, lane = threadIdx.x & 63;
    int i = blockIdx.x * 4 + wave;
    if (i >= n) return;
    int beg = rp[i], end = rp[i + 1];
    float edi = ed[i];
    float eself = lrelu(es[i] + edi);
    float m = eself;
    for (int j = beg + lane; j < end; j += 64) m = fmaxf(m, lrelu(es[col[j]] + edi));
    m = wredmax(m);
    float ssum = (lane == 0) ? __expf(eself - m) : 0.f;
    for (int j = beg + lane; j < end; j += 64) ssum += __expf(lrelu(es[col[j]] + edi) - m);
    ssum = wredsum(ssum);
    float inv = 1.0f / ssum;
    int c = lane * 4;
    float al = __expf(eself - m) * inv;
    float4 hv = ld4h(h + (size_t)i * NF + c);
    float4 acc;
    acc.x = b[c + 0] + al * hv.x;
    acc.y = b[c + 1] + al * hv.y;
    acc.z = b[c + 2] + al * hv.z;
    acc.w = b[c + 3] + al * hv.w;
    int j = beg;
    for (; j + 3 < end; j += 4) {
        int s0 = col[j], s1 = col[j + 1], s2 = col[j + 2], s3 = col[j + 3];
        float e0 = es[s0], e1 = es[s1], e2 = es[s2], e3 = es[s3];
        float4 h0 = ld4h(h + (size_t)s0 * NF + c);
        float4 h1 = ld4h(h + (size_t)s1 * NF + c);
        float4 h2 = ld4h(h + (size_t)s2 * NF + c);
        float4 h3 = ld4h(h + (size_t)s3 * NF + c);
        float a0 = __expf(lrelu(e0 + edi) - m) * inv;
        float a1 = __expf(lrelu(e1 + edi) - m) * inv;
        float a2 = __expf(lrelu(e2 + edi) - m) * inv;
        float a3 = __expf(lrelu(e3 + edi) - m) * inv;
        acc.x += h0.x * a0 + h1.x * a1 + h2.x * a2 + h3.x * a3;
        acc.y += h0.y * a0 + h1.y * a1 + h2.y * a2 + h3.y * a3;
        acc.z += h0.z * a0 + h1.z * a1 + h2.z * a2 + h3.z * a3;
        acc.w += h0.w * a0 + h1.w * a1 + h2.w * a2 + h3.w * a3;
    }
    for (; j < end; ++j) {
        int s = col[j];
        float a = __expf(lrelu(es[s] + edi) - m) * inv;
        float4 hs = ld4h(h + (size_t)s * NF + c);
        acc.x += a * hs.x;
        acc.y += a * hs.y;
        acc.z += a * hs.z;
        acc.w += a * hs.w;
    }
    if (do_relu) {
        acc.x = fmaxf(acc.x, 0.f); acc.y = fmaxf(acc.y, 0.f);
        acc.z = fmaxf(acc.z, 0.f); acc.w = fmaxf(acc.w, 0.f);
    }
    st4h(out + (size_t)i * NF + c, acc);
}

// ---------------- batched final-stage BN stats over cat(x,h) (512 ch) ----------------
__global__ void bn_stats_cat2_k(const u16* __restrict__ xp, const u16* __restrict__ hp,
                                int n, float* __restrict__ psum, float* __restrict__ psq) {
    int y = blockIdx.y;
    int c = threadIdx.x;  // 512
    int r0 = blockIdx.x * 128;
    int rend = min(r0 + 128, n);
    const u16* src = ((c < 256) ? xp : hp) + (size_t)y * n * NF;
    int cc = c & 255;
    float s = 0.f, qq = 0.f;
    for (int r = r0; r < rend; ++r) {
        float v = bf2f(src[(size_t)r * NF + cc]);
        s += v; qq += v * v;
    }
    size_t o = (size_t)(y * PB + blockIdx.x) * 512 + c;
    psum[o] = s; psq[o] = qq;
}
__global__ void bn_fin_cat2_k(const float* __restrict__ psum, const float* __restrict__ psq,
                              float* __restrict__ stc, int n, int nb) {
    int y = blockIdx.y;
    int c = threadIdx.x;  // 512
    float s = 0.f, qq = 0.f;
    for (int b = 0; b < nb; ++b) {
        size_t o = (size_t)(y * PB + b) * 512 + c;
        s += psum[o]; qq += psq[o];
    }
    float inv_n = 1.0f / (float)n;
    float mean = s * inv_n;
    float var = fmaxf(qq * inv_n - mean * mean, 0.f);
    stc[y * 1024 + c] = mean;
    stc[y * 1024 + 512 + c] = rsqrtf(var + EPSV);
}
__global__ void final2_k(const u16* __restrict__ xp, const u16* __restrict__ hp,
                         const float* __restrict__ stc, const float* __restrict__ prm,
                         float* __restrict__ out, int n) {
    int y = blockIdx.y;
    int wave = threadIdx.x >> 6, lane = threadIdx.x & 63;
    int i = blockIdx.x * 4 + wave;
    if (i >= n) return;
    const float* st = stc + y * 1024;
    const float* g = prm + (y ? P_AGG2 : P_G2);
    const float* be = prm + (y ? P_AGBE2 : P_BE2);
    const float* w = prm + (y ? P_WAGFC : P_WFC);
    float bias = prm[y ? P_BAGFC : P_BFC];
    const u16* src = (((lane < 32) ? xp : hp) + (size_t)y * n * NF) + (size_t)i * NF
                     + (lane < 32 ? lane * 8 : (lane - 32) * 8);
    uint4 u = *(const uint4*)src;
    float vv[8];
    vv[0] = bf2f((u16)(u.x & 0xFFFFu)); vv[1] = bf2f((u16)(u.x >> 16));
    vv[2] = bf2f((u16)(u.y & 0xFFFFu)); vv[3] = bf2f((u16)(u.y >> 16));
    vv[4] = bf2f((u16)(u.z & 0xFFFFu)); vv[5] = bf2f((u16)(u.z >> 16));
    vv[6] = bf2f((u16)(u.w & 0xFFFFu)); vv[7] = bf2f((u16)(u.w >> 16));
    int c0 = lane * 8;
    float acc = 0.f;
#pragma unroll
    for (int j = 0; j < 8; ++j) {
        int c = c0 + j;
        float v = (vv[j] - st[c]) * st[512 + c] * g[c] + be[c];
        v = fmaxf(v, 0.f);
        acc += v * w[c];
    }
    acc = wredsum(acc);
    if (lane == 0) out[(size_t)y * 20000 + i] = acc + bias;
}

// ---------------- host ----------------
extern "C" void kernel_launch(void* const* d_in, const int* in_sizes, int n_in,
                              void* d_out, int out_size, void* d_ws, size_t ws_size,
                              hipStream_t stream) {
    const void* x_ab = d_in[0];
    const void* x_ag = d_in[1];
    const int* e_ab = (const int*)d_in[26];
    const int* e_ag = (const int*)d_in[27];
    const int* e_d = (const int*)d_in[28];

    const int NAB = 20000, NT = 40000;
    const int EAB = 320000, EAG = 320000, ED = 640000;
    const int NTp1 = NT + 1;

    u16* hcat = (u16*)d_ws;                     // NT*NF u16
    u16* bufA = hcat + (size_t)NT * NF;         // NT*NF u16
    u16* bufB = bufA + (size_t)NT * NF;         // NT*NF u16
    u16* wt4 = bufB + (size_t)NT * NF;          // 4*65536 u16
    float* dv0 = (float*)(wt4 + 4 * 65536);     // NAB
    float* dv1 = dv0 + NAB;                     // NAB
    float* es = dv1 + NAB;                      // NT
    float* edv = es + NT;                       // NT
    float* stg = edv + NT;                      // 1024
    float* stc = stg + 1024;                    // 2048
    float* psum = stc + 2048;                   // 2*PB*512
    float* psq = psum + 2 * PB * 512;           // 2*PB*512
    float* prm = psq + 2 * PB * 512;            // 8192
    int* flag = (int*)(prm + 8192);             // 16
    int* rp_ab = flag + 16;                     // NAB+1
    int* rp_ag = rp_ab + NAB + 1;               // NAB+1
    int* rp_d = rp_ag + NAB + 1;                // NT+1
    int* cnt3 = rp_d + NT + 1;                  // 3*(NT+1)
    int* bsum3 = cnt3 + 3 * NTp1;               // 768
    int* col_ab = bsum3 + 768;                  // EAB
    int* col_ag = col_ab + EAB;                 // EAG
    int* col_d = col_ag + EAG;                  // ED

    u16* wt_gcn = wt4;
    u16* wt_aggcn = wt4 + 65536;
    u16* wt_gat = wt4 + 2 * 65536;
    u16* wt_gat2 = wt4 + 3 * 65536;

    dim3 t256(256), t512(512);
    const int nbg = (NAB + 127) / 128;   // 157 bn partial blocks per graph

    detect_k<<<dim3(1), t256, 0, stream>>>((const u16*)x_ab, flag);
    prep_k<<<dim3(1049), t256, 0, stream>>>(
        d_in[2], d_in[6], d_in[10], d_in[14],
        d_in[3], d_in[4], d_in[5], d_in[7], d_in[8], d_in[9],
        d_in[11], d_in[12], d_in[13], d_in[15], d_in[16], d_in[17],
        d_in[22], d_in[23], d_in[24], d_in[18], d_in[19], d_in[20],
        d_in[25], d_in[21], wt4, prm, flag);

    // batched CSR build (7 dispatches)
    zero_i_k<<<dim3((3 * NTp1 + 255) / 256), t256, 0, stream>>>(cnt3, 3 * NTp1);
    cnt3_k<<<dim3(2500, 3), t256, 0, stream>>>(e_ab, e_ag, e_d, cnt3, NTp1);
    scan_sum3_k<<<dim3(157, 3), t256, 0, stream>>>(cnt3, bsum3, NTp1);
    scan_base3_k<<<dim3(1, 3), t256, 0, stream>>>(bsum3, rp_ab, rp_ag, rp_d);
    scan_fin3_k<<<dim3(157, 3), t256, 0, stream>>>(cnt3, bsum3, rp_ab, rp_ag, rp_d,
                                                   dv0, dv1, NTp1);
    zero_i_k<<<dim3((3 * NTp1 + 255) / 256), t256, 0, stream>>>(cnt3, 3 * NTp1);
    scatter3_k<<<dim3(2500, 3), t256, 0, stream>>>(e_ab, e_ag, e_d, rp_ab, rp_ag, rp_d,
                                                   cnt3, col_ab, col_ag, col_d, NTp1);

    // batched GCN stage (5 dispatches)
    gemm2_k<<<dim3((NAB + 63) / 64, 2), t256, 0, stream>>>(x_ab, x_ag, wt_gcn, wt_aggcn,
                                                           flag, bufA, NAB);
    gcn_csr2_k<<<dim3((NAB + 3) / 4, 2), t256, 0, stream>>>(bufA, rp_ab, rp_ag,
                                                            col_ab, col_ag, dv0, dv1,
                                                            prm, bufB, NAB);
    bn_stats2_k<<<dim3(nbg, 2), t256, 0, stream>>>(bufB, NAB, psum, psq);
    bn_fin2_k<<<dim3(1, 2), t256, 0, stream>>>(psum, psq, stg, NAB, nbg);
    bn_apply2_k<<<dim3((NAB * NF + 255) / 256, 2), t256, 0, stream>>>(bufB, stg, prm,
                                                                      hcat, NAB);

    // GAT layer 1 (2 dispatches)
    gemm_gat_k<<<dim3((NT + 63) / 64), t256, 0, stream>>>(hcat, wt_gat, bufA, NT,
                                                          prm + P_ASRC, prm + P_ADST,
                                                          es, edv);
    gat_csr_k<<<dim3((NT + 3) / 4), t256, 0, stream>>>(bufA, rp_d, col_d, es, edv,
                                                       prm + P_BGAT, bufB, NT, 1);
    // GAT layer 2 (2 dispatches)
    gemm_gat_k<<<dim3((NT + 63) / 64), t256, 0, stream>>>(bufB, wt_gat2, bufA, NT,
                                                          prm + P_ASRC2, prm + P_ADST2,
                                                          es, edv);
    gat_csr_k<<<dim3((NT + 3) / 4), t256, 0, stream>>>(bufA, rp_d, col_d, es, edv,
                                                       prm + P_BGAT2, bufB, NT, 0);

    // batched final stage (3 dispatches)
    bn_stats_cat2_k<<<dim3(nbg, 2), t512, 0, stream>>>(bufB, hcat, NAB, psum, psq);
    bn_fin_cat2_k<<<dim3(1, 2), t512, 0, stream>>>(psum, psq, stc, NAB, nbg);
    final2_k<<<dim3((NAB + 3) / 4, 2), t256, 0, stream>>>(bufB, hcat, stc, prm,
                                                          (float*)d_out, NAB);
}